// Round 1
// baseline (4354.339 us; speedup 1.0000x reference)
//
#include <hip/hip_runtime.h>
#include <hip/hip_bf16.h>
#include <cstdint>
#include <cstddef>

namespace {

constexpr int HW = 16384;   // 128*128

__device__ __forceinline__ float u2f(uint32_t u){ union { uint32_t u; float f; } v; v.u = u; return v.f; }
__device__ __forceinline__ uint32_t f2u(float f){ union { float f; uint32_t u; } v; v.f = f; return v.u; }
__device__ __forceinline__ uint16_t f2bf(float f){
  uint32_t u = f2u(f);
  u += 0x7fffu + ((u >> 16) & 1u);   // round-to-nearest-even
  return (uint16_t)(u >> 16);
}
__device__ __forceinline__ void unpack2(uint32_t w, float& lo, float& hi){
  lo = u2f(w << 16);
  hi = u2f(w & 0xffff0000u);
}

// ---------------------------------------------------------------------------
// 1x1 conv as GEMM: out[b,co,p] = sum_ci W[co,ci] * in[b,ci,p]  (+ optional BN)
// Block: 128 co x 128 px (one image row), 256 threads, thread tile 8x8.
// ---------------------------------------------------------------------------
template<bool DO_BN, bool OUT_BF16>
__global__ __launch_bounds__(256) void k_gemm1x1(
    const float* __restrict__ in, const float* __restrict__ wmat,
    const float* __restrict__ bnp, int M,
    float* __restrict__ outf, uint16_t* __restrict__ outb)
{
  __shared__ __align__(16) float sW[16][128];
  __shared__ __align__(16) float sX[16][128];
  const int t = threadIdx.x;
  const int b  = blockIdx.x >> 7;
  const int p0 = (blockIdx.x & 127) << 7;
  const int co0 = blockIdx.y << 7;
  const int cog = t >> 4, pxg = t & 15;

  float acc[8][8];
  #pragma unroll
  for (int i = 0; i < 8; ++i)
    #pragma unroll
    for (int j = 0; j < 8; ++j) acc[i][j] = 0.f;

  const int wr = t >> 1, whf = (t & 1) << 3;
  const float* wsrc = wmat + (co0 + wr) * 256 + whf;
  const int xcc = t >> 4, xpp = (t & 15) << 3;
  const float* xsrc = in + (size_t)(b * 256 + xcc) * HW + p0 + xpp;

  for (int kc = 0; kc < 16; ++kc) {
    float4 wa = *(const float4*)(wsrc + kc * 16);
    float4 wb = *(const float4*)(wsrc + kc * 16 + 4);
    float4 xa = *(const float4*)(xsrc + (size_t)kc * 16 * HW);
    float4 xb = *(const float4*)(xsrc + (size_t)kc * 16 * HW + 4);
    sW[whf + 0][wr] = wa.x; sW[whf + 1][wr] = wa.y;
    sW[whf + 2][wr] = wa.z; sW[whf + 3][wr] = wa.w;
    sW[whf + 4][wr] = wb.x; sW[whf + 5][wr] = wb.y;
    sW[whf + 6][wr] = wb.z; sW[whf + 7][wr] = wb.w;
    *(float4*)&sX[xcc][xpp]     = xa;
    *(float4*)&sX[xcc][xpp + 4] = xb;
    __syncthreads();
    #pragma unroll
    for (int cc = 0; cc < 16; ++cc) {
      float4 wfa = *(const float4*)&sW[cc][cog * 8];
      float4 wfb = *(const float4*)&sW[cc][cog * 8 + 4];
      float4 xfa = *(const float4*)&sX[cc][pxg * 8];
      float4 xfb = *(const float4*)&sX[cc][pxg * 8 + 4];
      const float wf[8] = {wfa.x,wfa.y,wfa.z,wfa.w, wfb.x,wfb.y,wfb.z,wfb.w};
      const float xf[8] = {xfa.x,xfa.y,xfa.z,xfa.w, xfb.x,xfb.y,xfb.z,xfb.w};
      #pragma unroll
      for (int i = 0; i < 8; ++i)
        #pragma unroll
        for (int j = 0; j < 8; ++j) acc[i][j] = fmaf(wf[i], xf[j], acc[i][j]);
    }
    __syncthreads();
  }

  const int cbase = co0 + cog * 8;
  const int px = p0 + pxg * 8;
  #pragma unroll
  for (int i = 0; i < 8; ++i) {
    const int c = cbase + i;
    float sc = 1.f, sh = 0.f;
    if constexpr (DO_BN) {
      float g = bnp[c], be = bnp[M + c], mu = bnp[2 * M + c], va = bnp[3 * M + c];
      sc = g * rsqrtf(va + 1e-5f);
      sh = be - mu * sc;
    }
    float v[8];
    #pragma unroll
    for (int j = 0; j < 8; ++j) v[j] = fmaf(acc[i][j], sc, sh);
    const size_t dst = (size_t)(b * M + c) * HW + px;
    if constexpr (OUT_BF16) {
      uint4 pk;
      pk.x = (uint32_t)f2bf(v[0]) | ((uint32_t)f2bf(v[1]) << 16);
      pk.y = (uint32_t)f2bf(v[2]) | ((uint32_t)f2bf(v[3]) << 16);
      pk.z = (uint32_t)f2bf(v[4]) | ((uint32_t)f2bf(v[5]) << 16);
      pk.w = (uint32_t)f2bf(v[6]) | ((uint32_t)f2bf(v[7]) << 16);
      *(uint4*)(outb + dst) = pk;
    } else {
      float4 o0 = {v[0], v[1], v[2], v[3]};
      float4 o1 = {v[4], v[5], v[6], v[7]};
      *(float4*)(outf + dst)     = o0;
      *(float4*)(outf + dst + 4) = o1;
    }
  }
}

// ---------------------------------------------------------------------------
// Dilated 3x3 conv + BN on a channel group (zero padding = DIL).
// Block: 128 thr, 32 co x (2 rows x 128 cols). Thread tile 8 co x 8 px,
// x-taps resolved by compile-time register window slicing.
// ---------------------------------------------------------------------------
template<int DIL, int CG>
__global__ __launch_bounds__(128) void k_dilconv(
    const float* __restrict__ in, const float* __restrict__ wt,
    const float* __restrict__ bnp, float* __restrict__ out, int cb)
{
  constexpr int R = 2 + 2 * DIL;
  __shared__ __align__(16) float sX[8][R][140];
  __shared__ __align__(16) float sW[8][9][32];
  const int t = threadIdx.x;
  const int h0  = blockIdx.x * 2;
  const int co0 = blockIdx.y * 32;
  const int b   = blockIdx.z;
  const int cog   = t >> 5;
  const int row_t = (t >> 4) & 1;
  const int w0    = (t & 15) * 8;

  float acc[8][8];
  #pragma unroll
  for (int i = 0; i < 8; ++i)
    #pragma unroll
    for (int p = 0; p < 8; ++p) acc[i][p] = 0.f;

  const int NCH = (CG + 7) / 8;
  for (int kc = 0; kc < NCH; ++kc) {
    const int cib = kc * 8;
    // weights: 32co x 8ci x 9taps = 2304 = 128*18
    for (int k = 0; k < 18; ++k) {
      int idx = t + k * 128;
      int co = idx / 72, rem = idx - co * 72;
      int ci = rem / 9,  tap = rem - ci * 9;
      float v = 0.f;
      if (co0 + co < CG && cib + ci < CG)
        v = wt[(size_t)((co0 + co) * CG + (cib + ci)) * 9 + tap];
      sW[ci][tap][co] = v;
    }
    // input: 8ci x R rows x 136 cols (col c holds global col c-DIL, zero-padded)
    constexpr int NITX = (8 * R * 136) / 128;
    for (int k = 0; k < NITX; ++k) {
      int idx = t + k * 128;
      int ci  = idx / (136 * R);
      int rem = idx - ci * (136 * R);
      int rr  = rem / 136;
      int col = rem - rr * 136;
      int gcol = col - DIL;
      int grow = h0 - DIL + rr;
      float v = 0.f;
      if (cib + ci < CG && (unsigned)gcol < 128u && (unsigned)grow < 128u)
        v = in[(size_t)(b * 256 + cb + cib + ci) * HW + grow * 128 + gcol];
      sX[ci][rr][col] = v;
    }
    __syncthreads();
    #pragma unroll 1
    for (int cc = 0; cc < 8; ++cc) {
      #pragma unroll
      for (int ty = 0; ty < 3; ++ty) {
        const float* xr = &sX[cc][ty * DIL + row_t][w0];
        float win[16];
        *(float4*)&win[0]  = *(const float4*)(xr);
        *(float4*)&win[4]  = *(const float4*)(xr + 4);
        *(float4*)&win[8]  = *(const float4*)(xr + 8);
        *(float4*)&win[12] = *(const float4*)(xr + 12);
        #pragma unroll
        for (int tx = 0; tx < 3; ++tx) {
          const float* wp = &sW[cc][ty * 3 + tx][cog * 8];
          float4 wfa = *(const float4*)wp;
          float4 wfb = *(const float4*)(wp + 4);
          const float wf[8] = {wfa.x,wfa.y,wfa.z,wfa.w, wfb.x,wfb.y,wfb.z,wfb.w};
          #pragma unroll
          for (int i = 0; i < 8; ++i)
            #pragma unroll
            for (int p = 0; p < 8; ++p)
              acc[i][p] = fmaf(wf[i], win[tx * DIL + p], acc[i][p]);
        }
      }
    }
    __syncthreads();
  }

  #pragma unroll
  for (int i = 0; i < 8; ++i) {
    int c = co0 + cog * 8 + i;
    if (c < CG) {
      float g = bnp[c], be = bnp[CG + c], mu = bnp[2 * CG + c], va = bnp[3 * CG + c];
      float sc = g * rsqrtf(va + 1e-5f);
      float sh = be - mu * sc;
      float* dst = out + (size_t)(b * 256 + cb + c) * HW + (h0 + row_t) * 128 + w0;
      float4 o0 = {fmaf(acc[i][0],sc,sh), fmaf(acc[i][1],sc,sh), fmaf(acc[i][2],sc,sh), fmaf(acc[i][3],sc,sh)};
      float4 o1 = {fmaf(acc[i][4],sc,sh), fmaf(acc[i][5],sc,sh), fmaf(acc[i][6],sc,sh), fmaf(acc[i][7],sc,sh)};
      *(float4*)(dst)     = o0;
      *(float4*)(dst + 4) = o1;
    }
  }
}

// ---------------------------------------------------------------------------
// Windowed attention: one block per 8x8 window, loop over 16 heads.
// qkv is bf16 [B][768][HW] (channel = s*256 + n*16 + dd).
// ---------------------------------------------------------------------------
__global__ __launch_bounds__(256) void k_attn(
    const uint16_t* __restrict__ qkv, const float* __restrict__ rpb,
    float* __restrict__ outp)
{
  __shared__ __align__(16) float sQ[16][64];
  __shared__ __align__(16) float sK[16][64];
  __shared__ __align__(16) uint16_t sV[64][16];
  __shared__ __align__(16) float sD[64][68];
  __shared__ float srpb[225];
  const int t  = threadIdx.x;
  const int b  = blockIdx.y;
  const int wy = blockIdx.x >> 4, wx = blockIdx.x & 15;
  const int wbase = (wy * 8) * 128 + wx * 8;

  for (int n = 0; n < 16; ++n) {
    // ---- load q/k/v window + this head's bias column ----
    if (t < 225) srpb[t] = rpb[t * 16 + n];
    {
      int tt = t & 127;
      int dd = tt >> 3, r = tt & 7;
      int ch = ((t < 128) ? 0 : 256) + n * 16 + dd;
      const uint16_t* src = qkv + (size_t)(b * 768 + ch) * HW + wbase + r * 128;
      uint4 w4 = *(const uint4*)src;       // 8 bf16 = one window row
      float f[8];
      unpack2(w4.x, f[0], f[1]); unpack2(w4.y, f[2], f[3]);
      unpack2(w4.z, f[4], f[5]); unpack2(w4.w, f[6], f[7]);
      float* dst = (t < 128) ? &sQ[dd][r * 8] : &sK[dd][r * 8];
      float4 a = {f[0],f[1],f[2],f[3]}, bq = {f[4],f[5],f[6],f[7]};
      *(float4*)dst = a; *(float4*)(dst + 4) = bq;
      if (t < 128) {
        const uint16_t* vs = qkv + (size_t)(b * 768 + 512 + n * 16 + dd) * HW + wbase + r * 128;
        uint4 v4 = *(const uint4*)vs;
        const uint16_t* ve = (const uint16_t*)&v4;
        #pragma unroll
        for (int c = 0; c < 8; ++c) sV[r * 8 + c][dd] = ve[c];
      }
    }
    __syncthreads();
    // ---- dots = (q.k)*0.25 + bias ----
    {
      const int ig = t >> 4, jg = t & 15;
      const int i0 = ig * 4, j0 = jg * 4;
      float a[4][4];
      #pragma unroll
      for (int x = 0; x < 4; ++x)
        #pragma unroll
        for (int y = 0; y < 4; ++y) a[x][y] = 0.f;
      #pragma unroll
      for (int dd = 0; dd < 16; ++dd) {
        float4 qv = *(const float4*)&sQ[dd][i0];
        float4 kv = *(const float4*)&sK[dd][j0];
        const float qa[4] = {qv.x, qv.y, qv.z, qv.w};
        const float ka[4] = {kv.x, kv.y, kv.z, kv.w};
        #pragma unroll
        for (int x = 0; x < 4; ++x)
          #pragma unroll
          for (int y = 0; y < 4; ++y) a[x][y] = fmaf(qa[x], ka[y], a[x][y]);
      }
      #pragma unroll
      for (int x = 0; x < 4; ++x) {
        float dv[4];
        #pragma unroll
        for (int y = 0; y < 4; ++y) {
          int ii = i0 + x, jj = j0 + y;
          int rel = ((ii >> 3) - (jj >> 3) + 7) * 15 + ((ii & 7) - (jj & 7) + 7);
          dv[y] = fmaf(a[x][y], 0.25f, srpb[rel]);
        }
        float4 o = {dv[0], dv[1], dv[2], dv[3]};
        *(float4*)&sD[i0 + x][j0] = o;
      }
    }
    __syncthreads();
    // ---- softmax (4 lanes per row) + PV in registers ----
    {
      const int i = t >> 2, q4 = t & 3;
      float p[16];
      *(float4*)&p[0]  = *(const float4*)&sD[i][q4 * 16];
      *(float4*)&p[4]  = *(const float4*)&sD[i][q4 * 16 + 4];
      *(float4*)&p[8]  = *(const float4*)&sD[i][q4 * 16 + 8];
      *(float4*)&p[12] = *(const float4*)&sD[i][q4 * 16 + 12];
      float mx = p[0];
      #pragma unroll
      for (int jj = 1; jj < 16; ++jj) mx = fmaxf(mx, p[jj]);
      mx = fmaxf(mx, __shfl_xor(mx, 1));
      mx = fmaxf(mx, __shfl_xor(mx, 2));
      float s = 0.f;
      #pragma unroll
      for (int jj = 0; jj < 16; ++jj) { p[jj] = __expf(p[jj] - mx); s += p[jj]; }
      s += __shfl_xor(s, 1);
      s += __shfl_xor(s, 2);
      const float sinv = 1.f / s;
      float part[16];
      #pragma unroll
      for (int dd = 0; dd < 16; ++dd) part[dd] = 0.f;
      #pragma unroll
      for (int jj = 0; jj < 16; ++jj) {
        const uint16_t* vr = &sV[q4 * 16 + jj][0];
        uint4 lo = *(const uint4*)vr;
        uint4 hi = *(const uint4*)(vr + 8);
        float vv[16];
        unpack2(lo.x, vv[0], vv[1]);   unpack2(lo.y, vv[2], vv[3]);
        unpack2(lo.z, vv[4], vv[5]);   unpack2(lo.w, vv[6], vv[7]);
        unpack2(hi.x, vv[8], vv[9]);   unpack2(hi.y, vv[10], vv[11]);
        unpack2(hi.z, vv[12], vv[13]); unpack2(hi.w, vv[14], vv[15]);
        #pragma unroll
        for (int dd = 0; dd < 16; ++dd) part[dd] = fmaf(p[jj], vv[dd], part[dd]);
      }
      #pragma unroll
      for (int dd = 0; dd < 16; ++dd) {
        part[dd] += __shfl_xor(part[dd], 1);
        part[dd] += __shfl_xor(part[dd], 2);
      }
      const int r = i >> 3, c = i & 7;
      float* dst = outp + (size_t)(b * 256 + n * 16 + q4 * 4) * HW + wbase + r * 128 + c;
      #pragma unroll
      for (int m2 = 0; m2 < 4; ++m2) dst[(size_t)m2 * HW] = part[q4 * 4 + m2] * sinv;
    }
    __syncthreads();
  }
}

// ---------------------------------------------------------------------------
// combined = avgpool_v(attn) + avgpool_h(attn) + local   (in-place into loc)
// Block handles 64 rows of one (b,c) plane.
// ---------------------------------------------------------------------------
__global__ __launch_bounds__(256) void k_pool(
    const float* __restrict__ attn, float* __restrict__ loc)
{
  __shared__ __align__(16) float sP[71][132];
  const int t = threadIdx.x;
  const int plane = blockIdx.x >> 1;
  const int h0 = (blockIdx.x & 1) * 64;
  const size_t pbase = (size_t)plane * HW;
  for (int k = 0; k < 36; ++k) {
    int idx = t + k * 256;
    if (idx < 71 * 128) {
      int lr = idx >> 7, c = idx & 127;
      int g = h0 - 3 + lr;
      if (g >= 0 && g <= 127) sP[lr][c] = attn[pbase + g * 128 + c];
    }
  }
  __syncthreads();
  for (int k = 0; k < 32; ++k) {
    int idx = t + k * 256;
    int lh = idx >> 7, w = idx & 127;
    int h = h0 + lh;
    float ax = 0.f;
    #pragma unroll
    for (int o = -3; o <= 4; ++o) {
      int j = h + o;
      if (j >= 0 && j <= 128) {
        int jr = (j == 128) ? 126 : j;
        ax += sP[jr - h0 + 3][w];
      }
    }
    float ay = 0.f;
    #pragma unroll
    for (int o = -3; o <= 4; ++o) {
      int j = w + o;
      if (j >= 0 && j <= 128) {
        int jr = (j == 128) ? 126 : j;
        ay += sP[lh + 3][jr];
      }
    }
    size_t gi = pbase + (size_t)h * 128 + w;
    loc[gi] = fmaf(ax + ay, 0.125f, loc[gi]);
  }
}

// ---------------------------------------------------------------------------
// Depthwise 8x8 conv on reflect(+1)-padded combined, zero pad 3.
// Block handles 64 rows of one (b,c) plane. Thread: 16 cols x 2 row-groups.
// ---------------------------------------------------------------------------
__global__ __launch_bounds__(256) void k_dw(
    const float* __restrict__ comb, const float* __restrict__ wdw,
    float* __restrict__ out)
{
  __shared__ __align__(16) float sZ[71][140];
  __shared__ float sWd[64];
  const int t = threadIdx.x;
  const int plane = blockIdx.x >> 1;
  const int cch = plane & 255;
  const int h0 = (blockIdx.x & 1) * 64;
  const size_t pbase = (size_t)plane * HW;
  if (t < 64) sWd[t] = wdw[cch * 64 + t];
  for (int k = 0; k < 38; ++k) {
    int idx = t + k * 256;
    if (idx < 71 * 136) {
      int u = idx / 136, vc = idx - u * 136;
      int g = h0 - 3 + u;
      if (g >= 0 && g <= 128) {
        int bb = vc - 3;
        float v = 0.f;
        if (bb >= 0 && bb <= 128) {
          int gr = (g == 128) ? 126 : g;
          int br = (bb == 128) ? 126 : bb;
          v = comb[pbase + gr * 128 + br];
        }
        sZ[u][vc] = v;
      }
    }
  }
  __syncthreads();
  const int wg = t & 7, hl = t >> 3;   // wg 0..7, hl 0..31
  const int w0 = wg * 16;
  float acc[2][16];
  #pragma unroll
  for (int a = 0; a < 2; ++a)
    #pragma unroll
    for (int p = 0; p < 16; ++p) acc[a][p] = 0.f;
  #pragma unroll 1
  for (int i = 0; i < 8; ++i) {
    float wrow[8];
    *(float4*)&wrow[0] = *(const float4*)&sWd[i * 8];
    *(float4*)&wrow[4] = *(const float4*)&sWd[i * 8 + 4];
    #pragma unroll
    for (int hi = 0; hi < 2; ++hi) {
      int h = h0 + hl + 32 * hi;
      int u = h + i - 3;
      bool ok = (u >= 0 && u <= 128);
      int lr = ok ? (u - h0 + 3) : 0;
      const float* zr = &sZ[lr][w0];
      float win[24];
      *(float4*)&win[0]  = *(const float4*)(zr);
      *(float4*)&win[4]  = *(const float4*)(zr + 4);
      *(float4*)&win[8]  = *(const float4*)(zr + 8);
      *(float4*)&win[12] = *(const float4*)(zr + 12);
      *(float4*)&win[16] = *(const float4*)(zr + 16);
      *(float4*)&win[20] = *(const float4*)(zr + 20);
      float m = ok ? 1.f : 0.f;
      float wv[8];
      #pragma unroll
      for (int j = 0; j < 8; ++j) wv[j] = wrow[j] * m;
      #pragma unroll
      for (int p = 0; p < 16; ++p)
        #pragma unroll
        for (int j = 0; j < 8; ++j)
          acc[hi][p] = fmaf(wv[j], win[p + j], acc[hi][p]);
    }
  }
  #pragma unroll
  for (int hi = 0; hi < 2; ++hi) {
    int h = h0 + hl + 32 * hi;
    float* dst = out + pbase + (size_t)h * 128 + w0;
    float4 o0 = {acc[hi][0],  acc[hi][1],  acc[hi][2],  acc[hi][3]};
    float4 o1 = {acc[hi][4],  acc[hi][5],  acc[hi][6],  acc[hi][7]};
    float4 o2 = {acc[hi][8],  acc[hi][9],  acc[hi][10], acc[hi][11]};
    float4 o3 = {acc[hi][12], acc[hi][13], acc[hi][14], acc[hi][15]};
    *(float4*)(dst)      = o0;
    *(float4*)(dst + 4)  = o1;
    *(float4*)(dst + 8)  = o2;
    *(float4*)(dst + 12) = o3;
  }
}

} // namespace

extern "C" void kernel_launch(void* const* d_in, const int* in_sizes, int n_in,
                              void* d_out, int out_size, void* d_ws, size_t ws_size,
                              hipStream_t stream)
{
  const float* x      = (const float*)d_in[0];
  const float* w_pre  = (const float*)d_in[1];
  const float* bn_pre = (const float*)d_in[2];
  const float* w_l1   = (const float*)d_in[3];
  const float* bn_l1  = (const float*)d_in[4];
  const float* w_l2   = (const float*)d_in[5];
  const float* bn_l2  = (const float*)d_in[6];
  const float* w_l3   = (const float*)d_in[7];
  const float* bn_l3  = (const float*)d_in[8];
  const float* w_qkv  = (const float*)d_in[9];
  const float* rpb    = (const float*)d_in[10];
  const float* w_dw   = (const float*)d_in[11];
  const float* w_pw   = (const float*)d_in[12];
  const float* bn_pj  = (const float*)d_in[13];
  float* out = (float*)d_out;

  float* bufA = (float*)d_ws;                         // 8*256*16384 fp32
  float* bufB = bufA + (size_t)33554432;              // 8*256*16384 fp32
  uint16_t* bufQ = (uint16_t*)(bufB + (size_t)33554432); // 8*768*16384 bf16

  dim3 blk(256);
  // 1. pre 1x1 conv + bn  -> bufA
  k_gemm1x1<true, false><<<dim3(1024, 2), blk, 0, stream>>>(x, w_pre, bn_pre, 256, bufA, nullptr);
  // 2. dilated 3x3 convs + bn -> bufB
  k_dilconv<1, 86><<<dim3(64, 3, 8), dim3(128), 0, stream>>>(bufA, w_l1, bn_l1, bufB, 0);
  k_dilconv<2, 86><<<dim3(64, 3, 8), dim3(128), 0, stream>>>(bufA, w_l2, bn_l2, bufB, 86);
  k_dilconv<3, 84><<<dim3(64, 3, 8), dim3(128), 0, stream>>>(bufA, w_l3, bn_l3, bufB, 172);
  // 3. qkv 1x1 conv -> bufQ (bf16)
  k_gemm1x1<false, true><<<dim3(1024, 6), blk, 0, stream>>>(x, w_qkv, nullptr, 768, nullptr, bufQ);
  // 4. windowed attention -> bufA
  k_attn<<<dim3(256, 8), blk, 0, stream>>>(bufQ, rpb, bufA);
  // 5. pools + residual combine (in-place on bufB)
  k_pool<<<dim3(4096), blk, 0, stream>>>(bufA, bufB);
  // 6. depthwise 8x8 -> bufA
  k_dw<<<dim3(4096), blk, 0, stream>>>(bufB, w_dw, bufA);
  // 7. pw 1x1 conv + bn -> out
  k_gemm1x1<true, false><<<dim3(1024, 2), blk, 0, stream>>>(bufA, w_pw, bn_pj, 256, out, nullptr);

  (void)in_sizes; (void)n_in; (void)out_size; (void)ws_size;
}

// Round 3
// 1858.575 us; speedup vs baseline: 2.3428x; 2.3428x over previous
//
#include <hip/hip_runtime.h>
#include <hip/hip_bf16.h>
#include <cstdint>
#include <cstddef>

namespace {

constexpr int HW = 16384;   // 128*128

typedef short vec8s __attribute__((ext_vector_type(8)));
typedef float f32x4 __attribute__((ext_vector_type(4)));

__device__ __forceinline__ float u2f(uint32_t u){ union { uint32_t u; float f; } v; v.u = u; return v.f; }
__device__ __forceinline__ uint32_t f2u(float f){ union { float f; uint32_t u; } v; v.f = f; return v.u; }
__device__ __forceinline__ uint16_t f2bf(float f){
  uint32_t u = f2u(f);
  u += 0x7fffu + ((u >> 16) & 1u);   // round-to-nearest-even
  return (uint16_t)(u >> 16);
}
__device__ __forceinline__ void unpack2(uint32_t w, float& lo, float& hi){
  lo = u2f(w << 16);
  hi = u2f(w & 0xffff0000u);
}

// ---------------------------------------------------------------------------
// 1x1 conv as GEMM: out[b,co,p] = sum_ci W[co,ci] * in[b,ci,p]  (+ optional BN)
// Block: 128 co x 128 px, 256 threads, thread tile 8x8.
// NHWC=true: write bf16 [b][px][co] (for MFMA conv staging).
// ---------------------------------------------------------------------------
template<bool DO_BN, bool OUT_BF16, bool NHWC>
__global__ __launch_bounds__(256) void k_gemm1x1(
    const float* __restrict__ in, const float* __restrict__ wmat,
    const float* __restrict__ bnp, int M,
    float* __restrict__ outf, uint16_t* __restrict__ outb)
{
  __shared__ __align__(16) float sW[16][128];
  __shared__ __align__(16) float sX[16][128];
  const int t = threadIdx.x;
  const int b  = blockIdx.x >> 7;
  const int p0 = (blockIdx.x & 127) << 7;
  const int co0 = blockIdx.y << 7;
  const int cog = t >> 4, pxg = t & 15;

  float acc[8][8];
  #pragma unroll
  for (int i = 0; i < 8; ++i)
    #pragma unroll
    for (int j = 0; j < 8; ++j) acc[i][j] = 0.f;

  const int wr = t >> 1, whf = (t & 1) << 3;
  const float* wsrc = wmat + (co0 + wr) * 256 + whf;
  const int xcc = t >> 4, xpp = (t & 15) << 3;
  const float* xsrc = in + (size_t)(b * 256 + xcc) * HW + p0 + xpp;

  for (int kc = 0; kc < 16; ++kc) {
    float4 wa = *(const float4*)(wsrc + kc * 16);
    float4 wb = *(const float4*)(wsrc + kc * 16 + 4);
    float4 xa = *(const float4*)(xsrc + (size_t)kc * 16 * HW);
    float4 xb = *(const float4*)(xsrc + (size_t)kc * 16 * HW + 4);
    sW[whf + 0][wr] = wa.x; sW[whf + 1][wr] = wa.y;
    sW[whf + 2][wr] = wa.z; sW[whf + 3][wr] = wa.w;
    sW[whf + 4][wr] = wb.x; sW[whf + 5][wr] = wb.y;
    sW[whf + 6][wr] = wb.z; sW[whf + 7][wr] = wb.w;
    *(float4*)&sX[xcc][xpp]     = xa;
    *(float4*)&sX[xcc][xpp + 4] = xb;
    __syncthreads();
    #pragma unroll
    for (int cc = 0; cc < 16; ++cc) {
      float4 wfa = *(const float4*)&sW[cc][cog * 8];
      float4 wfb = *(const float4*)&sW[cc][cog * 8 + 4];
      float4 xfa = *(const float4*)&sX[cc][pxg * 8];
      float4 xfb = *(const float4*)&sX[cc][pxg * 8 + 4];
      const float wf[8] = {wfa.x,wfa.y,wfa.z,wfa.w, wfb.x,wfb.y,wfb.z,wfb.w};
      const float xf[8] = {xfa.x,xfa.y,xfa.z,xfa.w, xfb.x,xfb.y,xfb.z,xfb.w};
      #pragma unroll
      for (int i = 0; i < 8; ++i)
        #pragma unroll
        for (int j = 0; j < 8; ++j) acc[i][j] = fmaf(wf[i], xf[j], acc[i][j]);
    }
    __syncthreads();
  }

  const int cbase = co0 + cog * 8;
  const int px = p0 + pxg * 8;
  float sc[8], sh[8];
  #pragma unroll
  for (int i = 0; i < 8; ++i) {
    sc[i] = 1.f; sh[i] = 0.f;
    if constexpr (DO_BN) {
      const int c = cbase + i;
      float g = bnp[c], be = bnp[M + c], mu = bnp[2 * M + c], va = bnp[3 * M + c];
      sc[i] = g * rsqrtf(va + 1e-5f);
      sh[i] = be - mu * sc[i];
    }
  }
  if constexpr (OUT_BF16 && NHWC) {
    #pragma unroll
    for (int j = 0; j < 8; ++j) {
      uint4 pk;
      float v0 = fmaf(acc[0][j], sc[0], sh[0]);
      float v1 = fmaf(acc[1][j], sc[1], sh[1]);
      float v2 = fmaf(acc[2][j], sc[2], sh[2]);
      float v3 = fmaf(acc[3][j], sc[3], sh[3]);
      float v4 = fmaf(acc[4][j], sc[4], sh[4]);
      float v5 = fmaf(acc[5][j], sc[5], sh[5]);
      float v6 = fmaf(acc[6][j], sc[6], sh[6]);
      float v7 = fmaf(acc[7][j], sc[7], sh[7]);
      pk.x = (uint32_t)f2bf(v0) | ((uint32_t)f2bf(v1) << 16);
      pk.y = (uint32_t)f2bf(v2) | ((uint32_t)f2bf(v3) << 16);
      pk.z = (uint32_t)f2bf(v4) | ((uint32_t)f2bf(v5) << 16);
      pk.w = (uint32_t)f2bf(v6) | ((uint32_t)f2bf(v7) << 16);
      *(uint4*)(outb + ((size_t)b * HW + px + j) * 256 + cbase) = pk;
    }
  } else {
    #pragma unroll
    for (int i = 0; i < 8; ++i) {
      float v[8];
      #pragma unroll
      for (int j = 0; j < 8; ++j) v[j] = fmaf(acc[i][j], sc[i], sh[i]);
      const size_t dst = (size_t)(b * M + cbase + i) * HW + px;
      if constexpr (OUT_BF16) {
        uint4 pk;
        pk.x = (uint32_t)f2bf(v[0]) | ((uint32_t)f2bf(v[1]) << 16);
        pk.y = (uint32_t)f2bf(v[2]) | ((uint32_t)f2bf(v[3]) << 16);
        pk.z = (uint32_t)f2bf(v[4]) | ((uint32_t)f2bf(v[5]) << 16);
        pk.w = (uint32_t)f2bf(v[6]) | ((uint32_t)f2bf(v[7]) << 16);
        *(uint4*)(outb + dst) = pk;
      } else {
        float4 o0 = {v[0], v[1], v[2], v[3]};
        float4 o1 = {v[4], v[5], v[6], v[7]};
        *(float4*)(outf + dst)     = o0;
        *(float4*)(outf + dst + 4) = o1;
      }
    }
  }
}

// ---------------------------------------------------------------------------
// Dilated 3x3 conv + BN via bf16 MFMA implicit GEMM.
// Input: NHWC bf16 preT[b][y][x][256].  Output: NCHW fp32 (+BN).
// K = (2 taps x 16 ci) per MFMA step; 9 taps padded to 10 (zero weights);
// ci window [cb_al, cb_al+96) 16-aligned, out-of-group weights zeroed.
// Block: 256 thr (4 waves), tile 48co x (8 rows x 64 cols).
// ---------------------------------------------------------------------------
template<int DIL, int CG>
__global__ __launch_bounds__(256) void k_dilconv_mfma(
    const uint16_t* __restrict__ preT, const float* __restrict__ wt,
    const float* __restrict__ bnp, float* __restrict__ out,
    int cb, int cb_al)
{
  constexpr int R = 8 + 2 * DIL;        // staged rows
  constexpr int C = 64 + 2 * DIL;       // staged cols
  constexpr int NPOS = R * C;
  constexpr int NIT = (NPOS + 255) / 256;
  __shared__ __align__(16) uint16_t sX[NPOS * 16];
  __shared__ __align__(16) uint16_t sW[10 * 50 * 16];

  const int t = threadIdx.x;
  const int rt    = blockIdx.x >> 1;    // 0..15 row tile
  const int ctile = blockIdx.x & 1;     // 0..1 col tile
  const int ct2   = blockIdx.y;         // 0..1 co tile (48 each)
  const int b     = blockIdx.z;
  const int y0 = rt * 8, x0 = ctile * 64;
  const int l = t & 63, w = t >> 6;
  const int l15 = l & 15, oct = (l >> 4) & 1, half = l >> 5;
  const int rbase = w * 2;

  f32x4 acc[3][8];
  #pragma unroll
  for (int cf = 0; cf < 3; ++cf)
    #pragma unroll
    for (int q = 0; q < 8; ++q) acc[cf][q] = (f32x4){0.f,0.f,0.f,0.f};

  for (int kc = 0; kc < 6; ++kc) {
    // ---- stage weights: sW[tap][co(pad50)][ci16], bf16.
    //      UB-free: index is guarded so wp is always in-bounds. ----
    #pragma unroll
    for (int i = 0; i < 3; ++i) {
      int pair = t + i * 256;              // 768 = 48co x 16ci
      int co = pair >> 4, ci = pair & 15;
      int cog = ct2 * 48 + co;
      int c = cb_al + kc * 16 + ci;
      bool ok = (cog < CG) && (c >= cb) && (c < cb + CG);
      size_t widx = ok ? ((size_t)cog * (size_t)CG + (size_t)(c - cb)) * 9u
                       : (size_t)0;
      const float* wp = wt + widx;
      uint16_t* dst = &sW[co * 16 + ci];
      #pragma unroll
      for (int tap = 0; tap < 9; ++tap)
        dst[tap * 800] = ok ? f2bf(wp[tap]) : (uint16_t)0;
      dst[9 * 800] = 0;
    }
    // ---- stage input: sX[row][col][ci16], straight NHWC copy ----
    #pragma unroll
    for (int i = 0; i < NIT; ++i) {
      int p = t + i * 256;
      if (p < NPOS) {
        int row = p / C, col = p % C;
        int gy = y0 + row - DIL, gx = x0 + col - DIL;
        uint4 va = {0,0,0,0}, vb = {0,0,0,0};
        if ((unsigned)gy < 128u && (unsigned)gx < 128u) {
          const uint4* src = (const uint4*)(preT +
              (((size_t)b * HW + gy * 128 + gx) * 256 + cb_al + kc * 16));
          va = src[0]; vb = src[1];
        }
        uint4* dst = (uint4*)&sX[p * 16];
        dst[0] = va; dst[1] = vb;
      }
    }
    __syncthreads();

    // ---- MFMA: 5 K-steps of (2 taps x 16 ci) ----
    #pragma unroll
    for (int s = 0; s < 5; ++s) {
      const int tap0 = 2 * s, tap1 = 2 * s + 1;
      const int dy0 = tap0 / 3, dx0 = tap0 % 3;
      const int dy1 = (tap1 <= 8) ? tap1 / 3 : 2;
      const int dx1 = (tap1 <= 8) ? tap1 % 3 : 2;
      const int dy = half ? dy1 : dy0;
      const int dx = half ? dx1 : dx0;
      const int atap = tap0 + half;
      vec8s a0 = *(const vec8s*)&sW[(atap * 50 + 0  + l15) * 16 + oct * 8];
      vec8s a1 = *(const vec8s*)&sW[(atap * 50 + 16 + l15) * 16 + oct * 8];
      vec8s a2 = *(const vec8s*)&sW[(atap * 50 + 32 + l15) * 16 + oct * 8];
      #pragma unroll
      for (int rs = 0; rs < 2; ++rs) {
        const int rowin = rbase + rs + dy * DIL;
        #pragma unroll
        for (int c4 = 0; c4 < 4; ++c4) {
          const int colin = c4 * 16 + l15 + dx * DIL;
          vec8s bf = *(const vec8s*)&sX[(rowin * C + colin) * 16 + oct * 8];
          acc[0][rs*4+c4] = __builtin_amdgcn_mfma_f32_16x16x32_bf16(a0, bf, acc[0][rs*4+c4], 0, 0, 0);
          acc[1][rs*4+c4] = __builtin_amdgcn_mfma_f32_16x16x32_bf16(a1, bf, acc[1][rs*4+c4], 0, 0, 0);
          acc[2][rs*4+c4] = __builtin_amdgcn_mfma_f32_16x16x32_bf16(a2, bf, acc[2][rs*4+c4], 0, 0, 0);
        }
      }
    }
    __syncthreads();
  }

  // ---- epilogue: BN + NCHW store. D: row m=(l>>4)*4+r (co), col n=l15 (px) ----
  const int row4 = (l >> 4);
  #pragma unroll
  for (int cf = 0; cf < 3; ++cf) {
    #pragma unroll
    for (int r = 0; r < 4; ++r) {
      int c_loc = ct2 * 48 + cf * 16 + row4 * 4 + r;
      if (c_loc < CG) {
        int cg = cb + c_loc;
        float g = bnp[c_loc], be = bnp[CG + c_loc];
        float mu = bnp[2 * CG + c_loc], va = bnp[3 * CG + c_loc];
        float scv = g * rsqrtf(va + 1e-5f);
        float shv = be - mu * scv;
        #pragma unroll
        for (int rs = 0; rs < 2; ++rs) {
          int y = y0 + rbase + rs;
          #pragma unroll
          for (int c4 = 0; c4 < 4; ++c4) {
            int x = x0 + c4 * 16 + l15;
            out[(size_t)(b * 256 + cg) * HW + y * 128 + x] =
                fmaf(acc[cf][rs*4+c4][r], scv, shv);
          }
        }
      }
    }
  }
}

// ---------------------------------------------------------------------------
// Windowed attention: one block per 8x8 window, loop over 16 heads.
// qkv bf16 [B][768][HW]; output bf16 NCHW.
// ---------------------------------------------------------------------------
__global__ __launch_bounds__(256) void k_attn(
    const uint16_t* __restrict__ qkv, const float* __restrict__ rpb,
    uint16_t* __restrict__ outp)
{
  __shared__ __align__(16) float sQ[16][64];
  __shared__ __align__(16) float sK[16][64];
  __shared__ __align__(16) uint16_t sV[64][16];
  __shared__ __align__(16) float sD[64][68];
  __shared__ float srpb[225];
  const int t  = threadIdx.x;
  const int b  = blockIdx.y;
  const int wy = blockIdx.x >> 4, wx = blockIdx.x & 15;
  const int wbase = (wy * 8) * 128 + wx * 8;

  for (int n = 0; n < 16; ++n) {
    if (t < 225) srpb[t] = rpb[t * 16 + n];
    {
      int tt = t & 127;
      int dd = tt >> 3, r = tt & 7;
      int ch = ((t < 128) ? 0 : 256) + n * 16 + dd;
      const uint16_t* src = qkv + (size_t)(b * 768 + ch) * HW + wbase + r * 128;
      uint4 w4 = *(const uint4*)src;
      float f[8];
      unpack2(w4.x, f[0], f[1]); unpack2(w4.y, f[2], f[3]);
      unpack2(w4.z, f[4], f[5]); unpack2(w4.w, f[6], f[7]);
      float* dst = (t < 128) ? &sQ[dd][r * 8] : &sK[dd][r * 8];
      float4 a = {f[0],f[1],f[2],f[3]}, bq = {f[4],f[5],f[6],f[7]};
      *(float4*)dst = a; *(float4*)(dst + 4) = bq;
      if (t < 128) {
        const uint16_t* vs = qkv + (size_t)(b * 768 + 512 + n * 16 + dd) * HW + wbase + r * 128;
        uint4 v4 = *(const uint4*)vs;
        const uint16_t* ve = (const uint16_t*)&v4;
        #pragma unroll
        for (int c = 0; c < 8; ++c) sV[r * 8 + c][dd] = ve[c];
      }
    }
    __syncthreads();
    {
      const int ig = t >> 4, jg = t & 15;
      const int i0 = ig * 4, j0 = jg * 4;
      float a[4][4];
      #pragma unroll
      for (int x = 0; x < 4; ++x)
        #pragma unroll
        for (int y = 0; y < 4; ++y) a[x][y] = 0.f;
      #pragma unroll
      for (int dd = 0; dd < 16; ++dd) {
        float4 qv = *(const float4*)&sQ[dd][i0];
        float4 kv = *(const float4*)&sK[dd][j0];
        const float qa[4] = {qv.x, qv.y, qv.z, qv.w};
        const float ka[4] = {kv.x, kv.y, kv.z, kv.w};
        #pragma unroll
        for (int x = 0; x < 4; ++x)
          #pragma unroll
          for (int y = 0; y < 4; ++y) a[x][y] = fmaf(qa[x], ka[y], a[x][y]);
      }
      #pragma unroll
      for (int x = 0; x < 4; ++x) {
        float dv[4];
        #pragma unroll
        for (int y = 0; y < 4; ++y) {
          int ii = i0 + x, jj = j0 + y;
          int rel = ((ii >> 3) - (jj >> 3) + 7) * 15 + ((ii & 7) - (jj & 7) + 7);
          dv[y] = fmaf(a[x][y], 0.25f, srpb[rel]);
        }
        float4 o = {dv[0], dv[1], dv[2], dv[3]};
        *(float4*)&sD[i0 + x][j0] = o;
      }
    }
    __syncthreads();
    {
      const int i = t >> 2, q4 = t & 3;
      float p[16];
      *(float4*)&p[0]  = *(const float4*)&sD[i][q4 * 16];
      *(float4*)&p[4]  = *(const float4*)&sD[i][q4 * 16 + 4];
      *(float4*)&p[8]  = *(const float4*)&sD[i][q4 * 16 + 8];
      *(float4*)&p[12] = *(const float4*)&sD[i][q4 * 16 + 12];
      float mx = p[0];
      #pragma unroll
      for (int jj = 1; jj < 16; ++jj) mx = fmaxf(mx, p[jj]);
      mx = fmaxf(mx, __shfl_xor(mx, 1));
      mx = fmaxf(mx, __shfl_xor(mx, 2));
      float s = 0.f;
      #pragma unroll
      for (int jj = 0; jj < 16; ++jj) { p[jj] = __expf(p[jj] - mx); s += p[jj]; }
      s += __shfl_xor(s, 1);
      s += __shfl_xor(s, 2);
      const float sinv = 1.f / s;
      float part[16];
      #pragma unroll
      for (int dd = 0; dd < 16; ++dd) part[dd] = 0.f;
      #pragma unroll
      for (int jj = 0; jj < 16; ++jj) {
        const uint16_t* vr = &sV[q4 * 16 + jj][0];
        uint4 lo = *(const uint4*)vr;
        uint4 hi = *(const uint4*)(vr + 8);
        float vv[16];
        unpack2(lo.x, vv[0], vv[1]);   unpack2(lo.y, vv[2], vv[3]);
        unpack2(lo.z, vv[4], vv[5]);   unpack2(lo.w, vv[6], vv[7]);
        unpack2(hi.x, vv[8], vv[9]);   unpack2(hi.y, vv[10], vv[11]);
        unpack2(hi.z, vv[12], vv[13]); unpack2(hi.w, vv[14], vv[15]);
        #pragma unroll
        for (int dd = 0; dd < 16; ++dd) part[dd] = fmaf(p[jj], vv[dd], part[dd]);
      }
      #pragma unroll
      for (int dd = 0; dd < 16; ++dd) {
        part[dd] += __shfl_xor(part[dd], 1);
        part[dd] += __shfl_xor(part[dd], 2);
      }
      const int r = i >> 3, c = i & 7;
      uint16_t* dst = outp + (size_t)(b * 256 + n * 16 + q4 * 4) * HW + wbase + r * 128 + c;
      #pragma unroll
      for (int m2 = 0; m2 < 4; ++m2) dst[(size_t)m2 * HW] = f2bf(part[q4 * 4 + m2] * sinv);
    }
    __syncthreads();
  }
}

// ---------------------------------------------------------------------------
// combined = avgpool_v(attn) + avgpool_h(attn) + local (in-place into loc)
// attn is bf16.
// ---------------------------------------------------------------------------
__global__ __launch_bounds__(256) void k_pool(
    const uint16_t* __restrict__ attnb, float* __restrict__ loc)
{
  __shared__ __align__(16) float sP[71][132];
  const int t = threadIdx.x;
  const int plane = blockIdx.x >> 1;
  const int h0 = (blockIdx.x & 1) * 64;
  const size_t pbase = (size_t)plane * HW;
  for (int k = 0; k < 5; ++k) {
    int idx = t + k * 256;
    if (idx < 71 * 16) {
      int lr = idx >> 4, c8 = (idx & 15) * 8;
      int g = h0 - 3 + lr;
      if (g >= 0 && g <= 127) {
        uint4 v4 = *(const uint4*)(attnb + pbase + (size_t)g * 128 + c8);
        float f[8];
        unpack2(v4.x, f[0], f[1]); unpack2(v4.y, f[2], f[3]);
        unpack2(v4.z, f[4], f[5]); unpack2(v4.w, f[6], f[7]);
        #pragma unroll
        for (int j = 0; j < 8; ++j) sP[lr][c8 + j] = f[j];
      }
    }
  }
  __syncthreads();
  for (int k = 0; k < 32; ++k) {
    int idx = t + k * 256;
    int lh = idx >> 7, w = idx & 127;
    int h = h0 + lh;
    float ax = 0.f;
    #pragma unroll
    for (int o = -3; o <= 4; ++o) {
      int j = h + o;
      if (j >= 0 && j <= 128) {
        int jr = (j == 128) ? 126 : j;
        ax += sP[jr - h0 + 3][w];
      }
    }
    float ay = 0.f;
    #pragma unroll
    for (int o = -3; o <= 4; ++o) {
      int j = w + o;
      if (j >= 0 && j <= 128) {
        int jr = (j == 128) ? 126 : j;
        ay += sP[lh + 3][jr];
      }
    }
    size_t gi = pbase + (size_t)h * 128 + w;
    loc[gi] = fmaf(ax + ay, 0.125f, loc[gi]);
  }
}

// ---------------------------------------------------------------------------
// Depthwise 8x8 conv on reflect(+1)-padded combined, zero pad 3.
// ---------------------------------------------------------------------------
__global__ __launch_bounds__(256) void k_dw(
    const float* __restrict__ comb, const float* __restrict__ wdw,
    float* __restrict__ out)
{
  __shared__ __align__(16) float sZ[71][140];
  __shared__ float sWd[64];
  const int t = threadIdx.x;
  const int plane = blockIdx.x >> 1;
  const int cch = plane & 255;
  const int h0 = (blockIdx.x & 1) * 64;
  const size_t pbase = (size_t)plane * HW;
  if (t < 64) sWd[t] = wdw[cch * 64 + t];
  for (int k = 0; k < 38; ++k) {
    int idx = t + k * 256;
    if (idx < 71 * 136) {
      int u = idx / 136, vc = idx - u * 136;
      int g = h0 - 3 + u;
      if (g >= 0 && g <= 128) {
        int bb = vc - 3;
        float v = 0.f;
        if (bb >= 0 && bb <= 128) {
          int gr = (g == 128) ? 126 : g;
          int br = (bb == 128) ? 126 : bb;
          v = comb[pbase + gr * 128 + br];
        }
        sZ[u][vc] = v;
      }
    }
  }
  __syncthreads();
  const int wg = t & 7, hl = t >> 3;
  const int w0 = wg * 16;
  float acc[2][16];
  #pragma unroll
  for (int a = 0; a < 2; ++a)
    #pragma unroll
    for (int p = 0; p < 16; ++p) acc[a][p] = 0.f;
  #pragma unroll 1
  for (int i = 0; i < 8; ++i) {
    float wrow[8];
    *(float4*)&wrow[0] = *(const float4*)&sWd[i * 8];
    *(float4*)&wrow[4] = *(const float4*)&sWd[i * 8 + 4];
    #pragma unroll
    for (int hi = 0; hi < 2; ++hi) {
      int h = h0 + hl + 32 * hi;
      int u = h + i - 3;
      bool ok = (u >= 0 && u <= 128);
      int lr = ok ? (u - h0 + 3) : 0;
      const float* zr = &sZ[lr][w0];
      float win[24];
      *(float4*)&win[0]  = *(const float4*)(zr);
      *(float4*)&win[4]  = *(const float4*)(zr + 4);
      *(float4*)&win[8]  = *(const float4*)(zr + 8);
      *(float4*)&win[12] = *(const float4*)(zr + 12);
      *(float4*)&win[16] = *(const float4*)(zr + 16);
      *(float4*)&win[20] = *(const float4*)(zr + 20);
      float m = ok ? 1.f : 0.f;
      float wv[8];
      #pragma unroll
      for (int j = 0; j < 8; ++j) wv[j] = wrow[j] * m;
      #pragma unroll
      for (int p = 0; p < 16; ++p)
        #pragma unroll
        for (int j = 0; j < 8; ++j)
          acc[hi][p] = fmaf(wv[j], win[p + j], acc[hi][p]);
    }
  }
  #pragma unroll
  for (int hi = 0; hi < 2; ++hi) {
    int h = h0 + hl + 32 * hi;
    float* dst = out + pbase + (size_t)h * 128 + w0;
    float4 o0 = {acc[hi][0],  acc[hi][1],  acc[hi][2],  acc[hi][3]};
    float4 o1 = {acc[hi][4],  acc[hi][5],  acc[hi][6],  acc[hi][7]};
    float4 o2 = {acc[hi][8],  acc[hi][9],  acc[hi][10], acc[hi][11]};
    float4 o3 = {acc[hi][12], acc[hi][13], acc[hi][14], acc[hi][15]};
    *(float4*)(dst)      = o0;
    *(float4*)(dst + 4)  = o1;
    *(float4*)(dst + 8)  = o2;
    *(float4*)(dst + 12) = o3;
  }
}

} // namespace

extern "C" void kernel_launch(void* const* d_in, const int* in_sizes, int n_in,
                              void* d_out, int out_size, void* d_ws, size_t ws_size,
                              hipStream_t stream)
{
  const float* x      = (const float*)d_in[0];
  const float* w_pre  = (const float*)d_in[1];
  const float* bn_pre = (const float*)d_in[2];
  const float* w_l1   = (const float*)d_in[3];
  const float* bn_l1  = (const float*)d_in[4];
  const float* w_l2   = (const float*)d_in[5];
  const float* bn_l2  = (const float*)d_in[6];
  const float* w_l3   = (const float*)d_in[7];
  const float* bn_l3  = (const float*)d_in[8];
  const float* w_qkv  = (const float*)d_in[9];
  const float* rpb    = (const float*)d_in[10];
  const float* w_dw   = (const float*)d_in[11];
  const float* w_pw   = (const float*)d_in[12];
  const float* bn_pj  = (const float*)d_in[13];
  float* out = (float*)d_out;

  char* base = (char*)d_ws;
  uint16_t* preT  = (uint16_t*)base;                          // 64 MiB NHWC bf16 pre; later attn out
  float*    bufB  = (float*)(base + (size_t)67108864);        // 128 MiB fp32 local/combined
  uint16_t* bufQ  = (uint16_t*)(base + (size_t)201326592);    // 192 MiB bf16 qkv; later dw out
  uint16_t* attnO = preT;
  float*    bufDw = (float*)bufQ;

  dim3 blk(256);
  // 1. pre 1x1 conv + bn -> NHWC bf16
  k_gemm1x1<true, true, true><<<dim3(1024, 2), blk, 0, stream>>>(x, w_pre, bn_pre, 256, nullptr, preT);
  // 2. dilated 3x3 convs + bn (MFMA) -> bufB fp32 NCHW
  k_dilconv_mfma<1, 86><<<dim3(32, 2, 8), blk, 0, stream>>>(preT, w_l1, bn_l1, bufB, 0, 0);
  k_dilconv_mfma<2, 86><<<dim3(32, 2, 8), blk, 0, stream>>>(preT, w_l2, bn_l2, bufB, 86, 80);
  k_dilconv_mfma<3, 84><<<dim3(32, 2, 8), blk, 0, stream>>>(preT, w_l3, bn_l3, bufB, 172, 160);
  // 3. qkv 1x1 conv -> bufQ bf16 NCHW
  k_gemm1x1<false, true, false><<<dim3(1024, 6), blk, 0, stream>>>(x, w_qkv, nullptr, 768, nullptr, bufQ);
  // 4. windowed attention -> attnO bf16 (overwrites preT region; safe, dilconv done)
  k_attn<<<dim3(256, 8), blk, 0, stream>>>(bufQ, rpb, attnO);
  // 5. pools + residual combine (in-place on bufB)
  k_pool<<<dim3(4096), blk, 0, stream>>>(attnO, bufB);
  // 6. depthwise 8x8 -> bufDw (overwrites bufQ region; safe, attn done)
  k_dw<<<dim3(4096), blk, 0, stream>>>(bufB, w_dw, bufDw);
  // 7. pw 1x1 conv + bn -> out
  k_gemm1x1<true, false, false><<<dim3(1024, 2), blk, 0, stream>>>(bufDw, w_pw, bn_pj, 256, out, nullptr);

  (void)in_sizes; (void)n_in; (void)out_size; (void)ws_size;
}

// Round 4
// 1331.331 us; speedup vs baseline: 3.2707x; 1.3960x over previous
//
#include <hip/hip_runtime.h>
#include <hip/hip_bf16.h>
#include <cstdint>
#include <cstddef>

namespace {

constexpr int HW = 16384;   // 128*128

typedef short vec8s __attribute__((ext_vector_type(8)));
typedef float f32x4 __attribute__((ext_vector_type(4)));

__device__ __forceinline__ float u2f(uint32_t u){ union { uint32_t u; float f; } v; v.u = u; return v.f; }
__device__ __forceinline__ uint32_t f2u(float f){ union { float f; uint32_t u; } v; v.f = f; return v.u; }
__device__ __forceinline__ uint16_t f2bf(float f){
  uint32_t u = f2u(f);
  u += 0x7fffu + ((u >> 16) & 1u);   // round-to-nearest-even
  return (uint16_t)(u >> 16);
}
__device__ __forceinline__ void unpack2(uint32_t w, float& lo, float& hi){
  lo = u2f(w << 16);
  hi = u2f(w & 0xffff0000u);
}

// ---------------------------------------------------------------------------
// Cast x (NCHW fp32) -> xT (NHWC bf16). Block = one (b, row): 128 px x 256 ci.
// LDS transpose, pad 129 to kill bank conflicts.
// ---------------------------------------------------------------------------
__global__ __launch_bounds__(256) void k_cast(
    const float* __restrict__ x, uint16_t* __restrict__ xT)
{
  __shared__ float sF[64][129];
  const int t = threadIdx.x;
  const int b = blockIdx.x >> 7;
  const int y = blockIdx.x & 127;
  const size_t rowoff = (size_t)y * 128;
  for (int cc = 0; cc < 4; ++cc) {
    const int cic0 = cc * 64;
    #pragma unroll
    for (int k = 0; k < 8; ++k) {
      int e = t + k * 256;          // 0..2047
      int ci = e >> 5;              // 0..63
      int pxq = (e & 31) * 4;
      float4 v = *(const float4*)(x + (size_t)(b * 256 + cic0 + ci) * HW + rowoff + pxq);
      sF[ci][pxq] = v.x; sF[ci][pxq+1] = v.y; sF[ci][pxq+2] = v.z; sF[ci][pxq+3] = v.w;
    }
    __syncthreads();
    {
      int px = t >> 1, h = t & 1;
      __align__(16) uint16_t tmp[32];
      #pragma unroll
      for (int j = 0; j < 32; ++j) tmp[j] = f2bf(sF[h * 32 + j][px]);
      uint16_t* dst = xT + ((size_t)b * HW + rowoff + px) * 256 + cic0 + h * 32;
      *(uint4*)(dst)      = *(uint4*)&tmp[0];
      *(uint4*)(dst + 8)  = *(uint4*)&tmp[8];
      *(uint4*)(dst + 16) = *(uint4*)&tmp[16];
      *(uint4*)(dst + 24) = *(uint4*)&tmp[24];
    }
    __syncthreads();
  }
}

// ---------------------------------------------------------------------------
// 1x1 conv via bf16 MFMA: out[co][px] = sum_ci W[co][ci] * xT[px][ci].
// Input xT NHWC bf16; W fp32 (bf16-cast on stage). K=256.
// Block 256 thr (4 waves): BM=64 co, BN=128 px (wave w owns px [32w,32w+32)).
// A: row=l&15 (co), k=(l>>4)*8+j.  B: col=l&15 (px), same k.
// D: col=l&15 (px), row=(l>>4)*4+r (co).   [verified by dilconv r3]
// NHWC_OUT: bf16 [b][px][co] (+BN) for pre; else bf16 NCHW for qkv.
// ---------------------------------------------------------------------------
template<bool DO_BN, bool NHWC_OUT>
__global__ __launch_bounds__(256) void k_gemm_mfma(
    const uint16_t* __restrict__ xT, const float* __restrict__ wmat,
    const float* __restrict__ bnp, int M,
    uint16_t* __restrict__ outb)
{
  __shared__ __align__(16) uint16_t sW[64][40];
  __shared__ __align__(16) uint16_t sX[128][40];
  const int t = threadIdx.x;
  const int b   = blockIdx.x >> 7;
  const int px0 = (blockIdx.x & 127) << 7;
  const int co0 = blockIdx.y * 64;
  const int l = t & 63, w = t >> 6;
  const int l15 = l & 15, koct = l >> 4;
  const int pxw = w * 32;

  f32x4 acc[4][2];
  #pragma unroll
  for (int cf = 0; cf < 4; ++cf)
    #pragma unroll
    for (int pf = 0; pf < 2; ++pf) acc[cf][pf] = (f32x4){0.f,0.f,0.f,0.f};

  const int sco = t >> 2, soc = t & 3;        // W stage: co, k-octet
  const int spx = t >> 1, sh = t & 1;         // X stage: px, 16-ci half
  const float* wsrc = wmat + (size_t)(co0 + sco) * 256 + soc * 8;
  const uint16_t* xsrc = xT + ((size_t)b * HW + px0 + spx) * 256 + sh * 16;

  for (int kc = 0; kc < 8; ++kc) {
    {
      float4 a  = *(const float4*)(wsrc + kc * 32);
      float4 b2 = *(const float4*)(wsrc + kc * 32 + 4);
      uint16_t* dst = &sW[sco][soc * 8];
      dst[0] = f2bf(a.x);  dst[1] = f2bf(a.y);  dst[2] = f2bf(a.z);  dst[3] = f2bf(a.w);
      dst[4] = f2bf(b2.x); dst[5] = f2bf(b2.y); dst[6] = f2bf(b2.z); dst[7] = f2bf(b2.w);
    }
    {
      const uint16_t* src = xsrc + kc * 32;
      uint4 v0 = *(const uint4*)src;
      uint4 v1 = *(const uint4*)(src + 8);
      *(uint4*)&sX[spx][sh * 16]     = v0;
      *(uint4*)&sX[spx][sh * 16 + 8] = v1;
    }
    __syncthreads();
    vec8s bf0 = *(const vec8s*)&sX[pxw + l15][koct * 8];
    vec8s bf1 = *(const vec8s*)&sX[pxw + 16 + l15][koct * 8];
    #pragma unroll
    for (int cf = 0; cf < 4; ++cf) {
      vec8s af = *(const vec8s*)&sW[cf * 16 + l15][koct * 8];
      acc[cf][0] = __builtin_amdgcn_mfma_f32_16x16x32_bf16(af, bf0, acc[cf][0], 0, 0, 0);
      acc[cf][1] = __builtin_amdgcn_mfma_f32_16x16x32_bf16(af, bf1, acc[cf][1], 0, 0, 0);
    }
    __syncthreads();
  }

  const int row4 = l >> 4;
  #pragma unroll
  for (int cf = 0; cf < 4; ++cf) {
    float scv[4], shv[4];
    #pragma unroll
    for (int r = 0; r < 4; ++r) {
      scv[r] = 1.f; shv[r] = 0.f;
      if constexpr (DO_BN) {
        int c = co0 + cf * 16 + row4 * 4 + r;
        float g = bnp[c], be = bnp[M + c], mu = bnp[2 * M + c], va = bnp[3 * M + c];
        scv[r] = g * rsqrtf(va + 1e-5f);
        shv[r] = be - mu * scv[r];
      }
    }
    #pragma unroll
    for (int pf = 0; pf < 2; ++pf) {
      int px = px0 + pxw + pf * 16 + l15;
      if constexpr (NHWC_OUT) {
        __align__(8) uint16_t pk[4];
        #pragma unroll
        for (int r = 0; r < 4; ++r)
          pk[r] = f2bf(fmaf(acc[cf][pf][r], scv[r], shv[r]));
        *(uint2*)(outb + ((size_t)b * HW + px) * 256 + co0 + cf * 16 + row4 * 4) =
            *(uint2*)pk;
      } else {
        #pragma unroll
        for (int r = 0; r < 4; ++r) {
          int c = co0 + cf * 16 + row4 * 4 + r;
          outb[(size_t)(b * M + c) * HW + px] =
              f2bf(fmaf(acc[cf][pf][r], scv[r], shv[r]));
        }
      }
    }
  }
}

// ---------------------------------------------------------------------------
// 1x1 conv as VALU GEMM (fp32 in, used for pw only now).
// ---------------------------------------------------------------------------
template<bool DO_BN>
__global__ __launch_bounds__(256) void k_gemm1x1(
    const float* __restrict__ in, const float* __restrict__ wmat,
    const float* __restrict__ bnp, int M, float* __restrict__ outf)
{
  __shared__ __align__(16) float sW[16][128];
  __shared__ __align__(16) float sX[16][128];
  const int t = threadIdx.x;
  const int b  = blockIdx.x >> 7;
  const int p0 = (blockIdx.x & 127) << 7;
  const int co0 = blockIdx.y << 7;
  const int cog = t >> 4, pxg = t & 15;

  float acc[8][8];
  #pragma unroll
  for (int i = 0; i < 8; ++i)
    #pragma unroll
    for (int j = 0; j < 8; ++j) acc[i][j] = 0.f;

  const int wr = t >> 1, whf = (t & 1) << 3;
  const float* wsrc = wmat + (co0 + wr) * 256 + whf;
  const int xcc = t >> 4, xpp = (t & 15) << 3;
  const float* xsrc = in + (size_t)(b * 256 + xcc) * HW + p0 + xpp;

  for (int kc = 0; kc < 16; ++kc) {
    float4 wa = *(const float4*)(wsrc + kc * 16);
    float4 wb = *(const float4*)(wsrc + kc * 16 + 4);
    float4 xa = *(const float4*)(xsrc + (size_t)kc * 16 * HW);
    float4 xb = *(const float4*)(xsrc + (size_t)kc * 16 * HW + 4);
    sW[whf + 0][wr] = wa.x; sW[whf + 1][wr] = wa.y;
    sW[whf + 2][wr] = wa.z; sW[whf + 3][wr] = wa.w;
    sW[whf + 4][wr] = wb.x; sW[whf + 5][wr] = wb.y;
    sW[whf + 6][wr] = wb.z; sW[whf + 7][wr] = wb.w;
    *(float4*)&sX[xcc][xpp]     = xa;
    *(float4*)&sX[xcc][xpp + 4] = xb;
    __syncthreads();
    #pragma unroll
    for (int cc = 0; cc < 16; ++cc) {
      float4 wfa = *(const float4*)&sW[cc][cog * 8];
      float4 wfb = *(const float4*)&sW[cc][cog * 8 + 4];
      float4 xfa = *(const float4*)&sX[cc][pxg * 8];
      float4 xfb = *(const float4*)&sX[cc][pxg * 8 + 4];
      const float wf[8] = {wfa.x,wfa.y,wfa.z,wfa.w, wfb.x,wfb.y,wfb.z,wfb.w};
      const float xf[8] = {xfa.x,xfa.y,xfa.z,xfa.w, xfb.x,xfb.y,xfb.z,xfb.w};
      #pragma unroll
      for (int i = 0; i < 8; ++i)
        #pragma unroll
        for (int j = 0; j < 8; ++j) acc[i][j] = fmaf(wf[i], xf[j], acc[i][j]);
    }
    __syncthreads();
  }

  const int cbase = co0 + cog * 8;
  const int px = p0 + pxg * 8;
  #pragma unroll
  for (int i = 0; i < 8; ++i) {
    const int c = cbase + i;
    float sc = 1.f, sh = 0.f;
    if constexpr (DO_BN) {
      float g = bnp[c], be = bnp[M + c], mu = bnp[2 * M + c], va = bnp[3 * M + c];
      sc = g * rsqrtf(va + 1e-5f);
      sh = be - mu * sc;
    }
    float v[8];
    #pragma unroll
    for (int j = 0; j < 8; ++j) v[j] = fmaf(acc[i][j], sc, sh);
    const size_t dst = (size_t)(b * M + c) * HW + px;
    float4 o0 = {v[0], v[1], v[2], v[3]};
    float4 o1 = {v[4], v[5], v[6], v[7]};
    *(float4*)(outf + dst)     = o0;
    *(float4*)(outf + dst + 4) = o1;
  }
}

// ---------------------------------------------------------------------------
// Dilated 3x3 conv + BN via bf16 MFMA implicit GEMM (unchanged from r3).
// ---------------------------------------------------------------------------
template<int DIL, int CG>
__global__ __launch_bounds__(256) void k_dilconv_mfma(
    const uint16_t* __restrict__ preT, const float* __restrict__ wt,
    const float* __restrict__ bnp, float* __restrict__ out,
    int cb, int cb_al)
{
  constexpr int R = 8 + 2 * DIL;
  constexpr int C = 64 + 2 * DIL;
  constexpr int NPOS = R * C;
  constexpr int NIT = (NPOS + 255) / 256;
  __shared__ __align__(16) uint16_t sX[NPOS * 16];
  __shared__ __align__(16) uint16_t sW[10 * 50 * 16];

  const int t = threadIdx.x;
  const int rt    = blockIdx.x >> 1;
  const int ctile = blockIdx.x & 1;
  const int ct2   = blockIdx.y;
  const int b     = blockIdx.z;
  const int y0 = rt * 8, x0 = ctile * 64;
  const int l = t & 63, w = t >> 6;
  const int l15 = l & 15, oct = (l >> 4) & 1, half = l >> 5;
  const int rbase = w * 2;

  f32x4 acc[3][8];
  #pragma unroll
  for (int cf = 0; cf < 3; ++cf)
    #pragma unroll
    for (int q = 0; q < 8; ++q) acc[cf][q] = (f32x4){0.f,0.f,0.f,0.f};

  for (int kc = 0; kc < 6; ++kc) {
    #pragma unroll
    for (int i = 0; i < 3; ++i) {
      int pair = t + i * 256;
      int co = pair >> 4, ci = pair & 15;
      int cog = ct2 * 48 + co;
      int c = cb_al + kc * 16 + ci;
      bool ok = (cog < CG) && (c >= cb) && (c < cb + CG);
      size_t widx = ok ? ((size_t)cog * (size_t)CG + (size_t)(c - cb)) * 9u
                       : (size_t)0;
      const float* wp = wt + widx;
      uint16_t* dst = &sW[co * 16 + ci];
      #pragma unroll
      for (int tap = 0; tap < 9; ++tap)
        dst[tap * 800] = ok ? f2bf(wp[tap]) : (uint16_t)0;
      dst[9 * 800] = 0;
    }
    #pragma unroll
    for (int i = 0; i < NIT; ++i) {
      int p = t + i * 256;
      if (p < NPOS) {
        int row = p / C, col = p % C;
        int gy = y0 + row - DIL, gx = x0 + col - DIL;
        uint4 va = {0,0,0,0}, vb = {0,0,0,0};
        if ((unsigned)gy < 128u && (unsigned)gx < 128u) {
          const uint4* src = (const uint4*)(preT +
              (((size_t)b * HW + gy * 128 + gx) * 256 + cb_al + kc * 16));
          va = src[0]; vb = src[1];
        }
        uint4* dst = (uint4*)&sX[p * 16];
        dst[0] = va; dst[1] = vb;
      }
    }
    __syncthreads();

    #pragma unroll
    for (int s = 0; s < 5; ++s) {
      const int tap0 = 2 * s, tap1 = 2 * s + 1;
      const int dy0 = tap0 / 3, dx0 = tap0 % 3;
      const int dy1 = (tap1 <= 8) ? tap1 / 3 : 2;
      const int dx1 = (tap1 <= 8) ? tap1 % 3 : 2;
      const int dy = half ? dy1 : dy0;
      const int dx = half ? dx1 : dx0;
      const int atap = tap0 + half;
      vec8s a0 = *(const vec8s*)&sW[(atap * 50 + 0  + l15) * 16 + oct * 8];
      vec8s a1 = *(const vec8s*)&sW[(atap * 50 + 16 + l15) * 16 + oct * 8];
      vec8s a2 = *(const vec8s*)&sW[(atap * 50 + 32 + l15) * 16 + oct * 8];
      #pragma unroll
      for (int rs = 0; rs < 2; ++rs) {
        const int rowin = rbase + rs + dy * DIL;
        #pragma unroll
        for (int c4 = 0; c4 < 4; ++c4) {
          const int colin = c4 * 16 + l15 + dx * DIL;
          vec8s bf = *(const vec8s*)&sX[(rowin * C + colin) * 16 + oct * 8];
          acc[0][rs*4+c4] = __builtin_amdgcn_mfma_f32_16x16x32_bf16(a0, bf, acc[0][rs*4+c4], 0, 0, 0);
          acc[1][rs*4+c4] = __builtin_amdgcn_mfma_f32_16x16x32_bf16(a1, bf, acc[1][rs*4+c4], 0, 0, 0);
          acc[2][rs*4+c4] = __builtin_amdgcn_mfma_f32_16x16x32_bf16(a2, bf, acc[2][rs*4+c4], 0, 0, 0);
        }
      }
    }
    __syncthreads();
  }

  const int row4 = (l >> 4);
  #pragma unroll
  for (int cf = 0; cf < 3; ++cf) {
    #pragma unroll
    for (int r = 0; r < 4; ++r) {
      int c_loc = ct2 * 48 + cf * 16 + row4 * 4 + r;
      if (c_loc < CG) {
        int cg = cb + c_loc;
        float g = bnp[c_loc], be = bnp[CG + c_loc];
        float mu = bnp[2 * CG + c_loc], va = bnp[3 * CG + c_loc];
        float scv = g * rsqrtf(va + 1e-5f);
        float shv = be - mu * scv;
        #pragma unroll
        for (int rs = 0; rs < 2; ++rs) {
          int y = y0 + rbase + rs;
          #pragma unroll
          for (int c4 = 0; c4 < 4; ++c4) {
            int x = x0 + c4 * 16 + l15;
            out[(size_t)(b * 256 + cg) * HW + y * 128 + x] =
                fmaf(acc[cf][rs*4+c4][r], scv, shv);
          }
        }
      }
    }
  }
}

// ---------------------------------------------------------------------------
// Windowed attention (unchanged from r3): qkv bf16 NCHW -> out bf16 NCHW.
// ---------------------------------------------------------------------------
__global__ __launch_bounds__(256) void k_attn(
    const uint16_t* __restrict__ qkv, const float* __restrict__ rpb,
    uint16_t* __restrict__ outp)
{
  __shared__ __align__(16) float sQ[16][64];
  __shared__ __align__(16) float sK[16][64];
  __shared__ __align__(16) uint16_t sV[64][16];
  __shared__ __align__(16) float sD[64][68];
  __shared__ float srpb[225];
  const int t  = threadIdx.x;
  const int b  = blockIdx.y;
  const int wy = blockIdx.x >> 4, wx = blockIdx.x & 15;
  const int wbase = (wy * 8) * 128 + wx * 8;

  for (int n = 0; n < 16; ++n) {
    if (t < 225) srpb[t] = rpb[t * 16 + n];
    {
      int tt = t & 127;
      int dd = tt >> 3, r = tt & 7;
      int ch = ((t < 128) ? 0 : 256) + n * 16 + dd;
      const uint16_t* src = qkv + (size_t)(b * 768 + ch) * HW + wbase + r * 128;
      uint4 w4 = *(const uint4*)src;
      float f[8];
      unpack2(w4.x, f[0], f[1]); unpack2(w4.y, f[2], f[3]);
      unpack2(w4.z, f[4], f[5]); unpack2(w4.w, f[6], f[7]);
      float* dst = (t < 128) ? &sQ[dd][r * 8] : &sK[dd][r * 8];
      float4 a = {f[0],f[1],f[2],f[3]}, bq = {f[4],f[5],f[6],f[7]};
      *(float4*)dst = a; *(float4*)(dst + 4) = bq;
      if (t < 128) {
        const uint16_t* vs = qkv + (size_t)(b * 768 + 512 + n * 16 + dd) * HW + wbase + r * 128;
        uint4 v4 = *(const uint4*)vs;
        const uint16_t* ve = (const uint16_t*)&v4;
        #pragma unroll
        for (int c = 0; c < 8; ++c) sV[r * 8 + c][dd] = ve[c];
      }
    }
    __syncthreads();
    {
      const int ig = t >> 4, jg = t & 15;
      const int i0 = ig * 4, j0 = jg * 4;
      float a[4][4];
      #pragma unroll
      for (int x = 0; x < 4; ++x)
        #pragma unroll
        for (int y = 0; y < 4; ++y) a[x][y] = 0.f;
      #pragma unroll
      for (int dd = 0; dd < 16; ++dd) {
        float4 qv = *(const float4*)&sQ[dd][i0];
        float4 kv = *(const float4*)&sK[dd][j0];
        const float qa[4] = {qv.x, qv.y, qv.z, qv.w};
        const float ka[4] = {kv.x, kv.y, kv.z, kv.w};
        #pragma unroll
        for (int x = 0; x < 4; ++x)
          #pragma unroll
          for (int y = 0; y < 4; ++y) a[x][y] = fmaf(qa[x], ka[y], a[x][y]);
      }
      #pragma unroll
      for (int x = 0; x < 4; ++x) {
        float dv[4];
        #pragma unroll
        for (int y = 0; y < 4; ++y) {
          int ii = i0 + x, jj = j0 + y;
          int rel = ((ii >> 3) - (jj >> 3) + 7) * 15 + ((ii & 7) - (jj & 7) + 7);
          dv[y] = fmaf(a[x][y], 0.25f, srpb[rel]);
        }
        float4 o = {dv[0], dv[1], dv[2], dv[3]};
        *(float4*)&sD[i0 + x][j0] = o;
      }
    }
    __syncthreads();
    {
      const int i = t >> 2, q4 = t & 3;
      float p[16];
      *(float4*)&p[0]  = *(const float4*)&sD[i][q4 * 16];
      *(float4*)&p[4]  = *(const float4*)&sD[i][q4 * 16 + 4];
      *(float4*)&p[8]  = *(const float4*)&sD[i][q4 * 16 + 8];
      *(float4*)&p[12] = *(const float4*)&sD[i][q4 * 16 + 12];
      float mx = p[0];
      #pragma unroll
      for (int jj = 1; jj < 16; ++jj) mx = fmaxf(mx, p[jj]);
      mx = fmaxf(mx, __shfl_xor(mx, 1));
      mx = fmaxf(mx, __shfl_xor(mx, 2));
      float s = 0.f;
      #pragma unroll
      for (int jj = 0; jj < 16; ++jj) { p[jj] = __expf(p[jj] - mx); s += p[jj]; }
      s += __shfl_xor(s, 1);
      s += __shfl_xor(s, 2);
      const float sinv = 1.f / s;
      float part[16];
      #pragma unroll
      for (int dd = 0; dd < 16; ++dd) part[dd] = 0.f;
      #pragma unroll
      for (int jj = 0; jj < 16; ++jj) {
        const uint16_t* vr = &sV[q4 * 16 + jj][0];
        uint4 lo = *(const uint4*)vr;
        uint4 hi = *(const uint4*)(vr + 8);
        float vv[16];
        unpack2(lo.x, vv[0], vv[1]);   unpack2(lo.y, vv[2], vv[3]);
        unpack2(lo.z, vv[4], vv[5]);   unpack2(lo.w, vv[6], vv[7]);
        unpack2(hi.x, vv[8], vv[9]);   unpack2(hi.y, vv[10], vv[11]);
        unpack2(hi.z, vv[12], vv[13]); unpack2(hi.w, vv[14], vv[15]);
        #pragma unroll
        for (int dd = 0; dd < 16; ++dd) part[dd] = fmaf(p[jj], vv[dd], part[dd]);
      }
      #pragma unroll
      for (int dd = 0; dd < 16; ++dd) {
        part[dd] += __shfl_xor(part[dd], 1);
        part[dd] += __shfl_xor(part[dd], 2);
      }
      const int r = i >> 3, c = i & 7;
      uint16_t* dst = outp + (size_t)(b * 256 + n * 16 + q4 * 4) * HW + wbase + r * 128 + c;
      #pragma unroll
      for (int m2 = 0; m2 < 4; ++m2) dst[(size_t)m2 * HW] = f2bf(part[q4 * 4 + m2] * sinv);
    }
    __syncthreads();
  }
}

// ---------------------------------------------------------------------------
// combined = avgpool_v(attn) + avgpool_h(attn) + local (in-place into loc)
// ---------------------------------------------------------------------------
__global__ __launch_bounds__(256) void k_pool(
    const uint16_t* __restrict__ attnb, float* __restrict__ loc)
{
  __shared__ __align__(16) float sP[71][132];
  const int t = threadIdx.x;
  const int plane = blockIdx.x >> 1;
  const int h0 = (blockIdx.x & 1) * 64;
  const size_t pbase = (size_t)plane * HW;
  for (int k = 0; k < 5; ++k) {
    int idx = t + k * 256;
    if (idx < 71 * 16) {
      int lr = idx >> 4, c8 = (idx & 15) * 8;
      int g = h0 - 3 + lr;
      if (g >= 0 && g <= 127) {
        uint4 v4 = *(const uint4*)(attnb + pbase + (size_t)g * 128 + c8);
        float f[8];
        unpack2(v4.x, f[0], f[1]); unpack2(v4.y, f[2], f[3]);
        unpack2(v4.z, f[4], f[5]); unpack2(v4.w, f[6], f[7]);
        #pragma unroll
        for (int j = 0; j < 8; ++j) sP[lr][c8 + j] = f[j];
      }
    }
  }
  __syncthreads();
  for (int k = 0; k < 32; ++k) {
    int idx = t + k * 256;
    int lh = idx >> 7, w = idx & 127;
    int h = h0 + lh;
    float ax = 0.f;
    #pragma unroll
    for (int o = -3; o <= 4; ++o) {
      int j = h + o;
      if (j >= 0 && j <= 128) {
        int jr = (j == 128) ? 126 : j;
        ax += sP[jr - h0 + 3][w];
      }
    }
    float ay = 0.f;
    #pragma unroll
    for (int o = -3; o <= 4; ++o) {
      int j = w + o;
      if (j >= 0 && j <= 128) {
        int jr = (j == 128) ? 126 : j;
        ay += sP[lh + 3][jr];
      }
    }
    size_t gi = pbase + (size_t)h * 128 + w;
    loc[gi] = fmaf(ax + ay, 0.125f, loc[gi]);
  }
}

// ---------------------------------------------------------------------------
// Depthwise 8x8 conv on reflect(+1)-padded combined, zero pad 3.
// ---------------------------------------------------------------------------
__global__ __launch_bounds__(256) void k_dw(
    const float* __restrict__ comb, const float* __restrict__ wdw,
    float* __restrict__ out)
{
  __shared__ __align__(16) float sZ[71][140];
  __shared__ float sWd[64];
  const int t = threadIdx.x;
  const int plane = blockIdx.x >> 1;
  const int cch = plane & 255;
  const int h0 = (blockIdx.x & 1) * 64;
  const size_t pbase = (size_t)plane * HW;
  if (t < 64) sWd[t] = wdw[cch * 64 + t];
  for (int k = 0; k < 38; ++k) {
    int idx = t + k * 256;
    if (idx < 71 * 136) {
      int u = idx / 136, vc = idx - u * 136;
      int g = h0 - 3 + u;
      if (g >= 0 && g <= 128) {
        int bb = vc - 3;
        float v = 0.f;
        if (bb >= 0 && bb <= 128) {
          int gr = (g == 128) ? 126 : g;
          int br = (bb == 128) ? 126 : bb;
          v = comb[pbase + gr * 128 + br];
        }
        sZ[u][vc] = v;
      }
    }
  }
  __syncthreads();
  const int wg = t & 7, hl = t >> 3;
  const int w0 = wg * 16;
  float acc[2][16];
  #pragma unroll
  for (int a = 0; a < 2; ++a)
    #pragma unroll
    for (int p = 0; p < 16; ++p) acc[a][p] = 0.f;
  #pragma unroll 1
  for (int i = 0; i < 8; ++i) {
    float wrow[8];
    *(float4*)&wrow[0] = *(const float4*)&sWd[i * 8];
    *(float4*)&wrow[4] = *(const float4*)&sWd[i * 8 + 4];
    #pragma unroll
    for (int hi = 0; hi < 2; ++hi) {
      int h = h0 + hl + 32 * hi;
      int u = h + i - 3;
      bool ok = (u >= 0 && u <= 128);
      int lr = ok ? (u - h0 + 3) : 0;
      const float* zr = &sZ[lr][w0];
      float win[24];
      *(float4*)&win[0]  = *(const float4*)(zr);
      *(float4*)&win[4]  = *(const float4*)(zr + 4);
      *(float4*)&win[8]  = *(const float4*)(zr + 8);
      *(float4*)&win[12] = *(const float4*)(zr + 12);
      *(float4*)&win[16] = *(const float4*)(zr + 16);
      *(float4*)&win[20] = *(const float4*)(zr + 20);
      float m = ok ? 1.f : 0.f;
      float wv[8];
      #pragma unroll
      for (int j = 0; j < 8; ++j) wv[j] = wrow[j] * m;
      #pragma unroll
      for (int p = 0; p < 16; ++p)
        #pragma unroll
        for (int j = 0; j < 8; ++j)
          acc[hi][p] = fmaf(wv[j], win[p + j], acc[hi][p]);
    }
  }
  #pragma unroll
  for (int hi = 0; hi < 2; ++hi) {
    int h = h0 + hl + 32 * hi;
    float* dst = out + pbase + (size_t)h * 128 + w0;
    float4 o0 = {acc[hi][0],  acc[hi][1],  acc[hi][2],  acc[hi][3]};
    float4 o1 = {acc[hi][4],  acc[hi][5],  acc[hi][6],  acc[hi][7]};
    float4 o2 = {acc[hi][8],  acc[hi][9],  acc[hi][10], acc[hi][11]};
    float4 o3 = {acc[hi][12], acc[hi][13], acc[hi][14], acc[hi][15]};
    *(float4*)(dst)      = o0;
    *(float4*)(dst + 4)  = o1;
    *(float4*)(dst + 8)  = o2;
    *(float4*)(dst + 12) = o3;
  }
}

} // namespace

extern "C" void kernel_launch(void* const* d_in, const int* in_sizes, int n_in,
                              void* d_out, int out_size, void* d_ws, size_t ws_size,
                              hipStream_t stream)
{
  const float* x      = (const float*)d_in[0];
  const float* w_pre  = (const float*)d_in[1];
  const float* bn_pre = (const float*)d_in[2];
  const float* w_l1   = (const float*)d_in[3];
  const float* bn_l1  = (const float*)d_in[4];
  const float* w_l2   = (const float*)d_in[5];
  const float* bn_l2  = (const float*)d_in[6];
  const float* w_l3   = (const float*)d_in[7];
  const float* bn_l3  = (const float*)d_in[8];
  const float* w_qkv  = (const float*)d_in[9];
  const float* rpb    = (const float*)d_in[10];
  const float* w_dw   = (const float*)d_in[11];
  const float* w_pw   = (const float*)d_in[12];
  const float* bn_pj  = (const float*)d_in[13];
  float* out = (float*)d_out;

  char* base = (char*)d_ws;
  uint16_t* xT    = (uint16_t*)base;                          // 64 MiB NHWC bf16 x
  uint16_t* preT  = (uint16_t*)(base + (size_t)67108864);     // 64 MiB NHWC bf16 pre; later attn out
  float*    bufB  = (float*)(base + (size_t)134217728);       // 128 MiB fp32 local/combined
  uint16_t* bufQ  = (uint16_t*)(base + (size_t)268435456);    // 192 MiB bf16 qkv; later dw out
  uint16_t* attnO = preT;
  float*    bufDw = (float*)bufQ;

  dim3 blk(256);
  // 0. cast x -> NHWC bf16
  k_cast<<<dim3(1024), blk, 0, stream>>>(x, xT);
  // 1. pre 1x1 conv + bn -> NHWC bf16 (MFMA)
  k_gemm_mfma<true, true><<<dim3(1024, 4), blk, 0, stream>>>(xT, w_pre, bn_pre, 256, preT);
  // 2. dilated 3x3 convs + bn (MFMA) -> bufB fp32 NCHW
  k_dilconv_mfma<1, 86><<<dim3(32, 2, 8), blk, 0, stream>>>(preT, w_l1, bn_l1, bufB, 0, 0);
  k_dilconv_mfma<2, 86><<<dim3(32, 2, 8), blk, 0, stream>>>(preT, w_l2, bn_l2, bufB, 86, 80);
  k_dilconv_mfma<3, 84><<<dim3(32, 2, 8), blk, 0, stream>>>(preT, w_l3, bn_l3, bufB, 172, 160);
  // 3. qkv 1x1 conv -> bufQ bf16 NCHW (MFMA)
  k_gemm_mfma<false, false><<<dim3(1024, 12), blk, 0, stream>>>(xT, w_qkv, nullptr, 768, bufQ);
  // 4. windowed attention -> attnO bf16 (overwrites preT; safe, dilconv done)
  k_attn<<<dim3(256, 8), blk, 0, stream>>>(bufQ, rpb, attnO);
  // 5. pools + residual combine (in-place on bufB)
  k_pool<<<dim3(4096), blk, 0, stream>>>(attnO, bufB);
  // 6. depthwise 8x8 -> bufDw (overwrites bufQ; safe, attn done)
  k_dw<<<dim3(4096), blk, 0, stream>>>(bufB, w_dw, bufDw);
  // 7. pw 1x1 conv + bn -> out (VALU fp32)
  k_gemm1x1<true><<<dim3(1024, 2), blk, 0, stream>>>(bufDw, w_pw, bn_pj, 256, out);

  (void)in_sizes; (void)n_in; (void)out_size; (void)ws_size;
}

// Round 5
// 1288.390 us; speedup vs baseline: 3.3797x; 1.0333x over previous
//
#include <hip/hip_runtime.h>
#include <hip/hip_bf16.h>
#include <cstdint>
#include <cstddef>

namespace {

constexpr int HW = 16384;   // 128*128

typedef short vec8s __attribute__((ext_vector_type(8)));
typedef float f32x4 __attribute__((ext_vector_type(4)));

__device__ __forceinline__ float u2f(uint32_t u){ union { uint32_t u; float f; } v; v.u = u; return v.f; }
__device__ __forceinline__ uint32_t f2u(float f){ union { float f; uint32_t u; } v; v.f = f; return v.u; }
__device__ __forceinline__ uint16_t f2bf(float f){
  uint32_t u = f2u(f);
  u += 0x7fffu + ((u >> 16) & 1u);   // round-to-nearest-even
  return (uint16_t)(u >> 16);
}
__device__ __forceinline__ void unpack2(uint32_t w, float& lo, float& hi){
  lo = u2f(w << 16);
  hi = u2f(w & 0xffff0000u);
}

// ---------------------------------------------------------------------------
// Cast NCHW fp32 (256 ch) -> NHWC bf16. Block = one (b, row).
// ---------------------------------------------------------------------------
__global__ __launch_bounds__(256) void k_cast(
    const float* __restrict__ x, uint16_t* __restrict__ xT)
{
  __shared__ float sF[64][129];
  const int t = threadIdx.x;
  const int b = blockIdx.x >> 7;
  const int y = blockIdx.x & 127;
  const size_t rowoff = (size_t)y * 128;
  for (int cc = 0; cc < 4; ++cc) {
    const int cic0 = cc * 64;
    #pragma unroll
    for (int k = 0; k < 8; ++k) {
      int e = t + k * 256;
      int ci = e >> 5;
      int pxq = (e & 31) * 4;
      float4 v = *(const float4*)(x + (size_t)(b * 256 + cic0 + ci) * HW + rowoff + pxq);
      sF[ci][pxq] = v.x; sF[ci][pxq+1] = v.y; sF[ci][pxq+2] = v.z; sF[ci][pxq+3] = v.w;
    }
    __syncthreads();
    {
      int px = t >> 1, h = t & 1;
      __align__(16) uint16_t tmp[32];
      #pragma unroll
      for (int j = 0; j < 32; ++j) tmp[j] = f2bf(sF[h * 32 + j][px]);
      uint16_t* dst = xT + ((size_t)b * HW + rowoff + px) * 256 + cic0 + h * 32;
      *(uint4*)(dst)      = *(uint4*)&tmp[0];
      *(uint4*)(dst + 8)  = *(uint4*)&tmp[8];
      *(uint4*)(dst + 16) = *(uint4*)&tmp[16];
      *(uint4*)(dst + 24) = *(uint4*)&tmp[24];
    }
    __syncthreads();
  }
}

// ---------------------------------------------------------------------------
// 1x1 conv via bf16 MFMA. Input NHWC bf16, K=256, BM=64 co, BN=128 px.
// OUT_MODE 0: NHWC bf16 + BN (pre)
// OUT_MODE 2: NCHW fp32 + BN (pw -> d_out)
// OUT_MODE 3: qkv window layout bf16: [b][win][c(768)][p(64)]
// ---------------------------------------------------------------------------
template<int OUT_MODE>
__global__ __launch_bounds__(256) void k_gemm_mfma(
    const uint16_t* __restrict__ xT, const float* __restrict__ wmat,
    const float* __restrict__ bnp, int M,
    uint16_t* __restrict__ outb, float* __restrict__ outf)
{
  __shared__ __align__(16) uint16_t sW[64][40];
  __shared__ __align__(16) uint16_t sX[128][40];
  const int t = threadIdx.x;
  const int b   = blockIdx.x >> 7;
  const int yrow = blockIdx.x & 127;
  const int px0 = yrow << 7;
  const int co0 = blockIdx.y * 64;
  const int l = t & 63, w = t >> 6;
  const int l15 = l & 15, koct = l >> 4;
  const int pxw = w * 32;

  f32x4 acc[4][2];
  #pragma unroll
  for (int cf = 0; cf < 4; ++cf)
    #pragma unroll
    for (int pf = 0; pf < 2; ++pf) acc[cf][pf] = (f32x4){0.f,0.f,0.f,0.f};

  const int sco = t >> 2, soc = t & 3;
  const int spx = t >> 1, sh = t & 1;
  const float* wsrc = wmat + (size_t)(co0 + sco) * 256 + soc * 8;
  const uint16_t* xsrc = xT + ((size_t)b * HW + px0 + spx) * 256 + sh * 16;

  for (int kc = 0; kc < 8; ++kc) {
    {
      float4 a  = *(const float4*)(wsrc + kc * 32);
      float4 b2 = *(const float4*)(wsrc + kc * 32 + 4);
      uint16_t* dst = &sW[sco][soc * 8];
      dst[0] = f2bf(a.x);  dst[1] = f2bf(a.y);  dst[2] = f2bf(a.z);  dst[3] = f2bf(a.w);
      dst[4] = f2bf(b2.x); dst[5] = f2bf(b2.y); dst[6] = f2bf(b2.z); dst[7] = f2bf(b2.w);
    }
    {
      const uint16_t* src = xsrc + kc * 32;
      uint4 v0 = *(const uint4*)src;
      uint4 v1 = *(const uint4*)(src + 8);
      *(uint4*)&sX[spx][sh * 16]     = v0;
      *(uint4*)&sX[spx][sh * 16 + 8] = v1;
    }
    __syncthreads();
    vec8s bf0 = *(const vec8s*)&sX[pxw + l15][koct * 8];
    vec8s bf1 = *(const vec8s*)&sX[pxw + 16 + l15][koct * 8];
    #pragma unroll
    for (int cf = 0; cf < 4; ++cf) {
      vec8s af = *(const vec8s*)&sW[cf * 16 + l15][koct * 8];
      acc[cf][0] = __builtin_amdgcn_mfma_f32_16x16x32_bf16(af, bf0, acc[cf][0], 0, 0, 0);
      acc[cf][1] = __builtin_amdgcn_mfma_f32_16x16x32_bf16(af, bf1, acc[cf][1], 0, 0, 0);
    }
    __syncthreads();
  }

  const int row4 = l >> 4;
  #pragma unroll
  for (int cf = 0; cf < 4; ++cf) {
    float scv[4], shv[4];
    #pragma unroll
    for (int r = 0; r < 4; ++r) {
      scv[r] = 1.f; shv[r] = 0.f;
      if constexpr (OUT_MODE == 0 || OUT_MODE == 2) {
        int c = co0 + cf * 16 + row4 * 4 + r;
        float g = bnp[c], be = bnp[M + c], mu = bnp[2 * M + c], va = bnp[3 * M + c];
        scv[r] = g * rsqrtf(va + 1e-5f);
        shv[r] = be - mu * scv[r];
      }
    }
    #pragma unroll
    for (int pf = 0; pf < 2; ++pf) {
      int px = px0 + pxw + pf * 16 + l15;
      if constexpr (OUT_MODE == 0) {
        __align__(8) uint16_t pk[4];
        #pragma unroll
        for (int r = 0; r < 4; ++r)
          pk[r] = f2bf(fmaf(acc[cf][pf][r], scv[r], shv[r]));
        *(uint2*)(outb + ((size_t)b * HW + px) * 256 + co0 + cf * 16 + row4 * 4) =
            *(uint2*)pk;
      } else if constexpr (OUT_MODE == 2) {
        #pragma unroll
        for (int r = 0; r < 4; ++r) {
          int c = co0 + cf * 16 + row4 * 4 + r;
          outf[(size_t)(b * M + c) * HW + px] =
              fmaf(acc[cf][pf][r], scv[r], shv[r]);
        }
      } else {  // OUT_MODE == 3: window layout [b][win][c][p]
        int xcol = pxw + pf * 16 + l15;
        int win = (yrow >> 3) * 16 + (xcol >> 3);
        int p = (yrow & 7) * 8 + (xcol & 7);
        #pragma unroll
        for (int r = 0; r < 4; ++r) {
          int c = co0 + cf * 16 + row4 * 4 + r;
          outb[((size_t)(b * 256 + win) * 768 + c) * 64 + p] = f2bf(acc[cf][pf][r]);
        }
      }
    }
  }
}

// ---------------------------------------------------------------------------
// Dilated 3x3 conv + BN via bf16 MFMA implicit GEMM (unchanged from r3).
// ---------------------------------------------------------------------------
template<int DIL, int CG>
__global__ __launch_bounds__(256) void k_dilconv_mfma(
    const uint16_t* __restrict__ preT, const float* __restrict__ wt,
    const float* __restrict__ bnp, float* __restrict__ out,
    int cb, int cb_al)
{
  constexpr int R = 8 + 2 * DIL;
  constexpr int C = 64 + 2 * DIL;
  constexpr int NPOS = R * C;
  constexpr int NIT = (NPOS + 255) / 256;
  __shared__ __align__(16) uint16_t sX[NPOS * 16];
  __shared__ __align__(16) uint16_t sW[10 * 50 * 16];

  const int t = threadIdx.x;
  const int rt    = blockIdx.x >> 1;
  const int ctile = blockIdx.x & 1;
  const int ct2   = blockIdx.y;
  const int b     = blockIdx.z;
  const int y0 = rt * 8, x0 = ctile * 64;
  const int l = t & 63, w = t >> 6;
  const int l15 = l & 15, oct = (l >> 4) & 1, half = l >> 5;
  const int rbase = w * 2;

  f32x4 acc[3][8];
  #pragma unroll
  for (int cf = 0; cf < 3; ++cf)
    #pragma unroll
    for (int q = 0; q < 8; ++q) acc[cf][q] = (f32x4){0.f,0.f,0.f,0.f};

  for (int kc = 0; kc < 6; ++kc) {
    #pragma unroll
    for (int i = 0; i < 3; ++i) {
      int pair = t + i * 256;
      int co = pair >> 4, ci = pair & 15;
      int cog = ct2 * 48 + co;
      int c = cb_al + kc * 16 + ci;
      bool ok = (cog < CG) && (c >= cb) && (c < cb + CG);
      size_t widx = ok ? ((size_t)cog * (size_t)CG + (size_t)(c - cb)) * 9u
                       : (size_t)0;
      const float* wp = wt + widx;
      uint16_t* dst = &sW[co * 16 + ci];
      #pragma unroll
      for (int tap = 0; tap < 9; ++tap)
        dst[tap * 800] = ok ? f2bf(wp[tap]) : (uint16_t)0;
      dst[9 * 800] = 0;
    }
    #pragma unroll
    for (int i = 0; i < NIT; ++i) {
      int p = t + i * 256;
      if (p < NPOS) {
        int row = p / C, col = p % C;
        int gy = y0 + row - DIL, gx = x0 + col - DIL;
        uint4 va = {0,0,0,0}, vb = {0,0,0,0};
        if ((unsigned)gy < 128u && (unsigned)gx < 128u) {
          const uint4* src = (const uint4*)(preT +
              (((size_t)b * HW + gy * 128 + gx) * 256 + cb_al + kc * 16));
          va = src[0]; vb = src[1];
        }
        uint4* dst = (uint4*)&sX[p * 16];
        dst[0] = va; dst[1] = vb;
      }
    }
    __syncthreads();

    #pragma unroll
    for (int s = 0; s < 5; ++s) {
      const int tap0 = 2 * s, tap1 = 2 * s + 1;
      const int dy0 = tap0 / 3, dx0 = tap0 % 3;
      const int dy1 = (tap1 <= 8) ? tap1 / 3 : 2;
      const int dx1 = (tap1 <= 8) ? tap1 % 3 : 2;
      const int dy = half ? dy1 : dy0;
      const int dx = half ? dx1 : dx0;
      const int atap = tap0 + half;
      vec8s a0 = *(const vec8s*)&sW[(atap * 50 + 0  + l15) * 16 + oct * 8];
      vec8s a1 = *(const vec8s*)&sW[(atap * 50 + 16 + l15) * 16 + oct * 8];
      vec8s a2 = *(const vec8s*)&sW[(atap * 50 + 32 + l15) * 16 + oct * 8];
      #pragma unroll
      for (int rs = 0; rs < 2; ++rs) {
        const int rowin = rbase + rs + dy * DIL;
        #pragma unroll
        for (int c4 = 0; c4 < 4; ++c4) {
          const int colin = c4 * 16 + l15 + dx * DIL;
          vec8s bf = *(const vec8s*)&sX[(rowin * C + colin) * 16 + oct * 8];
          acc[0][rs*4+c4] = __builtin_amdgcn_mfma_f32_16x16x32_bf16(a0, bf, acc[0][rs*4+c4], 0, 0, 0);
          acc[1][rs*4+c4] = __builtin_amdgcn_mfma_f32_16x16x32_bf16(a1, bf, acc[1][rs*4+c4], 0, 0, 0);
          acc[2][rs*4+c4] = __builtin_amdgcn_mfma_f32_16x16x32_bf16(a2, bf, acc[2][rs*4+c4], 0, 0, 0);
        }
      }
    }
    __syncthreads();
  }

  const int row4 = (l >> 4);
  #pragma unroll
  for (int cf = 0; cf < 3; ++cf) {
    #pragma unroll
    for (int r = 0; r < 4; ++r) {
      int c_loc = ct2 * 48 + cf * 16 + row4 * 4 + r;
      if (c_loc < CG) {
        int cg = cb + c_loc;
        float g = bnp[c_loc], be = bnp[CG + c_loc];
        float mu = bnp[2 * CG + c_loc], va = bnp[3 * CG + c_loc];
        float scv = g * rsqrtf(va + 1e-5f);
        float shv = be - mu * scv;
        #pragma unroll
        for (int rs = 0; rs < 2; ++rs) {
          int y = y0 + rbase + rs;
          #pragma unroll
          for (int c4 = 0; c4 < 4; ++c4) {
            int x = x0 + c4 * 16 + l15;
            out[(size_t)(b * 256 + cg) * HW + y * 128 + x] =
                fmaf(acc[cf][rs*4+c4][r], scv, shv);
          }
        }
      }
    }
  }
}

// ---------------------------------------------------------------------------
// Windowed attention on window-layout qkv: qkvW[b][win][c(768)][p(64)] bf16.
// One block per (b, win), loop 16 heads. Output bf16 NCHW.
// ---------------------------------------------------------------------------
__global__ __launch_bounds__(256) void k_attn(
    const uint16_t* __restrict__ qkvW, const float* __restrict__ rpb,
    uint16_t* __restrict__ outp)
{
  __shared__ __align__(16) float sQ[16][64];
  __shared__ __align__(16) float sK[16][64];
  __shared__ __align__(16) float sV[16][64];
  __shared__ __align__(16) float sD[64][68];
  __shared__ float srpb[225];
  const int t  = threadIdx.x;
  const int b  = blockIdx.y;
  const int win = blockIdx.x;
  const int wy = win >> 4, wx = win & 15;
  const int wbase = (wy * 8) * 128 + wx * 8;
  const uint16_t* base = qkvW + (size_t)(b * 256 + win) * 49152;  // 768*64

  for (int n = 0; n < 16; ++n) {
    if (t < 225) srpb[t] = rpb[t * 16 + n];
    // ---- stage q,k,v for head n: 3 x 1024 bf16 contiguous chunks ----
    #pragma unroll
    for (int rr = 0; rr < 2; ++rr) {
      int e = t + rr * 256;
      if (e < 384) {
        int s = e >> 7;           // 0=q,1=k,2=v
        int tt = e & 127;         // 128 x 8 elems = 1024
        const uint16_t* src = base + ((size_t)(s * 16 + n)) * 1024 + tt * 8;
        uint4 v4 = *(const uint4*)src;
        float f[8];
        unpack2(v4.x, f[0], f[1]); unpack2(v4.y, f[2], f[3]);
        unpack2(v4.z, f[4], f[5]); unpack2(v4.w, f[6], f[7]);
        int dd = tt >> 3, p0 = (tt & 7) * 8;
        float* dst = (s == 0) ? &sQ[dd][p0] : (s == 1) ? &sK[dd][p0] : &sV[dd][p0];
        float4 a = {f[0],f[1],f[2],f[3]}, bq = {f[4],f[5],f[6],f[7]};
        *(float4*)dst = a; *(float4*)(dst + 4) = bq;
      }
    }
    __syncthreads();
    // ---- dots = (q.k)*0.25 + bias ----
    {
      const int ig = t >> 4, jg = t & 15;
      const int i0 = ig * 4, j0 = jg * 4;
      float a[4][4];
      #pragma unroll
      for (int x = 0; x < 4; ++x)
        #pragma unroll
        for (int y = 0; y < 4; ++y) a[x][y] = 0.f;
      #pragma unroll
      for (int dd = 0; dd < 16; ++dd) {
        float4 qv = *(const float4*)&sQ[dd][i0];
        float4 kv = *(const float4*)&sK[dd][j0];
        const float qa[4] = {qv.x, qv.y, qv.z, qv.w};
        const float ka[4] = {kv.x, kv.y, kv.z, kv.w};
        #pragma unroll
        for (int x = 0; x < 4; ++x)
          #pragma unroll
          for (int y = 0; y < 4; ++y) a[x][y] = fmaf(qa[x], ka[y], a[x][y]);
      }
      #pragma unroll
      for (int x = 0; x < 4; ++x) {
        float dv[4];
        #pragma unroll
        for (int y = 0; y < 4; ++y) {
          int ii = i0 + x, jj = j0 + y;
          int rel = ((ii >> 3) - (jj >> 3) + 7) * 15 + ((ii & 7) - (jj & 7) + 7);
          dv[y] = fmaf(a[x][y], 0.25f, srpb[rel]);
        }
        float4 o = {dv[0], dv[1], dv[2], dv[3]};
        *(float4*)&sD[i0 + x][j0] = o;
      }
    }
    __syncthreads();
    // ---- softmax (4 lanes/row) + PV (dd-major V) ----
    {
      const int i = t >> 2, q4 = t & 3;
      float p[16];
      *(float4*)&p[0]  = *(const float4*)&sD[i][q4 * 16];
      *(float4*)&p[4]  = *(const float4*)&sD[i][q4 * 16 + 4];
      *(float4*)&p[8]  = *(const float4*)&sD[i][q4 * 16 + 8];
      *(float4*)&p[12] = *(const float4*)&sD[i][q4 * 16 + 12];
      float mx = p[0];
      #pragma unroll
      for (int jj = 1; jj < 16; ++jj) mx = fmaxf(mx, p[jj]);
      mx = fmaxf(mx, __shfl_xor(mx, 1));
      mx = fmaxf(mx, __shfl_xor(mx, 2));
      float s = 0.f;
      #pragma unroll
      for (int jj = 0; jj < 16; ++jj) { p[jj] = __expf(p[jj] - mx); s += p[jj]; }
      s += __shfl_xor(s, 1);
      s += __shfl_xor(s, 2);
      const float sinv = 1.f / s;
      float part[16];
      #pragma unroll
      for (int dd = 0; dd < 16; ++dd) {
        float4 v0 = *(const float4*)&sV[dd][q4 * 16];
        float4 v1 = *(const float4*)&sV[dd][q4 * 16 + 4];
        float4 v2 = *(const float4*)&sV[dd][q4 * 16 + 8];
        float4 v3 = *(const float4*)&sV[dd][q4 * 16 + 12];
        float acc2;
        acc2  = p[0]*v0.x + p[1]*v0.y + p[2]*v0.z + p[3]*v0.w;
        acc2 += p[4]*v1.x + p[5]*v1.y + p[6]*v1.z + p[7]*v1.w;
        acc2 += p[8]*v2.x + p[9]*v2.y + p[10]*v2.z + p[11]*v2.w;
        acc2 += p[12]*v3.x + p[13]*v3.y + p[14]*v3.z + p[15]*v3.w;
        part[dd] = acc2;
      }
      #pragma unroll
      for (int dd = 0; dd < 16; ++dd) {
        part[dd] += __shfl_xor(part[dd], 1);
        part[dd] += __shfl_xor(part[dd], 2);
      }
      const int r = i >> 3, c = i & 7;
      uint16_t* dst = outp + (size_t)(b * 256 + n * 16 + q4 * 4) * HW + wbase + r * 128 + c;
      #pragma unroll
      for (int m2 = 0; m2 < 4; ++m2) dst[(size_t)m2 * HW] = f2bf(part[q4 * 4 + m2] * sinv);
    }
    __syncthreads();
  }
}

// ---------------------------------------------------------------------------
// combined = avgpool_v(attn) + avgpool_h(attn) + local (in-place into loc)
// ---------------------------------------------------------------------------
__global__ __launch_bounds__(256) void k_pool(
    const uint16_t* __restrict__ attnb, float* __restrict__ loc)
{
  __shared__ __align__(16) float sP[71][132];
  const int t = threadIdx.x;
  const int plane = blockIdx.x >> 1;
  const int h0 = (blockIdx.x & 1) * 64;
  const size_t pbase = (size_t)plane * HW;
  for (int k = 0; k < 5; ++k) {
    int idx = t + k * 256;
    if (idx < 71 * 16) {
      int lr = idx >> 4, c8 = (idx & 15) * 8;
      int g = h0 - 3 + lr;
      if (g >= 0 && g <= 127) {
        uint4 v4 = *(const uint4*)(attnb + pbase + (size_t)g * 128 + c8);
        float f[8];
        unpack2(v4.x, f[0], f[1]); unpack2(v4.y, f[2], f[3]);
        unpack2(v4.z, f[4], f[5]); unpack2(v4.w, f[6], f[7]);
        #pragma unroll
        for (int j = 0; j < 8; ++j) sP[lr][c8 + j] = f[j];
      }
    }
  }
  __syncthreads();
  for (int k = 0; k < 32; ++k) {
    int idx = t + k * 256;
    int lh = idx >> 7, w = idx & 127;
    int h = h0 + lh;
    float ax = 0.f;
    #pragma unroll
    for (int o = -3; o <= 4; ++o) {
      int j = h + o;
      if (j >= 0 && j <= 128) {
        int jr = (j == 128) ? 126 : j;
        ax += sP[jr - h0 + 3][w];
      }
    }
    float ay = 0.f;
    #pragma unroll
    for (int o = -3; o <= 4; ++o) {
      int j = w + o;
      if (j >= 0 && j <= 128) {
        int jr = (j == 128) ? 126 : j;
        ay += sP[lh + 3][jr];
      }
    }
    size_t gi = pbase + (size_t)h * 128 + w;
    loc[gi] = fmaf(ax + ay, 0.125f, loc[gi]);
  }
}

// ---------------------------------------------------------------------------
// Depthwise 8x8 conv on reflect(+1)-padded combined, zero pad 3.
// ---------------------------------------------------------------------------
__global__ __launch_bounds__(256) void k_dw(
    const float* __restrict__ comb, const float* __restrict__ wdw,
    float* __restrict__ out)
{
  __shared__ __align__(16) float sZ[71][140];
  __shared__ float sWd[64];
  const int t = threadIdx.x;
  const int plane = blockIdx.x >> 1;
  const int cch = plane & 255;
  const int h0 = (blockIdx.x & 1) * 64;
  const size_t pbase = (size_t)plane * HW;
  if (t < 64) sWd[t] = wdw[cch * 64 + t];
  for (int k = 0; k < 38; ++k) {
    int idx = t + k * 256;
    if (idx < 71 * 136) {
      int u = idx / 136, vc = idx - u * 136;
      int g = h0 - 3 + u;
      if (g >= 0 && g <= 128) {
        int bb = vc - 3;
        float v = 0.f;
        if (bb >= 0 && bb <= 128) {
          int gr = (g == 128) ? 126 : g;
          int br = (bb == 128) ? 126 : bb;
          v = comb[pbase + gr * 128 + br];
        }
        sZ[u][vc] = v;
      }
    }
  }
  __syncthreads();
  const int wg = t & 7, hl = t >> 3;
  const int w0 = wg * 16;
  float acc[2][16];
  #pragma unroll
  for (int a = 0; a < 2; ++a)
    #pragma unroll
    for (int p = 0; p < 16; ++p) acc[a][p] = 0.f;
  #pragma unroll 1
  for (int i = 0; i < 8; ++i) {
    float wrow[8];
    *(float4*)&wrow[0] = *(const float4*)&sWd[i * 8];
    *(float4*)&wrow[4] = *(const float4*)&sWd[i * 8 + 4];
    #pragma unroll
    for (int hi = 0; hi < 2; ++hi) {
      int h = h0 + hl + 32 * hi;
      int u = h + i - 3;
      bool ok = (u >= 0 && u <= 128);
      int lr = ok ? (u - h0 + 3) : 0;
      const float* zr = &sZ[lr][w0];
      float win[24];
      *(float4*)&win[0]  = *(const float4*)(zr);
      *(float4*)&win[4]  = *(const float4*)(zr + 4);
      *(float4*)&win[8]  = *(const float4*)(zr + 8);
      *(float4*)&win[12] = *(const float4*)(zr + 12);
      *(float4*)&win[16] = *(const float4*)(zr + 16);
      *(float4*)&win[20] = *(const float4*)(zr + 20);
      float m = ok ? 1.f : 0.f;
      float wv[8];
      #pragma unroll
      for (int j = 0; j < 8; ++j) wv[j] = wrow[j] * m;
      #pragma unroll
      for (int p = 0; p < 16; ++p)
        #pragma unroll
        for (int j = 0; j < 8; ++j)
          acc[hi][p] = fmaf(wv[j], win[p + j], acc[hi][p]);
    }
  }
  #pragma unroll
  for (int hi = 0; hi < 2; ++hi) {
    int h = h0 + hl + 32 * hi;
    float* dst = out + pbase + (size_t)h * 128 + w0;
    float4 o0 = {acc[hi][0],  acc[hi][1],  acc[hi][2],  acc[hi][3]};
    float4 o1 = {acc[hi][4],  acc[hi][5],  acc[hi][6],  acc[hi][7]};
    float4 o2 = {acc[hi][8],  acc[hi][9],  acc[hi][10], acc[hi][11]};
    float4 o3 = {acc[hi][12], acc[hi][13], acc[hi][14], acc[hi][15]};
    *(float4*)(dst)      = o0;
    *(float4*)(dst + 4)  = o1;
    *(float4*)(dst + 8)  = o2;
    *(float4*)(dst + 12) = o3;
  }
}

} // namespace

extern "C" void kernel_launch(void* const* d_in, const int* in_sizes, int n_in,
                              void* d_out, int out_size, void* d_ws, size_t ws_size,
                              hipStream_t stream)
{
  const float* x      = (const float*)d_in[0];
  const float* w_pre  = (const float*)d_in[1];
  const float* bn_pre = (const float*)d_in[2];
  const float* w_l1   = (const float*)d_in[3];
  const float* bn_l1  = (const float*)d_in[4];
  const float* w_l2   = (const float*)d_in[5];
  const float* bn_l2  = (const float*)d_in[6];
  const float* w_l3   = (const float*)d_in[7];
  const float* bn_l3  = (const float*)d_in[8];
  const float* w_qkv  = (const float*)d_in[9];
  const float* rpb    = (const float*)d_in[10];
  const float* w_dw   = (const float*)d_in[11];
  const float* w_pw   = (const float*)d_in[12];
  const float* bn_pj  = (const float*)d_in[13];
  float* out = (float*)d_out;

  char* base = (char*)d_ws;
  uint16_t* xT    = (uint16_t*)base;                          // 64 MiB NHWC bf16 x; later dwT
  uint16_t* preT  = (uint16_t*)(base + (size_t)67108864);     // 64 MiB NHWC bf16 pre; later attn out
  float*    bufB  = (float*)(base + (size_t)134217728);       // 128 MiB fp32 local/combined
  uint16_t* bufQ  = (uint16_t*)(base + (size_t)268435456);    // 192 MiB bf16 qkv windows; later dw out
  uint16_t* attnO = preT;
  float*    bufDw = (float*)bufQ;
  uint16_t* dwT   = xT;

  dim3 blk(256);
  // 0. cast x -> NHWC bf16
  k_cast<<<dim3(1024), blk, 0, stream>>>(x, xT);
  // 1. pre 1x1 conv + bn -> NHWC bf16 (MFMA)
  k_gemm_mfma<0><<<dim3(1024, 4), blk, 0, stream>>>(xT, w_pre, bn_pre, 256, preT, nullptr);
  // 2. dilated 3x3 convs + bn (MFMA) -> bufB fp32 NCHW
  k_dilconv_mfma<1, 86><<<dim3(32, 2, 8), blk, 0, stream>>>(preT, w_l1, bn_l1, bufB, 0, 0);
  k_dilconv_mfma<2, 86><<<dim3(32, 2, 8), blk, 0, stream>>>(preT, w_l2, bn_l2, bufB, 86, 80);
  k_dilconv_mfma<3, 84><<<dim3(32, 2, 8), blk, 0, stream>>>(preT, w_l3, bn_l3, bufB, 172, 160);
  // 3. qkv 1x1 conv -> bufQ window-layout bf16 (MFMA)
  k_gemm_mfma<3><<<dim3(1024, 12), blk, 0, stream>>>(xT, w_qkv, nullptr, 768, bufQ, nullptr);
  // 4. windowed attention -> attnO bf16 NCHW (overwrites preT; safe)
  k_attn<<<dim3(256, 8), blk, 0, stream>>>(bufQ, rpb, attnO);
  // 5. pools + residual combine (in-place on bufB)
  k_pool<<<dim3(4096), blk, 0, stream>>>(attnO, bufB);
  // 6. depthwise 8x8 -> bufDw fp32 NCHW (overwrites bufQ; safe)
  k_dw<<<dim3(4096), blk, 0, stream>>>(bufB, w_dw, bufDw);
  // 7. cast dw-out -> NHWC bf16 (overwrites xT; safe)
  k_cast<<<dim3(1024), blk, 0, stream>>>(bufDw, dwT);
  // 8. pw 1x1 conv + bn -> out fp32 NCHW (MFMA)
  k_gemm_mfma<2><<<dim3(1024, 4), blk, 0, stream>>>(dwT, w_pw, bn_pj, 256, nullptr, out);

  (void)in_sizes; (void)n_in; (void)out_size; (void)ws_size;
}

// Round 6
// 1082.957 us; speedup vs baseline: 4.0208x; 1.1897x over previous
//
#include <hip/hip_runtime.h>
#include <hip/hip_bf16.h>
#include <cstdint>
#include <cstddef>

namespace {

constexpr int HW = 16384;   // 128*128

typedef short vec8s __attribute__((ext_vector_type(8)));
typedef float f32x4 __attribute__((ext_vector_type(4)));

__device__ __forceinline__ float u2f(uint32_t u){ union { uint32_t u; float f; } v; v.u = u; return v.f; }
__device__ __forceinline__ uint32_t f2u(float f){ union { float f; uint32_t u; } v; v.f = f; return v.u; }
__device__ __forceinline__ uint16_t f2bf(float f){
  uint32_t u = f2u(f);
  u += 0x7fffu + ((u >> 16) & 1u);   // round-to-nearest-even
  return (uint16_t)(u >> 16);
}
__device__ __forceinline__ void unpack2(uint32_t w, float& lo, float& hi){
  lo = u2f(w << 16);
  hi = u2f(w & 0xffff0000u);
}

// ---------------------------------------------------------------------------
// Cast NCHW fp32 (256 ch) -> NHWC bf16. Block = one (b, row).
// ---------------------------------------------------------------------------
__global__ __launch_bounds__(256) void k_cast(
    const float* __restrict__ x, uint16_t* __restrict__ xT)
{
  __shared__ float sF[64][129];
  const int t = threadIdx.x;
  const int b = blockIdx.x >> 7;
  const int y = blockIdx.x & 127;
  const size_t rowoff = (size_t)y * 128;
  for (int cc = 0; cc < 4; ++cc) {
    const int cic0 = cc * 64;
    #pragma unroll
    for (int k = 0; k < 8; ++k) {
      int e = t + k * 256;
      int ci = e >> 5;
      int pxq = (e & 31) * 4;
      float4 v = *(const float4*)(x + (size_t)(b * 256 + cic0 + ci) * HW + rowoff + pxq);
      sF[ci][pxq] = v.x; sF[ci][pxq+1] = v.y; sF[ci][pxq+2] = v.z; sF[ci][pxq+3] = v.w;
    }
    __syncthreads();
    {
      int px = t >> 1, h = t & 1;
      __align__(16) uint16_t tmp[32];
      #pragma unroll
      for (int j = 0; j < 32; ++j) tmp[j] = f2bf(sF[h * 32 + j][px]);
      uint16_t* dst = xT + ((size_t)b * HW + rowoff + px) * 256 + cic0 + h * 32;
      *(uint4*)(dst)      = *(uint4*)&tmp[0];
      *(uint4*)(dst + 8)  = *(uint4*)&tmp[8];
      *(uint4*)(dst + 16) = *(uint4*)&tmp[16];
      *(uint4*)(dst + 24) = *(uint4*)&tmp[24];
    }
    __syncthreads();
  }
}

// ---------------------------------------------------------------------------
// 1x1 conv via bf16 MFMA, X-resident co-loop version.
// X tile: 128 px x 256 ci staged ONCE in LDS (66.5 KB). Loop NCO chunks of
// 128 co; W staged per-K-step (reg-prefetched). Per wave: 64co x 64px.
// OUT_MODE 0: NHWC bf16 + BN (pre)     [px linear]
// OUT_MODE 2: NCHW fp32 + BN (pw->out) [px linear]
// OUT_MODE 3: qkv window layout bf16 [b][win][c(768)][p(64)]  [px win-major]
// Layout conventions (HW-verified r3/r5): A row=l&15, k=(l>>4)*8+j;
// B col=l&15; D col=l&15(px), row=(l>>4)*4+r (co).
// ---------------------------------------------------------------------------
template<int OUT_MODE, int NCO>
__global__ __launch_bounds__(256) void k_gemm_v2(
    const uint16_t* __restrict__ xT, const float* __restrict__ wmat,
    const float* __restrict__ bnp, int M,
    uint16_t* __restrict__ outb, float* __restrict__ outf)
{
  __shared__ __align__(16) uint16_t sX[128][260];
  __shared__ __align__(16) uint16_t sW[128][36];
  const int t = threadIdx.x;
  const int b    = blockIdx.x >> 7;
  const int tile = blockIdx.x & 127;
  const int l = t & 63, w = t >> 6;
  const int l15 = l & 15, koct = l >> 4;
  const int wc = w >> 1, wp = w & 1;     // wave co-half / px-half

  // ---- stage X tile once: thread t -> pixel t>>1, ci half (t&1)*128 ----
  {
    const int spx = t >> 1, sh = t & 1;
    int gpx;
    if constexpr (OUT_MODE == 3) {
      int win = tile * 2 + (spx >> 6);
      int p = spx & 63;
      gpx = ((win >> 4) * 8 + (p >> 3)) * 128 + (win & 15) * 8 + (p & 7);
    } else {
      gpx = tile * 128 + spx;
    }
    const uint16_t* src = xT + ((size_t)b * HW + gpx) * 256 + sh * 128;
    uint16_t* dst = &sX[spx][sh * 128];
    #pragma unroll
    for (int i = 0; i < 16; ++i)
      *(uint4*)(dst + i * 8) = *(const uint4*)(src + i * 8);
  }

  // ---- W prefetch: thread t -> co row t>>1, ci half (t&1)*16 (of 32) ----
  const int swc = t >> 1, swh = t & 1;
  float4 wr0, wr1, wr2, wr3;
  {
    const float* p = wmat + (size_t)swc * 256 + swh * 16;   // cc=0, kc=0
    wr0 = *(const float4*)(p);     wr1 = *(const float4*)(p + 4);
    wr2 = *(const float4*)(p + 8); wr3 = *(const float4*)(p + 12);
  }
  __syncthreads();   // X resident

  for (int cc = 0; cc < NCO; ++cc) {
    f32x4 acc[4][4];
    #pragma unroll
    for (int cf = 0; cf < 4; ++cf)
      #pragma unroll
      for (int pf = 0; pf < 4; ++pf) acc[cf][pf] = (f32x4){0.f,0.f,0.f,0.f};

    for (int kc = 0; kc < 8; ++kc) {
      if (cc | kc) __syncthreads();          // prior readers of sW done
      {
        __align__(16) uint16_t tmp[16];
        tmp[0]=f2bf(wr0.x); tmp[1]=f2bf(wr0.y); tmp[2]=f2bf(wr0.z); tmp[3]=f2bf(wr0.w);
        tmp[4]=f2bf(wr1.x); tmp[5]=f2bf(wr1.y); tmp[6]=f2bf(wr1.z); tmp[7]=f2bf(wr1.w);
        tmp[8]=f2bf(wr2.x); tmp[9]=f2bf(wr2.y); tmp[10]=f2bf(wr2.z); tmp[11]=f2bf(wr2.w);
        tmp[12]=f2bf(wr3.x); tmp[13]=f2bf(wr3.y); tmp[14]=f2bf(wr3.z); tmp[15]=f2bf(wr3.w);
        uint16_t* dst = &sW[swc][swh * 16];
        *(uint4*)(dst)     = *(uint4*)&tmp[0];
        *(uint4*)(dst + 8) = *(uint4*)&tmp[8];
      }
      {
        int nkc = kc + 1, ncc = cc;
        if (nkc == 8) { nkc = 0; ncc = cc + 1; }
        if (ncc < NCO) {   // issue next W loads early (hide under MFMA)
          const float* p = wmat + (size_t)(ncc * 128 + swc) * 256 + nkc * 32 + swh * 16;
          wr0 = *(const float4*)(p);     wr1 = *(const float4*)(p + 4);
          wr2 = *(const float4*)(p + 8); wr3 = *(const float4*)(p + 12);
        }
      }
      __syncthreads();                        // sW chunk ready
      vec8s bf[4];
      #pragma unroll
      for (int pf = 0; pf < 4; ++pf)
        bf[pf] = *(const vec8s*)&sX[wp * 64 + pf * 16 + l15][kc * 32 + koct * 8];
      #pragma unroll
      for (int cf = 0; cf < 4; ++cf) {
        vec8s af = *(const vec8s*)&sW[wc * 64 + cf * 16 + l15][koct * 8];
        #pragma unroll
        for (int pf = 0; pf < 4; ++pf)
          acc[cf][pf] = __builtin_amdgcn_mfma_f32_16x16x32_bf16(af, bf[pf], acc[cf][pf], 0, 0, 0);
      }
    }

    // ---- epilogue for this co chunk ----
    #pragma unroll
    for (int cf = 0; cf < 4; ++cf) {
      const int cbase = cc * 128 + wc * 64 + cf * 16 + koct * 4;
      float scv[4], shv[4];
      #pragma unroll
      for (int r = 0; r < 4; ++r) {
        scv[r] = 1.f; shv[r] = 0.f;
        if constexpr (OUT_MODE == 0 || OUT_MODE == 2) {
          int c = cbase + r;
          float g = bnp[c], be = bnp[M + c], mu = bnp[2 * M + c], va = bnp[3 * M + c];
          scv[r] = g * rsqrtf(va + 1e-5f);
          shv[r] = be - mu * scv[r];
        }
      }
      #pragma unroll
      for (int pf = 0; pf < 4; ++pf) {
        if constexpr (OUT_MODE == 0) {
          int px = tile * 128 + wp * 64 + pf * 16 + l15;
          __align__(8) uint16_t pk[4];
          #pragma unroll
          for (int r = 0; r < 4; ++r)
            pk[r] = f2bf(fmaf(acc[cf][pf][r], scv[r], shv[r]));
          *(uint2*)(outb + ((size_t)b * HW + px) * 256 + cbase) = *(uint2*)pk;
        } else if constexpr (OUT_MODE == 2) {
          int px = tile * 128 + wp * 64 + pf * 16 + l15;
          #pragma unroll
          for (int r = 0; r < 4; ++r)
            outf[(size_t)(b * M + cbase + r) * HW + px] =
                fmaf(acc[cf][pf][r], scv[r], shv[r]);
        } else {   // OUT_MODE 3
          int win = tile * 2 + wp;
          int p = pf * 16 + l15;
          uint16_t* dstp = outb + ((size_t)(b * 256 + win) * 768 + cbase) * 64 + p;
          #pragma unroll
          for (int r = 0; r < 4; ++r)
            dstp[(size_t)r * 64] = f2bf(acc[cf][pf][r]);
        }
      }
    }
  }
}

// ---------------------------------------------------------------------------
// Dilated 3x3 conv + BN via bf16 MFMA implicit GEMM (unchanged from r3).
// ---------------------------------------------------------------------------
template<int DIL, int CG>
__global__ __launch_bounds__(256) void k_dilconv_mfma(
    const uint16_t* __restrict__ preT, const float* __restrict__ wt,
    const float* __restrict__ bnp, float* __restrict__ out,
    int cb, int cb_al)
{
  constexpr int R = 8 + 2 * DIL;
  constexpr int C = 64 + 2 * DIL;
  constexpr int NPOS = R * C;
  constexpr int NIT = (NPOS + 255) / 256;
  __shared__ __align__(16) uint16_t sX[NPOS * 16];
  __shared__ __align__(16) uint16_t sW[10 * 50 * 16];

  const int t = threadIdx.x;
  const int rt    = blockIdx.x >> 1;
  const int ctile = blockIdx.x & 1;
  const int ct2   = blockIdx.y;
  const int b     = blockIdx.z;
  const int y0 = rt * 8, x0 = ctile * 64;
  const int l = t & 63, w = t >> 6;
  const int l15 = l & 15, oct = (l >> 4) & 1, half = l >> 5;
  const int rbase = w * 2;

  f32x4 acc[3][8];
  #pragma unroll
  for (int cf = 0; cf < 3; ++cf)
    #pragma unroll
    for (int q = 0; q < 8; ++q) acc[cf][q] = (f32x4){0.f,0.f,0.f,0.f};

  for (int kc = 0; kc < 6; ++kc) {
    #pragma unroll
    for (int i = 0; i < 3; ++i) {
      int pair = t + i * 256;
      int co = pair >> 4, ci = pair & 15;
      int cog = ct2 * 48 + co;
      int c = cb_al + kc * 16 + ci;
      bool ok = (cog < CG) && (c >= cb) && (c < cb + CG);
      size_t widx = ok ? ((size_t)cog * (size_t)CG + (size_t)(c - cb)) * 9u
                       : (size_t)0;
      const float* wp = wt + widx;
      uint16_t* dst = &sW[co * 16 + ci];
      #pragma unroll
      for (int tap = 0; tap < 9; ++tap)
        dst[tap * 800] = ok ? f2bf(wp[tap]) : (uint16_t)0;
      dst[9 * 800] = 0;
    }
    #pragma unroll
    for (int i = 0; i < NIT; ++i) {
      int p = t + i * 256;
      if (p < NPOS) {
        int row = p / C, col = p % C;
        int gy = y0 + row - DIL, gx = x0 + col - DIL;
        uint4 va = {0,0,0,0}, vb = {0,0,0,0};
        if ((unsigned)gy < 128u && (unsigned)gx < 128u) {
          const uint4* src = (const uint4*)(preT +
              (((size_t)b * HW + gy * 128 + gx) * 256 + cb_al + kc * 16));
          va = src[0]; vb = src[1];
        }
        uint4* dst = (uint4*)&sX[p * 16];
        dst[0] = va; dst[1] = vb;
      }
    }
    __syncthreads();

    #pragma unroll
    for (int s = 0; s < 5; ++s) {
      const int tap0 = 2 * s, tap1 = 2 * s + 1;
      const int dy0 = tap0 / 3, dx0 = tap0 % 3;
      const int dy1 = (tap1 <= 8) ? tap1 / 3 : 2;
      const int dx1 = (tap1 <= 8) ? tap1 % 3 : 2;
      const int dy = half ? dy1 : dy0;
      const int dx = half ? dx1 : dx0;
      const int atap = tap0 + half;
      vec8s a0 = *(const vec8s*)&sW[(atap * 50 + 0  + l15) * 16 + oct * 8];
      vec8s a1 = *(const vec8s*)&sW[(atap * 50 + 16 + l15) * 16 + oct * 8];
      vec8s a2 = *(const vec8s*)&sW[(atap * 50 + 32 + l15) * 16 + oct * 8];
      #pragma unroll
      for (int rs = 0; rs < 2; ++rs) {
        const int rowin = rbase + rs + dy * DIL;
        #pragma unroll
        for (int c4 = 0; c4 < 4; ++c4) {
          const int colin = c4 * 16 + l15 + dx * DIL;
          vec8s bf = *(const vec8s*)&sX[(rowin * C + colin) * 16 + oct * 8];
          acc[0][rs*4+c4] = __builtin_amdgcn_mfma_f32_16x16x32_bf16(a0, bf, acc[0][rs*4+c4], 0, 0, 0);
          acc[1][rs*4+c4] = __builtin_amdgcn_mfma_f32_16x16x32_bf16(a1, bf, acc[1][rs*4+c4], 0, 0, 0);
          acc[2][rs*4+c4] = __builtin_amdgcn_mfma_f32_16x16x32_bf16(a2, bf, acc[2][rs*4+c4], 0, 0, 0);
        }
      }
    }
    __syncthreads();
  }

  const int row4 = (l >> 4);
  #pragma unroll
  for (int cf = 0; cf < 3; ++cf) {
    #pragma unroll
    for (int r = 0; r < 4; ++r) {
      int c_loc = ct2 * 48 + cf * 16 + row4 * 4 + r;
      if (c_loc < CG) {
        int cg = cb + c_loc;
        float g = bnp[c_loc], be = bnp[CG + c_loc];
        float mu = bnp[2 * CG + c_loc], va = bnp[3 * CG + c_loc];
        float scv = g * rsqrtf(va + 1e-5f);
        float shv = be - mu * scv;
        #pragma unroll
        for (int rs = 0; rs < 2; ++rs) {
          int y = y0 + rbase + rs;
          #pragma unroll
          for (int c4 = 0; c4 < 4; ++c4) {
            int x = x0 + c4 * 16 + l15;
            out[(size_t)(b * 256 + cg) * HW + y * 128 + x] =
                fmaf(acc[cf][rs*4+c4][r], scv, shv);
          }
        }
      }
    }
  }
}

// ---------------------------------------------------------------------------
// Windowed attention on window-layout qkv: qkvW[b][win][c(768)][p(64)] bf16.
// ---------------------------------------------------------------------------
__global__ __launch_bounds__(256) void k_attn(
    const uint16_t* __restrict__ qkvW, const float* __restrict__ rpb,
    uint16_t* __restrict__ outp)
{
  __shared__ __align__(16) float sQ[16][64];
  __shared__ __align__(16) float sK[16][64];
  __shared__ __align__(16) float sV[16][64];
  __shared__ __align__(16) float sD[64][68];
  __shared__ float srpb[225];
  const int t  = threadIdx.x;
  const int b  = blockIdx.y;
  const int win = blockIdx.x;
  const int wy = win >> 4, wx = win & 15;
  const int wbase = (wy * 8) * 128 + wx * 8;
  const uint16_t* base = qkvW + (size_t)(b * 256 + win) * 49152;

  for (int n = 0; n < 16; ++n) {
    if (t < 225) srpb[t] = rpb[t * 16 + n];
    #pragma unroll
    for (int rr = 0; rr < 2; ++rr) {
      int e = t + rr * 256;
      if (e < 384) {
        int s = e >> 7;
        int tt = e & 127;
        const uint16_t* src = base + ((size_t)(s * 16 + n)) * 1024 + tt * 8;
        uint4 v4 = *(const uint4*)src;
        float f[8];
        unpack2(v4.x, f[0], f[1]); unpack2(v4.y, f[2], f[3]);
        unpack2(v4.z, f[4], f[5]); unpack2(v4.w, f[6], f[7]);
        int dd = tt >> 3, p0 = (tt & 7) * 8;
        float* dst = (s == 0) ? &sQ[dd][p0] : (s == 1) ? &sK[dd][p0] : &sV[dd][p0];
        float4 a = {f[0],f[1],f[2],f[3]}, bq = {f[4],f[5],f[6],f[7]};
        *(float4*)dst = a; *(float4*)(dst + 4) = bq;
      }
    }
    __syncthreads();
    {
      const int ig = t >> 4, jg = t & 15;
      const int i0 = ig * 4, j0 = jg * 4;
      float a[4][4];
      #pragma unroll
      for (int x = 0; x < 4; ++x)
        #pragma unroll
        for (int y = 0; y < 4; ++y) a[x][y] = 0.f;
      #pragma unroll
      for (int dd = 0; dd < 16; ++dd) {
        float4 qv = *(const float4*)&sQ[dd][i0];
        float4 kv = *(const float4*)&sK[dd][j0];
        const float qa[4] = {qv.x, qv.y, qv.z, qv.w};
        const float ka[4] = {kv.x, kv.y, kv.z, kv.w};
        #pragma unroll
        for (int x = 0; x < 4; ++x)
          #pragma unroll
          for (int y = 0; y < 4; ++y) a[x][y] = fmaf(qa[x], ka[y], a[x][y]);
      }
      #pragma unroll
      for (int x = 0; x < 4; ++x) {
        float dv[4];
        #pragma unroll
        for (int y = 0; y < 4; ++y) {
          int ii = i0 + x, jj = j0 + y;
          int rel = ((ii >> 3) - (jj >> 3) + 7) * 15 + ((ii & 7) - (jj & 7) + 7);
          dv[y] = fmaf(a[x][y], 0.25f, srpb[rel]);
        }
        float4 o = {dv[0], dv[1], dv[2], dv[3]};
        *(float4*)&sD[i0 + x][j0] = o;
      }
    }
    __syncthreads();
    {
      const int i = t >> 2, q4 = t & 3;
      float p[16];
      *(float4*)&p[0]  = *(const float4*)&sD[i][q4 * 16];
      *(float4*)&p[4]  = *(const float4*)&sD[i][q4 * 16 + 4];
      *(float4*)&p[8]  = *(const float4*)&sD[i][q4 * 16 + 8];
      *(float4*)&p[12] = *(const float4*)&sD[i][q4 * 16 + 12];
      float mx = p[0];
      #pragma unroll
      for (int jj = 1; jj < 16; ++jj) mx = fmaxf(mx, p[jj]);
      mx = fmaxf(mx, __shfl_xor(mx, 1));
      mx = fmaxf(mx, __shfl_xor(mx, 2));
      float s = 0.f;
      #pragma unroll
      for (int jj = 0; jj < 16; ++jj) { p[jj] = __expf(p[jj] - mx); s += p[jj]; }
      s += __shfl_xor(s, 1);
      s += __shfl_xor(s, 2);
      const float sinv = 1.f / s;
      float part[16];
      #pragma unroll
      for (int dd = 0; dd < 16; ++dd) {
        float4 v0 = *(const float4*)&sV[dd][q4 * 16];
        float4 v1 = *(const float4*)&sV[dd][q4 * 16 + 4];
        float4 v2 = *(const float4*)&sV[dd][q4 * 16 + 8];
        float4 v3 = *(const float4*)&sV[dd][q4 * 16 + 12];
        float acc2;
        acc2  = p[0]*v0.x + p[1]*v0.y + p[2]*v0.z + p[3]*v0.w;
        acc2 += p[4]*v1.x + p[5]*v1.y + p[6]*v1.z + p[7]*v1.w;
        acc2 += p[8]*v2.x + p[9]*v2.y + p[10]*v2.z + p[11]*v2.w;
        acc2 += p[12]*v3.x + p[13]*v3.y + p[14]*v3.z + p[15]*v3.w;
        part[dd] = acc2;
      }
      #pragma unroll
      for (int dd = 0; dd < 16; ++dd) {
        part[dd] += __shfl_xor(part[dd], 1);
        part[dd] += __shfl_xor(part[dd], 2);
      }
      const int r = i >> 3, c = i & 7;
      uint16_t* dst = outp + (size_t)(b * 256 + n * 16 + q4 * 4) * HW + wbase + r * 128 + c;
      #pragma unroll
      for (int m2 = 0; m2 < 4; ++m2) dst[(size_t)m2 * HW] = f2bf(part[q4 * 4 + m2] * sinv);
    }
    __syncthreads();
  }
}

// ---------------------------------------------------------------------------
// combined = avgpool_v(attn) + avgpool_h(attn) + local (in-place into loc)
// ---------------------------------------------------------------------------
__global__ __launch_bounds__(256) void k_pool(
    const uint16_t* __restrict__ attnb, float* __restrict__ loc)
{
  __shared__ __align__(16) float sP[71][132];
  const int t = threadIdx.x;
  const int plane = blockIdx.x >> 1;
  const int h0 = (blockIdx.x & 1) * 64;
  const size_t pbase = (size_t)plane * HW;
  for (int k = 0; k < 5; ++k) {
    int idx = t + k * 256;
    if (idx < 71 * 16) {
      int lr = idx >> 4, c8 = (idx & 15) * 8;
      int g = h0 - 3 + lr;
      if (g >= 0 && g <= 127) {
        uint4 v4 = *(const uint4*)(attnb + pbase + (size_t)g * 128 + c8);
        float f[8];
        unpack2(v4.x, f[0], f[1]); unpack2(v4.y, f[2], f[3]);
        unpack2(v4.z, f[4], f[5]); unpack2(v4.w, f[6], f[7]);
        #pragma unroll
        for (int j = 0; j < 8; ++j) sP[lr][c8 + j] = f[j];
      }
    }
  }
  __syncthreads();
  for (int k = 0; k < 32; ++k) {
    int idx = t + k * 256;
    int lh = idx >> 7, w = idx & 127;
    int h = h0 + lh;
    float ax = 0.f;
    #pragma unroll
    for (int o = -3; o <= 4; ++o) {
      int j = h + o;
      if (j >= 0 && j <= 128) {
        int jr = (j == 128) ? 126 : j;
        ax += sP[jr - h0 + 3][w];
      }
    }
    float ay = 0.f;
    #pragma unroll
    for (int o = -3; o <= 4; ++o) {
      int j = w + o;
      if (j >= 0 && j <= 128) {
        int jr = (j == 128) ? 126 : j;
        ay += sP[lh + 3][jr];
      }
    }
    size_t gi = pbase + (size_t)h * 128 + w;
    loc[gi] = fmaf(ax + ay, 0.125f, loc[gi]);
  }
}

// ---------------------------------------------------------------------------
// Depthwise 8x8 conv on reflect(+1)-padded combined, zero pad 3.
// ---------------------------------------------------------------------------
__global__ __launch_bounds__(256) void k_dw(
    const float* __restrict__ comb, const float* __restrict__ wdw,
    float* __restrict__ out)
{
  __shared__ __align__(16) float sZ[71][140];
  __shared__ float sWd[64];
  const int t = threadIdx.x;
  const int plane = blockIdx.x >> 1;
  const int cch = plane & 255;
  const int h0 = (blockIdx.x & 1) * 64;
  const size_t pbase = (size_t)plane * HW;
  if (t < 64) sWd[t] = wdw[cch * 64 + t];
  for (int k = 0; k < 38; ++k) {
    int idx = t + k * 256;
    if (idx < 71 * 136) {
      int u = idx / 136, vc = idx - u * 136;
      int g = h0 - 3 + u;
      if (g >= 0 && g <= 128) {
        int bb = vc - 3;
        float v = 0.f;
        if (bb >= 0 && bb <= 128) {
          int gr = (g == 128) ? 126 : g;
          int br = (bb == 128) ? 126 : bb;
          v = comb[pbase + gr * 128 + br];
        }
        sZ[u][vc] = v;
      }
    }
  }
  __syncthreads();
  const int wg = t & 7, hl = t >> 3;
  const int w0 = wg * 16;
  float acc[2][16];
  #pragma unroll
  for (int a = 0; a < 2; ++a)
    #pragma unroll
    for (int p = 0; p < 16; ++p) acc[a][p] = 0.f;
  #pragma unroll 1
  for (int i = 0; i < 8; ++i) {
    float wrow[8];
    *(float4*)&wrow[0] = *(const float4*)&sWd[i * 8];
    *(float4*)&wrow[4] = *(const float4*)&sWd[i * 8 + 4];
    #pragma unroll
    for (int hi = 0; hi < 2; ++hi) {
      int h = h0 + hl + 32 * hi;
      int u = h + i - 3;
      bool ok = (u >= 0 && u <= 128);
      int lr = ok ? (u - h0 + 3) : 0;
      const float* zr = &sZ[lr][w0];
      float win[24];
      *(float4*)&win[0]  = *(const float4*)(zr);
      *(float4*)&win[4]  = *(const float4*)(zr + 4);
      *(float4*)&win[8]  = *(const float4*)(zr + 8);
      *(float4*)&win[12] = *(const float4*)(zr + 12);
      *(float4*)&win[16] = *(const float4*)(zr + 16);
      *(float4*)&win[20] = *(const float4*)(zr + 20);
      float m = ok ? 1.f : 0.f;
      float wv[8];
      #pragma unroll
      for (int j = 0; j < 8; ++j) wv[j] = wrow[j] * m;
      #pragma unroll
      for (int p = 0; p < 16; ++p)
        #pragma unroll
        for (int j = 0; j < 8; ++j)
          acc[hi][p] = fmaf(wv[j], win[p + j], acc[hi][p]);
    }
  }
  #pragma unroll
  for (int hi = 0; hi < 2; ++hi) {
    int h = h0 + hl + 32 * hi;
    float* dst = out + pbase + (size_t)h * 128 + w0;
    float4 o0 = {acc[hi][0],  acc[hi][1],  acc[hi][2],  acc[hi][3]};
    float4 o1 = {acc[hi][4],  acc[hi][5],  acc[hi][6],  acc[hi][7]};
    float4 o2 = {acc[hi][8],  acc[hi][9],  acc[hi][10], acc[hi][11]};
    float4 o3 = {acc[hi][12], acc[hi][13], acc[hi][14], acc[hi][15]};
    *(float4*)(dst)      = o0;
    *(float4*)(dst + 4)  = o1;
    *(float4*)(dst + 8)  = o2;
    *(float4*)(dst + 12) = o3;
  }
}

} // namespace

extern "C" void kernel_launch(void* const* d_in, const int* in_sizes, int n_in,
                              void* d_out, int out_size, void* d_ws, size_t ws_size,
                              hipStream_t stream)
{
  const float* x      = (const float*)d_in[0];
  const float* w_pre  = (const float*)d_in[1];
  const float* bn_pre = (const float*)d_in[2];
  const float* w_l1   = (const float*)d_in[3];
  const float* bn_l1  = (const float*)d_in[4];
  const float* w_l2   = (const float*)d_in[5];
  const float* bn_l2  = (const float*)d_in[6];
  const float* w_l3   = (const float*)d_in[7];
  const float* bn_l3  = (const float*)d_in[8];
  const float* w_qkv  = (const float*)d_in[9];
  const float* rpb    = (const float*)d_in[10];
  const float* w_dw   = (const float*)d_in[11];
  const float* w_pw   = (const float*)d_in[12];
  const float* bn_pj  = (const float*)d_in[13];
  float* out = (float*)d_out;

  char* base = (char*)d_ws;
  uint16_t* xT    = (uint16_t*)base;                          // 64 MiB NHWC bf16 x; later dwT
  uint16_t* preT  = (uint16_t*)(base + (size_t)67108864);     // 64 MiB NHWC bf16 pre; later attn out
  float*    bufB  = (float*)(base + (size_t)134217728);       // 128 MiB fp32 local/combined
  uint16_t* bufQ  = (uint16_t*)(base + (size_t)268435456);    // 192 MiB bf16 qkv windows; later dw out
  uint16_t* attnO = preT;
  float*    bufDw = (float*)bufQ;
  uint16_t* dwT   = xT;

  dim3 blk(256);
  // 0. cast x -> NHWC bf16
  k_cast<<<dim3(1024), blk, 0, stream>>>(x, xT);
  // 1. pre 1x1 conv + bn -> NHWC bf16 (MFMA, X-resident)
  k_gemm_v2<0, 2><<<dim3(1024), blk, 0, stream>>>(xT, w_pre, bn_pre, 256, preT, nullptr);
  // 2. dilated 3x3 convs + bn (MFMA) -> bufB fp32 NCHW
  k_dilconv_mfma<1, 86><<<dim3(32, 2, 8), blk, 0, stream>>>(preT, w_l1, bn_l1, bufB, 0, 0);
  k_dilconv_mfma<2, 86><<<dim3(32, 2, 8), blk, 0, stream>>>(preT, w_l2, bn_l2, bufB, 86, 80);
  k_dilconv_mfma<3, 84><<<dim3(32, 2, 8), blk, 0, stream>>>(preT, w_l3, bn_l3, bufB, 172, 160);
  // 3. qkv 1x1 conv -> bufQ window-layout bf16 (MFMA, X-resident, win-major px)
  k_gemm_v2<3, 6><<<dim3(1024), blk, 0, stream>>>(xT, w_qkv, nullptr, 768, bufQ, nullptr);
  // 4. windowed attention -> attnO bf16 NCHW (overwrites preT; safe)
  k_attn<<<dim3(256, 8), blk, 0, stream>>>(bufQ, rpb, attnO);
  // 5. pools + residual combine (in-place on bufB)
  k_pool<<<dim3(4096), blk, 0, stream>>>(attnO, bufB);
  // 6. depthwise 8x8 -> bufDw fp32 NCHW (overwrites bufQ; safe)
  k_dw<<<dim3(4096), blk, 0, stream>>>(bufB, w_dw, bufDw);
  // 7. cast dw-out -> NHWC bf16 (overwrites xT; safe)
  k_cast<<<dim3(1024), blk, 0, stream>>>(bufDw, dwT);
  // 8. pw 1x1 conv + bn -> out fp32 NCHW (MFMA, X-resident)
  k_gemm_v2<2, 2><<<dim3(1024), blk, 0, stream>>>(dwT, w_pw, bn_pj, 256, nullptr, out);

  (void)in_sizes; (void)n_in; (void)out_size; (void)ws_size;
}

// Round 7
// 1005.635 us; speedup vs baseline: 4.3299x; 1.0769x over previous
//
#include <hip/hip_runtime.h>
#include <hip/hip_bf16.h>
#include <cstdint>
#include <cstddef>

namespace {

constexpr int HW = 16384;   // 128*128

typedef short vec8s __attribute__((ext_vector_type(8)));
typedef float f32x4 __attribute__((ext_vector_type(4)));

__device__ __forceinline__ float u2f(uint32_t u){ union { uint32_t u; float f; } v; v.u = u; return v.f; }
__device__ __forceinline__ uint32_t f2u(float f){ union { float f; uint32_t u; } v; v.f = f; return v.u; }
__device__ __forceinline__ uint16_t f2bf(float f){
  uint32_t u = f2u(f);
  u += 0x7fffu + ((u >> 16) & 1u);   // round-to-nearest-even
  return (uint16_t)(u >> 16);
}
__device__ __forceinline__ void unpack2(uint32_t w, float& lo, float& hi){
  lo = u2f(w << 16);
  hi = u2f(w & 0xffff0000u);
}

// ---------------------------------------------------------------------------
// Cast NCHW fp32 (256 ch) -> NHWC bf16. Block = one (b, row).
// ---------------------------------------------------------------------------
__global__ __launch_bounds__(256) void k_cast(
    const float* __restrict__ x, uint16_t* __restrict__ xT)
{
  __shared__ float sF[64][129];
  const int t = threadIdx.x;
  const int b = blockIdx.x >> 7;
  const int y = blockIdx.x & 127;
  const size_t rowoff = (size_t)y * 128;
  for (int cc = 0; cc < 4; ++cc) {
    const int cic0 = cc * 64;
    #pragma unroll
    for (int k = 0; k < 8; ++k) {
      int e = t + k * 256;
      int ci = e >> 5;
      int pxq = (e & 31) * 4;
      float4 v = *(const float4*)(x + (size_t)(b * 256 + cic0 + ci) * HW + rowoff + pxq);
      sF[ci][pxq] = v.x; sF[ci][pxq+1] = v.y; sF[ci][pxq+2] = v.z; sF[ci][pxq+3] = v.w;
    }
    __syncthreads();
    {
      int px = t >> 1, h = t & 1;
      __align__(16) uint16_t tmp[32];
      #pragma unroll
      for (int j = 0; j < 32; ++j) tmp[j] = f2bf(sF[h * 32 + j][px]);
      uint16_t* dst = xT + ((size_t)b * HW + rowoff + px) * 256 + cic0 + h * 32;
      *(uint4*)(dst)      = *(uint4*)&tmp[0];
      *(uint4*)(dst + 8)  = *(uint4*)&tmp[8];
      *(uint4*)(dst + 16) = *(uint4*)&tmp[16];
      *(uint4*)(dst + 24) = *(uint4*)&tmp[24];
    }
    __syncthreads();
  }
}

// ---------------------------------------------------------------------------
// 1x1 conv via bf16 MFMA, X-resident co-loop version (unchanged from r6).
// ---------------------------------------------------------------------------
template<int OUT_MODE, int NCO>
__global__ __launch_bounds__(256) void k_gemm_v2(
    const uint16_t* __restrict__ xT, const float* __restrict__ wmat,
    const float* __restrict__ bnp, int M,
    uint16_t* __restrict__ outb, float* __restrict__ outf)
{
  __shared__ __align__(16) uint16_t sX[128][260];
  __shared__ __align__(16) uint16_t sW[128][36];
  const int t = threadIdx.x;
  const int b    = blockIdx.x >> 7;
  const int tile = blockIdx.x & 127;
  const int l = t & 63, w = t >> 6;
  const int l15 = l & 15, koct = l >> 4;
  const int wc = w >> 1, wp = w & 1;

  {
    const int spx = t >> 1, sh = t & 1;
    int gpx;
    if constexpr (OUT_MODE == 3) {
      int win = tile * 2 + (spx >> 6);
      int p = spx & 63;
      gpx = ((win >> 4) * 8 + (p >> 3)) * 128 + (win & 15) * 8 + (p & 7);
    } else {
      gpx = tile * 128 + spx;
    }
    const uint16_t* src = xT + ((size_t)b * HW + gpx) * 256 + sh * 128;
    uint16_t* dst = &sX[spx][sh * 128];
    #pragma unroll
    for (int i = 0; i < 16; ++i)
      *(uint4*)(dst + i * 8) = *(const uint4*)(src + i * 8);
  }

  const int swc = t >> 1, swh = t & 1;
  float4 wr0, wr1, wr2, wr3;
  {
    const float* p = wmat + (size_t)swc * 256 + swh * 16;
    wr0 = *(const float4*)(p);     wr1 = *(const float4*)(p + 4);
    wr2 = *(const float4*)(p + 8); wr3 = *(const float4*)(p + 12);
  }
  __syncthreads();

  for (int cc = 0; cc < NCO; ++cc) {
    f32x4 acc[4][4];
    #pragma unroll
    for (int cf = 0; cf < 4; ++cf)
      #pragma unroll
      for (int pf = 0; pf < 4; ++pf) acc[cf][pf] = (f32x4){0.f,0.f,0.f,0.f};

    for (int kc = 0; kc < 8; ++kc) {
      if (cc | kc) __syncthreads();
      {
        __align__(16) uint16_t tmp[16];
        tmp[0]=f2bf(wr0.x); tmp[1]=f2bf(wr0.y); tmp[2]=f2bf(wr0.z); tmp[3]=f2bf(wr0.w);
        tmp[4]=f2bf(wr1.x); tmp[5]=f2bf(wr1.y); tmp[6]=f2bf(wr1.z); tmp[7]=f2bf(wr1.w);
        tmp[8]=f2bf(wr2.x); tmp[9]=f2bf(wr2.y); tmp[10]=f2bf(wr2.z); tmp[11]=f2bf(wr2.w);
        tmp[12]=f2bf(wr3.x); tmp[13]=f2bf(wr3.y); tmp[14]=f2bf(wr3.z); tmp[15]=f2bf(wr3.w);
        uint16_t* dst = &sW[swc][swh * 16];
        *(uint4*)(dst)     = *(uint4*)&tmp[0];
        *(uint4*)(dst + 8) = *(uint4*)&tmp[8];
      }
      {
        int nkc = kc + 1, ncc = cc;
        if (nkc == 8) { nkc = 0; ncc = cc + 1; }
        if (ncc < NCO) {
          const float* p = wmat + (size_t)(ncc * 128 + swc) * 256 + nkc * 32 + swh * 16;
          wr0 = *(const float4*)(p);     wr1 = *(const float4*)(p + 4);
          wr2 = *(const float4*)(p + 8); wr3 = *(const float4*)(p + 12);
        }
      }
      __syncthreads();
      vec8s bf[4];
      #pragma unroll
      for (int pf = 0; pf < 4; ++pf)
        bf[pf] = *(const vec8s*)&sX[wp * 64 + pf * 16 + l15][kc * 32 + koct * 8];
      #pragma unroll
      for (int cf = 0; cf < 4; ++cf) {
        vec8s af = *(const vec8s*)&sW[wc * 64 + cf * 16 + l15][koct * 8];
        #pragma unroll
        for (int pf = 0; pf < 4; ++pf)
          acc[cf][pf] = __builtin_amdgcn_mfma_f32_16x16x32_bf16(af, bf[pf], acc[cf][pf], 0, 0, 0);
      }
    }

    #pragma unroll
    for (int cf = 0; cf < 4; ++cf) {
      const int cbase = cc * 128 + wc * 64 + cf * 16 + koct * 4;
      float scv[4], shv[4];
      #pragma unroll
      for (int r = 0; r < 4; ++r) {
        scv[r] = 1.f; shv[r] = 0.f;
        if constexpr (OUT_MODE == 0 || OUT_MODE == 2) {
          int c = cbase + r;
          float g = bnp[c], be = bnp[M + c], mu = bnp[2 * M + c], va = bnp[3 * M + c];
          scv[r] = g * rsqrtf(va + 1e-5f);
          shv[r] = be - mu * scv[r];
        }
      }
      #pragma unroll
      for (int pf = 0; pf < 4; ++pf) {
        if constexpr (OUT_MODE == 0) {
          int px = tile * 128 + wp * 64 + pf * 16 + l15;
          __align__(8) uint16_t pk[4];
          #pragma unroll
          for (int r = 0; r < 4; ++r)
            pk[r] = f2bf(fmaf(acc[cf][pf][r], scv[r], shv[r]));
          *(uint2*)(outb + ((size_t)b * HW + px) * 256 + cbase) = *(uint2*)pk;
        } else if constexpr (OUT_MODE == 2) {
          int px = tile * 128 + wp * 64 + pf * 16 + l15;
          #pragma unroll
          for (int r = 0; r < 4; ++r)
            outf[(size_t)(b * M + cbase + r) * HW + px] =
                fmaf(acc[cf][pf][r], scv[r], shv[r]);
        } else {
          int win = tile * 2 + wp;
          int p = pf * 16 + l15;
          uint16_t* dstp = outb + ((size_t)(b * 256 + win) * 768 + cbase) * 64 + p;
          #pragma unroll
          for (int r = 0; r < 4; ++r)
            dstp[(size_t)r * 64] = f2bf(acc[cf][pf][r]);
        }
      }
    }
  }
}

// ---------------------------------------------------------------------------
// Dilated 3x3 conv + BN via bf16 MFMA implicit GEMM (unchanged from r3).
// ---------------------------------------------------------------------------
template<int DIL, int CG>
__global__ __launch_bounds__(256) void k_dilconv_mfma(
    const uint16_t* __restrict__ preT, const float* __restrict__ wt,
    const float* __restrict__ bnp, float* __restrict__ out,
    int cb, int cb_al)
{
  constexpr int R = 8 + 2 * DIL;
  constexpr int C = 64 + 2 * DIL;
  constexpr int NPOS = R * C;
  constexpr int NIT = (NPOS + 255) / 256;
  __shared__ __align__(16) uint16_t sX[NPOS * 16];
  __shared__ __align__(16) uint16_t sW[10 * 50 * 16];

  const int t = threadIdx.x;
  const int rt    = blockIdx.x >> 1;
  const int ctile = blockIdx.x & 1;
  const int ct2   = blockIdx.y;
  const int b     = blockIdx.z;
  const int y0 = rt * 8, x0 = ctile * 64;
  const int l = t & 63, w = t >> 6;
  const int l15 = l & 15, oct = (l >> 4) & 1, half = l >> 5;
  const int rbase = w * 2;

  f32x4 acc[3][8];
  #pragma unroll
  for (int cf = 0; cf < 3; ++cf)
    #pragma unroll
    for (int q = 0; q < 8; ++q) acc[cf][q] = (f32x4){0.f,0.f,0.f,0.f};

  for (int kc = 0; kc < 6; ++kc) {
    #pragma unroll
    for (int i = 0; i < 3; ++i) {
      int pair = t + i * 256;
      int co = pair >> 4, ci = pair & 15;
      int cog = ct2 * 48 + co;
      int c = cb_al + kc * 16 + ci;
      bool ok = (cog < CG) && (c >= cb) && (c < cb + CG);
      size_t widx = ok ? ((size_t)cog * (size_t)CG + (size_t)(c - cb)) * 9u
                       : (size_t)0;
      const float* wp = wt + widx;
      uint16_t* dst = &sW[co * 16 + ci];
      #pragma unroll
      for (int tap = 0; tap < 9; ++tap)
        dst[tap * 800] = ok ? f2bf(wp[tap]) : (uint16_t)0;
      dst[9 * 800] = 0;
    }
    #pragma unroll
    for (int i = 0; i < NIT; ++i) {
      int p = t + i * 256;
      if (p < NPOS) {
        int row = p / C, col = p % C;
        int gy = y0 + row - DIL, gx = x0 + col - DIL;
        uint4 va = {0,0,0,0}, vb = {0,0,0,0};
        if ((unsigned)gy < 128u && (unsigned)gx < 128u) {
          const uint4* src = (const uint4*)(preT +
              (((size_t)b * HW + gy * 128 + gx) * 256 + cb_al + kc * 16));
          va = src[0]; vb = src[1];
        }
        uint4* dst = (uint4*)&sX[p * 16];
        dst[0] = va; dst[1] = vb;
      }
    }
    __syncthreads();

    #pragma unroll
    for (int s = 0; s < 5; ++s) {
      const int tap0 = 2 * s, tap1 = 2 * s + 1;
      const int dy0 = tap0 / 3, dx0 = tap0 % 3;
      const int dy1 = (tap1 <= 8) ? tap1 / 3 : 2;
      const int dx1 = (tap1 <= 8) ? tap1 % 3 : 2;
      const int dy = half ? dy1 : dy0;
      const int dx = half ? dx1 : dx0;
      const int atap = tap0 + half;
      vec8s a0 = *(const vec8s*)&sW[(atap * 50 + 0  + l15) * 16 + oct * 8];
      vec8s a1 = *(const vec8s*)&sW[(atap * 50 + 16 + l15) * 16 + oct * 8];
      vec8s a2 = *(const vec8s*)&sW[(atap * 50 + 32 + l15) * 16 + oct * 8];
      #pragma unroll
      for (int rs = 0; rs < 2; ++rs) {
        const int rowin = rbase + rs + dy * DIL;
        #pragma unroll
        for (int c4 = 0; c4 < 4; ++c4) {
          const int colin = c4 * 16 + l15 + dx * DIL;
          vec8s bf = *(const vec8s*)&sX[(rowin * C + colin) * 16 + oct * 8];
          acc[0][rs*4+c4] = __builtin_amdgcn_mfma_f32_16x16x32_bf16(a0, bf, acc[0][rs*4+c4], 0, 0, 0);
          acc[1][rs*4+c4] = __builtin_amdgcn_mfma_f32_16x16x32_bf16(a1, bf, acc[1][rs*4+c4], 0, 0, 0);
          acc[2][rs*4+c4] = __builtin_amdgcn_mfma_f32_16x16x32_bf16(a2, bf, acc[2][rs*4+c4], 0, 0, 0);
        }
      }
    }
    __syncthreads();
  }

  const int row4 = (l >> 4);
  #pragma unroll
  for (int cf = 0; cf < 3; ++cf) {
    #pragma unroll
    for (int r = 0; r < 4; ++r) {
      int c_loc = ct2 * 48 + cf * 16 + row4 * 4 + r;
      if (c_loc < CG) {
        int cg = cb + c_loc;
        float g = bnp[c_loc], be = bnp[CG + c_loc];
        float mu = bnp[2 * CG + c_loc], va = bnp[3 * CG + c_loc];
        float scv = g * rsqrtf(va + 1e-5f);
        float shv = be - mu * scv;
        #pragma unroll
        for (int rs = 0; rs < 2; ++rs) {
          int y = y0 + rbase + rs;
          #pragma unroll
          for (int c4 = 0; c4 < 4; ++c4) {
            int x = x0 + c4 * 16 + l15;
            out[(size_t)(b * 256 + cg) * HW + y * 128 + x] =
                fmaf(acc[cf][rs*4+c4][r], scv, shv);
          }
        }
      }
    }
  }
}

// ---------------------------------------------------------------------------
// Windowed attention, wave-autonomous (ZERO block barriers).
// qkvW[b][win][c(768)][p(64)] bf16. Block = 1 window, wave w owns head
// w+4*it. Per wave: K,V -> private LDS fp32 [j][dd] (pad 20); Q in regs;
// lane = query pixel; dots/softmax/PV fully in-lane; O transposed through
// LDS (overlay on dead sK) -> 16B-run NCHW bf16 stores.
// Wave-local LDS ordering via s_waitcnt lgkmcnt(0) (no __syncthreads).
// ---------------------------------------------------------------------------
__global__ __launch_bounds__(256) void k_attn(
    const uint16_t* __restrict__ qkvW, const float* __restrict__ rpb,
    uint16_t* __restrict__ outp)
{
  __shared__ float sKV[4][2][64][20];   // [wave][K/V][j][dd(pad20)] fp32
  __shared__ float sB[4][228];          // per-wave bias
  const int t = threadIdx.x;
  const int l = t & 63, w = t >> 6;
  const int b = blockIdx.y;
  const int win = blockIdx.x;
  const int wy = win >> 4, wx = win & 15;
  const int wbase = (wy * 8) * 128 + wx * 8;
  const uint16_t* base = qkvW + (size_t)(b * 256 + win) * 49152;
  float* swK = &sKV[w][0][0][0];
  float* swV = &sKV[w][1][0][0];
  float* swB = &sB[w][0];
  const int irow = l >> 3, icol = l & 7;
  const int bias_base = irow * 15 + icol + 112;

  for (int it = 0; it < 4; ++it) {
    const int n = w + it * 4;
    // ---- stage bias (225), K,V transposed fp32; Q -> regs ----
    #pragma unroll
    for (int m = 0; m < 4; ++m) {
      int e = l + m * 64;
      if (e < 225) swB[e] = rpb[e * 16 + n];
    }
    const uint16_t* qg = base + (size_t)(n * 16) * 64;
    const uint16_t* kg = base + (size_t)(256 + n * 16) * 64;
    const uint16_t* vg = base + (size_t)(512 + n * 16) * 64;
    #pragma unroll
    for (int m = 0; m < 16; ++m) {
      swK[l * 20 + m] = u2f((uint32_t)kg[m * 64 + l] << 16);
      swV[l * 20 + m] = u2f((uint32_t)vg[m * 64 + l] << 16);
    }
    float q[16];
    #pragma unroll
    for (int m = 0; m < 16; ++m) q[m] = u2f((uint32_t)qg[m * 64 + l] << 16);
    asm volatile("s_waitcnt lgkmcnt(0)" ::: "memory");   // wave-local: LDS visible

    // ---- dots: S[j] for all 64 keys, fully in-lane ----
    float P[64];
    #pragma unroll
    for (int j = 0; j < 64; ++j) {
      const float* kr = &swK[j * 20];
      float4 k0 = *(const float4*)(kr);
      float4 k1 = *(const float4*)(kr + 4);
      float4 k2 = *(const float4*)(kr + 8);
      float4 k3 = *(const float4*)(kr + 12);
      float s;
      s  = q[0]*k0.x + q[1]*k0.y + q[2]*k0.z + q[3]*k0.w;
      s += q[4]*k1.x + q[5]*k1.y + q[6]*k1.z + q[7]*k1.w;
      s += q[8]*k2.x + q[9]*k2.y + q[10]*k2.z + q[11]*k2.w;
      s += q[12]*k3.x + q[13]*k3.y + q[14]*k3.z + q[15]*k3.w;
      P[j] = fmaf(s, 0.25f, swB[bias_base - ((j >> 3) * 15 + (j & 7))]);
    }
    // ---- softmax in-lane (no shuffles) ----
    float mx = P[0];
    #pragma unroll
    for (int j = 1; j < 64; ++j) mx = fmaxf(mx, P[j]);
    float sum = 0.f;
    #pragma unroll
    for (int j = 0; j < 64; ++j) { P[j] = __expf(P[j] - mx); sum += P[j]; }
    const float sinv = 1.f / sum;
    // ---- PV in-lane ----
    float O[16];
    #pragma unroll
    for (int m = 0; m < 16; ++m) O[m] = 0.f;
    #pragma unroll
    for (int j = 0; j < 64; ++j) {
      const float* vr = &swV[j * 20];
      float4 v0 = *(const float4*)(vr);
      float4 v1 = *(const float4*)(vr + 4);
      float4 v2 = *(const float4*)(vr + 8);
      float4 v3 = *(const float4*)(vr + 12);
      const float pj = P[j];
      O[0]  = fmaf(pj, v0.x, O[0]);  O[1]  = fmaf(pj, v0.y, O[1]);
      O[2]  = fmaf(pj, v0.z, O[2]);  O[3]  = fmaf(pj, v0.w, O[3]);
      O[4]  = fmaf(pj, v1.x, O[4]);  O[5]  = fmaf(pj, v1.y, O[5]);
      O[6]  = fmaf(pj, v1.z, O[6]);  O[7]  = fmaf(pj, v1.w, O[7]);
      O[8]  = fmaf(pj, v2.x, O[8]);  O[9]  = fmaf(pj, v2.y, O[9]);
      O[10] = fmaf(pj, v2.z, O[10]); O[11] = fmaf(pj, v2.w, O[11]);
      O[12] = fmaf(pj, v3.x, O[12]); O[13] = fmaf(pj, v3.y, O[13]);
      O[14] = fmaf(pj, v3.z, O[14]); O[15] = fmaf(pj, v3.w, O[15]);
    }
    // ---- O -> LDS transpose (overlay dead sK region), 16B-run stores ----
    float* swO = swK;   // sK reads fully consumed into P; safe to overwrite
    #pragma unroll
    for (int m = 0; m < 16; ++m) swO[m * 76 + l] = O[m] * sinv;
    asm volatile("s_waitcnt lgkmcnt(0)" ::: "memory");
    #pragma unroll
    for (int e2 = 0; e2 < 2; ++e2) {
      int e = l + e2 * 64;
      int dd = e >> 3, row = e & 7;
      const float* orow = &swO[dd * 76 + row * 8];
      float4 a = *(const float4*)(orow);
      float4 c = *(const float4*)(orow + 4);
      uint4 pk;
      pk.x = (uint32_t)f2bf(a.x) | ((uint32_t)f2bf(a.y) << 16);
      pk.y = (uint32_t)f2bf(a.z) | ((uint32_t)f2bf(a.w) << 16);
      pk.z = (uint32_t)f2bf(c.x) | ((uint32_t)f2bf(c.y) << 16);
      pk.w = (uint32_t)f2bf(c.z) | ((uint32_t)f2bf(c.w) << 16);
      *(uint4*)(outp + (size_t)(b * 256 + n * 16 + dd) * HW + wbase + row * 128) = pk;
    }
    // next iteration's staging writes depend on completed reads (data already
    // consumed into registers before the stores above issue) — no hazard.
  }
}

// ---------------------------------------------------------------------------
// combined = avgpool_v(attn) + avgpool_h(attn) + local (in-place into loc)
// ---------------------------------------------------------------------------
__global__ __launch_bounds__(256) void k_pool(
    const uint16_t* __restrict__ attnb, float* __restrict__ loc)
{
  __shared__ __align__(16) float sP[71][132];
  const int t = threadIdx.x;
  const int plane = blockIdx.x >> 1;
  const int h0 = (blockIdx.x & 1) * 64;
  const size_t pbase = (size_t)plane * HW;
  for (int k = 0; k < 5; ++k) {
    int idx = t + k * 256;
    if (idx < 71 * 16) {
      int lr = idx >> 4, c8 = (idx & 15) * 8;
      int g = h0 - 3 + lr;
      if (g >= 0 && g <= 127) {
        uint4 v4 = *(const uint4*)(attnb + pbase + (size_t)g * 128 + c8);
        float f[8];
        unpack2(v4.x, f[0], f[1]); unpack2(v4.y, f[2], f[3]);
        unpack2(v4.z, f[4], f[5]); unpack2(v4.w, f[6], f[7]);
        #pragma unroll
        for (int j = 0; j < 8; ++j) sP[lr][c8 + j] = f[j];
      }
    }
  }
  __syncthreads();
  for (int k = 0; k < 32; ++k) {
    int idx = t + k * 256;
    int lh = idx >> 7, w = idx & 127;
    int h = h0 + lh;
    float ax = 0.f;
    #pragma unroll
    for (int o = -3; o <= 4; ++o) {
      int j = h + o;
      if (j >= 0 && j <= 128) {
        int jr = (j == 128) ? 126 : j;
        ax += sP[jr - h0 + 3][w];
      }
    }
    float ay = 0.f;
    #pragma unroll
    for (int o = -3; o <= 4; ++o) {
      int j = w + o;
      if (j >= 0 && j <= 128) {
        int jr = (j == 128) ? 126 : j;
        ay += sP[lh + 3][jr];
      }
    }
    size_t gi = pbase + (size_t)h * 128 + w;
    loc[gi] = fmaf(ax + ay, 0.125f, loc[gi]);
  }
}

// ---------------------------------------------------------------------------
// Depthwise 8x8 conv on reflect(+1)-padded combined, zero pad 3.
// ---------------------------------------------------------------------------
__global__ __launch_bounds__(256) void k_dw(
    const float* __restrict__ comb, const float* __restrict__ wdw,
    float* __restrict__ out)
{
  __shared__ __align__(16) float sZ[71][140];
  __shared__ float sWd[64];
  const int t = threadIdx.x;
  const int plane = blockIdx.x >> 1;
  const int cch = plane & 255;
  const int h0 = (blockIdx.x & 1) * 64;
  const size_t pbase = (size_t)plane * HW;
  if (t < 64) sWd[t] = wdw[cch * 64 + t];
  for (int k = 0; k < 38; ++k) {
    int idx = t + k * 256;
    if (idx < 71 * 136) {
      int u = idx / 136, vc = idx - u * 136;
      int g = h0 - 3 + u;
      if (g >= 0 && g <= 128) {
        int bb = vc - 3;
        float v = 0.f;
        if (bb >= 0 && bb <= 128) {
          int gr = (g == 128) ? 126 : g;
          int br = (bb == 128) ? 126 : bb;
          v = comb[pbase + gr * 128 + br];
        }
        sZ[u][vc] = v;
      }
    }
  }
  __syncthreads();
  const int wg = t & 7, hl = t >> 3;
  const int w0 = wg * 16;
  float acc[2][16];
  #pragma unroll
  for (int a = 0; a < 2; ++a)
    #pragma unroll
    for (int p = 0; p < 16; ++p) acc[a][p] = 0.f;
  #pragma unroll 1
  for (int i = 0; i < 8; ++i) {
    float wrow[8];
    *(float4*)&wrow[0] = *(const float4*)&sWd[i * 8];
    *(float4*)&wrow[4] = *(const float4*)&sWd[i * 8 + 4];
    #pragma unroll
    for (int hi = 0; hi < 2; ++hi) {
      int h = h0 + hl + 32 * hi;
      int u = h + i - 3;
      bool ok = (u >= 0 && u <= 128);
      int lr = ok ? (u - h0 + 3) : 0;
      const float* zr = &sZ[lr][w0];
      float win[24];
      *(float4*)&win[0]  = *(const float4*)(zr);
      *(float4*)&win[4]  = *(const float4*)(zr + 4);
      *(float4*)&win[8]  = *(const float4*)(zr + 8);
      *(float4*)&win[12] = *(const float4*)(zr + 12);
      *(float4*)&win[16] = *(const float4*)(zr + 16);
      *(float4*)&win[20] = *(const float4*)(zr + 20);
      float m = ok ? 1.f : 0.f;
      float wv[8];
      #pragma unroll
      for (int j = 0; j < 8; ++j) wv[j] = wrow[j] * m;
      #pragma unroll
      for (int p = 0; p < 16; ++p)
        #pragma unroll
        for (int j = 0; j < 8; ++j)
          acc[hi][p] = fmaf(wv[j], win[p + j], acc[hi][p]);
    }
  }
  #pragma unroll
  for (int hi = 0; hi < 2; ++hi) {
    int h = h0 + hl + 32 * hi;
    float* dst = out + pbase + (size_t)h * 128 + w0;
    float4 o0 = {acc[hi][0],  acc[hi][1],  acc[hi][2],  acc[hi][3]};
    float4 o1 = {acc[hi][4],  acc[hi][5],  acc[hi][6],  acc[hi][7]};
    float4 o2 = {acc[hi][8],  acc[hi][9],  acc[hi][10], acc[hi][11]};
    float4 o3 = {acc[hi][12], acc[hi][13], acc[hi][14], acc[hi][15]};
    *(float4*)(dst)      = o0;
    *(float4*)(dst + 4)  = o1;
    *(float4*)(dst + 8)  = o2;
    *(float4*)(dst + 12) = o3;
  }
}

} // namespace

extern "C" void kernel_launch(void* const* d_in, const int* in_sizes, int n_in,
                              void* d_out, int out_size, void* d_ws, size_t ws_size,
                              hipStream_t stream)
{
  const float* x      = (const float*)d_in[0];
  const float* w_pre  = (const float*)d_in[1];
  const float* bn_pre = (const float*)d_in[2];
  const float* w_l1   = (const float*)d_in[3];
  const float* bn_l1  = (const float*)d_in[4];
  const float* w_l2   = (const float*)d_in[5];
  const float* bn_l2  = (const float*)d_in[6];
  const float* w_l3   = (const float*)d_in[7];
  const float* bn_l3  = (const float*)d_in[8];
  const float* w_qkv  = (const float*)d_in[9];
  const float* rpb    = (const float*)d_in[10];
  const float* w_dw   = (const float*)d_in[11];
  const float* w_pw   = (const float*)d_in[12];
  const float* bn_pj  = (const float*)d_in[13];
  float* out = (float*)d_out;

  char* base = (char*)d_ws;
  uint16_t* xT    = (uint16_t*)base;                          // 64 MiB NHWC bf16 x; later dwT
  uint16_t* preT  = (uint16_t*)(base + (size_t)67108864);     // 64 MiB NHWC bf16 pre; later attn out
  float*    bufB  = (float*)(base + (size_t)134217728);       // 128 MiB fp32 local/combined
  uint16_t* bufQ  = (uint16_t*)(base + (size_t)268435456);    // 192 MiB bf16 qkv windows; later dw out
  uint16_t* attnO = preT;
  float*    bufDw = (float*)bufQ;
  uint16_t* dwT   = xT;

  dim3 blk(256);
  // 0. cast x -> NHWC bf16
  k_cast<<<dim3(1024), blk, 0, stream>>>(x, xT);
  // 1. pre 1x1 conv + bn -> NHWC bf16 (MFMA, X-resident)
  k_gemm_v2<0, 2><<<dim3(1024), blk, 0, stream>>>(xT, w_pre, bn_pre, 256, preT, nullptr);
  // 2. dilated 3x3 convs + bn (MFMA) -> bufB fp32 NCHW
  k_dilconv_mfma<1, 86><<<dim3(32, 2, 8), blk, 0, stream>>>(preT, w_l1, bn_l1, bufB, 0, 0);
  k_dilconv_mfma<2, 86><<<dim3(32, 2, 8), blk, 0, stream>>>(preT, w_l2, bn_l2, bufB, 86, 80);
  k_dilconv_mfma<3, 84><<<dim3(32, 2, 8), blk, 0, stream>>>(preT, w_l3, bn_l3, bufB, 172, 160);
  // 3. qkv 1x1 conv -> bufQ window-layout bf16 (MFMA, X-resident, win-major px)
  k_gemm_v2<3, 6><<<dim3(1024), blk, 0, stream>>>(xT, w_qkv, nullptr, 768, bufQ, nullptr);
  // 4. windowed attention -> attnO bf16 NCHW (overwrites preT; safe)
  k_attn<<<dim3(256, 8), blk, 0, stream>>>(bufQ, rpb, attnO);
  // 5. pools + residual combine (in-place on bufB)
  k_pool<<<dim3(4096), blk, 0, stream>>>(attnO, bufB);
  // 6. depthwise 8x8 -> bufDw fp32 NCHW (overwrites bufQ; safe)
  k_dw<<<dim3(4096), blk, 0, stream>>>(bufB, w_dw, bufDw);
  // 7. cast dw-out -> NHWC bf16 (overwrites xT; safe)
  k_cast<<<dim3(1024), blk, 0, stream>>>(bufDw, dwT);
  // 8. pw 1x1 conv + bn -> out fp32 NCHW (MFMA, X-resident)
  k_gemm_v2<2, 2><<<dim3(1024), blk, 0, stream>>>(dwT, w_pw, bn_pj, 256, nullptr, out);

  (void)in_sizes; (void)n_in; (void)out_size; (void)ws_size;
}

// Round 8
// 952.788 us; speedup vs baseline: 4.5701x; 1.0555x over previous
//
#include <hip/hip_runtime.h>
#include <hip/hip_bf16.h>
#include <cstdint>
#include <cstddef>

namespace {

constexpr int HW = 16384;   // 128*128

typedef short vec8s __attribute__((ext_vector_type(8)));
typedef float f32x4 __attribute__((ext_vector_type(4)));

__device__ __forceinline__ float u2f(uint32_t u){ union { uint32_t u; float f; } v; v.u = u; return v.f; }
__device__ __forceinline__ uint32_t f2u(float f){ union { float f; uint32_t u; } v; v.f = f; return v.u; }
__device__ __forceinline__ uint16_t f2bf(float f){
  uint32_t u = f2u(f);
  u += 0x7fffu + ((u >> 16) & 1u);   // round-to-nearest-even
  return (uint16_t)(u >> 16);
}
__device__ __forceinline__ void unpack2(uint32_t w, float& lo, float& hi){
  lo = u2f(w << 16);
  hi = u2f(w & 0xffff0000u);
}

// ---------------------------------------------------------------------------
// Cast NCHW fp32 (256 ch) -> NHWC bf16. Block = one (b, row).
// ---------------------------------------------------------------------------
__global__ __launch_bounds__(256) void k_cast(
    const float* __restrict__ x, uint16_t* __restrict__ xT)
{
  __shared__ float sF[64][129];
  const int t = threadIdx.x;
  const int b = blockIdx.x >> 7;
  const int y = blockIdx.x & 127;
  const size_t rowoff = (size_t)y * 128;
  for (int cc = 0; cc < 4; ++cc) {
    const int cic0 = cc * 64;
    #pragma unroll
    for (int k = 0; k < 8; ++k) {
      int e = t + k * 256;
      int ci = e >> 5;
      int pxq = (e & 31) * 4;
      float4 v = *(const float4*)(x + (size_t)(b * 256 + cic0 + ci) * HW + rowoff + pxq);
      sF[ci][pxq] = v.x; sF[ci][pxq+1] = v.y; sF[ci][pxq+2] = v.z; sF[ci][pxq+3] = v.w;
    }
    __syncthreads();
    {
      int px = t >> 1, h = t & 1;
      __align__(16) uint16_t tmp[32];
      #pragma unroll
      for (int j = 0; j < 32; ++j) tmp[j] = f2bf(sF[h * 32 + j][px]);
      uint16_t* dst = xT + ((size_t)b * HW + rowoff + px) * 256 + cic0 + h * 32;
      *(uint4*)(dst)      = *(uint4*)&tmp[0];
      *(uint4*)(dst + 8)  = *(uint4*)&tmp[8];
      *(uint4*)(dst + 16) = *(uint4*)&tmp[16];
      *(uint4*)(dst + 24) = *(uint4*)&tmp[24];
    }
    __syncthreads();
  }
}

// ---------------------------------------------------------------------------
// 1x1 conv via bf16 MFMA, X-resident co-loop version (unchanged from r6).
// ---------------------------------------------------------------------------
template<int OUT_MODE, int NCO>
__global__ __launch_bounds__(256) void k_gemm_v2(
    const uint16_t* __restrict__ xT, const float* __restrict__ wmat,
    const float* __restrict__ bnp, int M,
    uint16_t* __restrict__ outb, float* __restrict__ outf)
{
  __shared__ __align__(16) uint16_t sX[128][260];
  __shared__ __align__(16) uint16_t sW[128][36];
  const int t = threadIdx.x;
  const int b    = blockIdx.x >> 7;
  const int tile = blockIdx.x & 127;
  const int l = t & 63, w = t >> 6;
  const int l15 = l & 15, koct = l >> 4;
  const int wc = w >> 1, wp = w & 1;

  {
    const int spx = t >> 1, sh = t & 1;
    int gpx;
    if constexpr (OUT_MODE == 3) {
      int win = tile * 2 + (spx >> 6);
      int p = spx & 63;
      gpx = ((win >> 4) * 8 + (p >> 3)) * 128 + (win & 15) * 8 + (p & 7);
    } else {
      gpx = tile * 128 + spx;
    }
    const uint16_t* src = xT + ((size_t)b * HW + gpx) * 256 + sh * 128;
    uint16_t* dst = &sX[spx][sh * 128];
    #pragma unroll
    for (int i = 0; i < 16; ++i)
      *(uint4*)(dst + i * 8) = *(const uint4*)(src + i * 8);
  }

  const int swc = t >> 1, swh = t & 1;
  float4 wr0, wr1, wr2, wr3;
  {
    const float* p = wmat + (size_t)swc * 256 + swh * 16;
    wr0 = *(const float4*)(p);     wr1 = *(const float4*)(p + 4);
    wr2 = *(const float4*)(p + 8); wr3 = *(const float4*)(p + 12);
  }
  __syncthreads();

  for (int cc = 0; cc < NCO; ++cc) {
    f32x4 acc[4][4];
    #pragma unroll
    for (int cf = 0; cf < 4; ++cf)
      #pragma unroll
      for (int pf = 0; pf < 4; ++pf) acc[cf][pf] = (f32x4){0.f,0.f,0.f,0.f};

    for (int kc = 0; kc < 8; ++kc) {
      if (cc | kc) __syncthreads();
      {
        __align__(16) uint16_t tmp[16];
        tmp[0]=f2bf(wr0.x); tmp[1]=f2bf(wr0.y); tmp[2]=f2bf(wr0.z); tmp[3]=f2bf(wr0.w);
        tmp[4]=f2bf(wr1.x); tmp[5]=f2bf(wr1.y); tmp[6]=f2bf(wr1.z); tmp[7]=f2bf(wr1.w);
        tmp[8]=f2bf(wr2.x); tmp[9]=f2bf(wr2.y); tmp[10]=f2bf(wr2.z); tmp[11]=f2bf(wr2.w);
        tmp[12]=f2bf(wr3.x); tmp[13]=f2bf(wr3.y); tmp[14]=f2bf(wr3.z); tmp[15]=f2bf(wr3.w);
        uint16_t* dst = &sW[swc][swh * 16];
        *(uint4*)(dst)     = *(uint4*)&tmp[0];
        *(uint4*)(dst + 8) = *(uint4*)&tmp[8];
      }
      {
        int nkc = kc + 1, ncc = cc;
        if (nkc == 8) { nkc = 0; ncc = cc + 1; }
        if (ncc < NCO) {
          const float* p = wmat + (size_t)(ncc * 128 + swc) * 256 + nkc * 32 + swh * 16;
          wr0 = *(const float4*)(p);     wr1 = *(const float4*)(p + 4);
          wr2 = *(const float4*)(p + 8); wr3 = *(const float4*)(p + 12);
        }
      }
      __syncthreads();
      vec8s bf[4];
      #pragma unroll
      for (int pf = 0; pf < 4; ++pf)
        bf[pf] = *(const vec8s*)&sX[wp * 64 + pf * 16 + l15][kc * 32 + koct * 8];
      #pragma unroll
      for (int cf = 0; cf < 4; ++cf) {
        vec8s af = *(const vec8s*)&sW[wc * 64 + cf * 16 + l15][koct * 8];
        #pragma unroll
        for (int pf = 0; pf < 4; ++pf)
          acc[cf][pf] = __builtin_amdgcn_mfma_f32_16x16x32_bf16(af, bf[pf], acc[cf][pf], 0, 0, 0);
      }
    }

    #pragma unroll
    for (int cf = 0; cf < 4; ++cf) {
      const int cbase = cc * 128 + wc * 64 + cf * 16 + koct * 4;
      float scv[4], shv[4];
      #pragma unroll
      for (int r = 0; r < 4; ++r) {
        scv[r] = 1.f; shv[r] = 0.f;
        if constexpr (OUT_MODE == 0 || OUT_MODE == 2) {
          int c = cbase + r;
          float g = bnp[c], be = bnp[M + c], mu = bnp[2 * M + c], va = bnp[3 * M + c];
          scv[r] = g * rsqrtf(va + 1e-5f);
          shv[r] = be - mu * scv[r];
        }
      }
      #pragma unroll
      for (int pf = 0; pf < 4; ++pf) {
        if constexpr (OUT_MODE == 0) {
          int px = tile * 128 + wp * 64 + pf * 16 + l15;
          __align__(8) uint16_t pk[4];
          #pragma unroll
          for (int r = 0; r < 4; ++r)
            pk[r] = f2bf(fmaf(acc[cf][pf][r], scv[r], shv[r]));
          *(uint2*)(outb + ((size_t)b * HW + px) * 256 + cbase) = *(uint2*)pk;
        } else if constexpr (OUT_MODE == 2) {
          int px = tile * 128 + wp * 64 + pf * 16 + l15;
          #pragma unroll
          for (int r = 0; r < 4; ++r)
            outf[(size_t)(b * M + cbase + r) * HW + px] =
                fmaf(acc[cf][pf][r], scv[r], shv[r]);
        } else {
          int win = tile * 2 + wp;
          int p = pf * 16 + l15;
          uint16_t* dstp = outb + ((size_t)(b * 256 + win) * 768 + cbase) * 64 + p;
          #pragma unroll
          for (int r = 0; r < 4; ++r)
            dstp[(size_t)r * 64] = f2bf(acc[cf][pf][r]);
        }
      }
    }
  }
}

// ---------------------------------------------------------------------------
// Dilated 3x3 conv + BN via bf16 MFMA implicit GEMM (unchanged from r3).
// ---------------------------------------------------------------------------
template<int DIL, int CG>
__global__ __launch_bounds__(256) void k_dilconv_mfma(
    const uint16_t* __restrict__ preT, const float* __restrict__ wt,
    const float* __restrict__ bnp, float* __restrict__ out,
    int cb, int cb_al)
{
  constexpr int R = 8 + 2 * DIL;
  constexpr int C = 64 + 2 * DIL;
  constexpr int NPOS = R * C;
  constexpr int NIT = (NPOS + 255) / 256;
  __shared__ __align__(16) uint16_t sX[NPOS * 16];
  __shared__ __align__(16) uint16_t sW[10 * 50 * 16];

  const int t = threadIdx.x;
  const int rt    = blockIdx.x >> 1;
  const int ctile = blockIdx.x & 1;
  const int ct2   = blockIdx.y;
  const int b     = blockIdx.z;
  const int y0 = rt * 8, x0 = ctile * 64;
  const int l = t & 63, w = t >> 6;
  const int l15 = l & 15, oct = (l >> 4) & 1, half = l >> 5;
  const int rbase = w * 2;

  f32x4 acc[3][8];
  #pragma unroll
  for (int cf = 0; cf < 3; ++cf)
    #pragma unroll
    for (int q = 0; q < 8; ++q) acc[cf][q] = (f32x4){0.f,0.f,0.f,0.f};

  for (int kc = 0; kc < 6; ++kc) {
    #pragma unroll
    for (int i = 0; i < 3; ++i) {
      int pair = t + i * 256;
      int co = pair >> 4, ci = pair & 15;
      int cog = ct2 * 48 + co;
      int c = cb_al + kc * 16 + ci;
      bool ok = (cog < CG) && (c >= cb) && (c < cb + CG);
      size_t widx = ok ? ((size_t)cog * (size_t)CG + (size_t)(c - cb)) * 9u
                       : (size_t)0;
      const float* wp = wt + widx;
      uint16_t* dst = &sW[co * 16 + ci];
      #pragma unroll
      for (int tap = 0; tap < 9; ++tap)
        dst[tap * 800] = ok ? f2bf(wp[tap]) : (uint16_t)0;
      dst[9 * 800] = 0;
    }
    #pragma unroll
    for (int i = 0; i < NIT; ++i) {
      int p = t + i * 256;
      if (p < NPOS) {
        int row = p / C, col = p % C;
        int gy = y0 + row - DIL, gx = x0 + col - DIL;
        uint4 va = {0,0,0,0}, vb = {0,0,0,0};
        if ((unsigned)gy < 128u && (unsigned)gx < 128u) {
          const uint4* src = (const uint4*)(preT +
              (((size_t)b * HW + gy * 128 + gx) * 256 + cb_al + kc * 16));
          va = src[0]; vb = src[1];
        }
        uint4* dst = (uint4*)&sX[p * 16];
        dst[0] = va; dst[1] = vb;
      }
    }
    __syncthreads();

    #pragma unroll
    for (int s = 0; s < 5; ++s) {
      const int tap0 = 2 * s, tap1 = 2 * s + 1;
      const int dy0 = tap0 / 3, dx0 = tap0 % 3;
      const int dy1 = (tap1 <= 8) ? tap1 / 3 : 2;
      const int dx1 = (tap1 <= 8) ? tap1 % 3 : 2;
      const int dy = half ? dy1 : dy0;
      const int dx = half ? dx1 : dx0;
      const int atap = tap0 + half;
      vec8s a0 = *(const vec8s*)&sW[(atap * 50 + 0  + l15) * 16 + oct * 8];
      vec8s a1 = *(const vec8s*)&sW[(atap * 50 + 16 + l15) * 16 + oct * 8];
      vec8s a2 = *(const vec8s*)&sW[(atap * 50 + 32 + l15) * 16 + oct * 8];
      #pragma unroll
      for (int rs = 0; rs < 2; ++rs) {
        const int rowin = rbase + rs + dy * DIL;
        #pragma unroll
        for (int c4 = 0; c4 < 4; ++c4) {
          const int colin = c4 * 16 + l15 + dx * DIL;
          vec8s bf = *(const vec8s*)&sX[(rowin * C + colin) * 16 + oct * 8];
          acc[0][rs*4+c4] = __builtin_amdgcn_mfma_f32_16x16x32_bf16(a0, bf, acc[0][rs*4+c4], 0, 0, 0);
          acc[1][rs*4+c4] = __builtin_amdgcn_mfma_f32_16x16x32_bf16(a1, bf, acc[1][rs*4+c4], 0, 0, 0);
          acc[2][rs*4+c4] = __builtin_amdgcn_mfma_f32_16x16x32_bf16(a2, bf, acc[2][rs*4+c4], 0, 0, 0);
        }
      }
    }
    __syncthreads();
  }

  const int row4 = (l >> 4);
  #pragma unroll
  for (int cf = 0; cf < 3; ++cf) {
    #pragma unroll
    for (int r = 0; r < 4; ++r) {
      int c_loc = ct2 * 48 + cf * 16 + row4 * 4 + r;
      if (c_loc < CG) {
        int cg = cb + c_loc;
        float g = bnp[c_loc], be = bnp[CG + c_loc];
        float mu = bnp[2 * CG + c_loc], va = bnp[3 * CG + c_loc];
        float scv = g * rsqrtf(va + 1e-5f);
        float shv = be - mu * scv;
        #pragma unroll
        for (int rs = 0; rs < 2; ++rs) {
          int y = y0 + rbase + rs;
          #pragma unroll
          for (int c4 = 0; c4 < 4; ++c4) {
            int x = x0 + c4 * 16 + l15;
            out[(size_t)(b * 256 + cg) * HW + y * 128 + x] =
                fmaf(acc[cf][rs*4+c4][r], scv, shv);
          }
        }
      }
    }
  }
}

// ---------------------------------------------------------------------------
// Windowed attention, wave-autonomous + MFMA.
// qkvW[b][win][c(768)][p(64)] bf16. Block = 1 window, wave w owns head
// w+4*it. Per wave per head:
//   stage K^T,Q^T bf16 [64][40] (dd padded 16->32 with zeros, rows 16B-aligned)
//   QK^T: S[j][i] = 16x mfma_16x16x32 (A=K-frag, B=Q-frag; verified layouts)
//   bias gather + softmax per lane (i=l&15+16ti; j over 16 regs + shfl 16/32)
//   P -> bf16 LDS [i][68]; PV: 8x mfma (A = V^T direct from global 16B runs,
//   B = P-frags via 2x b64); O^T accs -> LDS transpose -> 16B-run NCHW stores.
// No __syncthreads; wave-local ordering via lgkmcnt(0)+sched_barrier.
// ---------------------------------------------------------------------------
__global__ __launch_bounds__(256) void k_attn(
    const uint16_t* __restrict__ qkvW, const float* __restrict__ rpb,
    uint16_t* __restrict__ outp)
{
  // per-wave: KT [0,2560) QT [2560,5120) PT [5120,9472) bias-f32 [9472,9928)
  __shared__ __align__(16) uint16_t sAll[4][9928];
  const int t = threadIdx.x;
  const int l = t & 63, w = t >> 6;
  const int l15 = l & 15, koct = l >> 4;
  const int b = blockIdx.y;
  const int win = blockIdx.x;
  const int wy = win >> 4, wx = win & 15;
  const int wbase = (wy * 8) * 128 + wx * 8;
  const uint16_t* base = qkvW + (size_t)(b * 256 + win) * 49152;
  uint16_t* swKT = &sAll[w][0];
  uint16_t* swQT = &sAll[w][2560];
  uint16_t* swPT = &sAll[w][5120];
  float*    swB  = (float*)&sAll[w][9472];
  float*    swO  = (float*)swPT;   // overlay after PV consumes PT

  // zero dd=16..31 of KT,QT once (never rewritten)
  {
    uint4 z = {0,0,0,0};
    *(uint4*)(swKT + l * 40 + 16) = z;
    *(uint4*)(swKT + l * 40 + 24) = z;
    *(uint4*)(swQT + l * 40 + 16) = z;
    *(uint4*)(swQT + l * 40 + 24) = z;
  }

  for (int it = 0; it < 4; ++it) {
    const int n = w + it * 4;
    // ---- stage bias + K^T,Q^T (lane l = pixel j/i) ----
    #pragma unroll
    for (int m = 0; m < 4; ++m) {
      int e = l + m * 64;
      if (e < 225) swB[e] = rpb[e * 16 + n];
    }
    const uint16_t* qg = base + (size_t)(n * 16) * 64;
    const uint16_t* kg = base + (size_t)(256 + n * 16) * 64;
    const uint16_t* vg = base + (size_t)(512 + n * 16) * 64;
    {
      uint32_t kp[8], qp[8];
      #pragma unroll
      for (int m = 0; m < 8; ++m) {
        uint32_t k0 = kg[(2 * m) * 64 + l], k1 = kg[(2 * m + 1) * 64 + l];
        uint32_t q0 = qg[(2 * m) * 64 + l], q1 = qg[(2 * m + 1) * 64 + l];
        kp[m] = k0 | (k1 << 16);
        qp[m] = q0 | (q1 << 16);
      }
      *(uint4*)(swKT + l * 40)     = *(uint4*)&kp[0];
      *(uint4*)(swKT + l * 40 + 8) = *(uint4*)&kp[4];
      *(uint4*)(swQT + l * 40)     = *(uint4*)&qp[0];
      *(uint4*)(swQT + l * 40 + 8) = *(uint4*)&qp[4];
    }
    asm volatile("s_waitcnt lgkmcnt(0)" ::: "memory");
    __builtin_amdgcn_sched_barrier(0);

    // ---- QK^T: accS[ti][tj] = S tile [j 16][i 16] ----
    vec8s aK[4], bQ[4];
    #pragma unroll
    for (int tt = 0; tt < 4; ++tt) {
      aK[tt] = *(const vec8s*)(swKT + (tt * 16 + l15) * 40 + koct * 8);
      bQ[tt] = *(const vec8s*)(swQT + (tt * 16 + l15) * 40 + koct * 8);
    }
    f32x4 accS[4][4];
    #pragma unroll
    for (int ti = 0; ti < 4; ++ti)
      #pragma unroll
      for (int tj = 0; tj < 4; ++tj)
        accS[ti][tj] = __builtin_amdgcn_mfma_f32_16x16x32_bf16(
            aK[tj], bQ[ti], (f32x4){0.f, 0.f, 0.f, 0.f}, 0, 0, 0);

    // ---- bias + softmax: lane holds i = ti*16+l15, j = tj*16+koct*4+r ----
    float p[4][16], sinv[4];
    #pragma unroll
    for (int ti = 0; ti < 4; ++ti) {
      const int i = ti * 16 + l15;
      const int irow = i >> 3, icol = i & 7;
      #pragma unroll
      for (int tj = 0; tj < 4; ++tj) {
        #pragma unroll
        for (int r = 0; r < 4; ++r) {
          int j = tj * 16 + koct * 4 + r;
          int rel = (irow - (j >> 3) + 7) * 15 + (icol - (j & 7) + 7);
          p[ti][tj * 4 + r] = fmaf(accS[ti][tj][r], 0.25f, swB[rel]);
        }
      }
      float mx = p[ti][0];
      #pragma unroll
      for (int u = 1; u < 16; ++u) mx = fmaxf(mx, p[ti][u]);
      mx = fmaxf(mx, __shfl_xor(mx, 16));
      mx = fmaxf(mx, __shfl_xor(mx, 32));
      float s = 0.f;
      #pragma unroll
      for (int u = 0; u < 16; ++u) { p[ti][u] = __expf(p[ti][u] - mx); s += p[ti][u]; }
      s += __shfl_xor(s, 16);
      s += __shfl_xor(s, 32);
      sinv[ti] = 1.f / s;
    }

    // ---- pack P (unnormalized, in (0,1]) -> PT[i][j] bf16 ----
    #pragma unroll
    for (int ti = 0; ti < 4; ++ti) {
      uint16_t* rowp = swPT + (ti * 16 + l15) * 68 + koct * 4;
      #pragma unroll
      for (int tj = 0; tj < 4; ++tj) {
        uint32_t u0 = (uint32_t)f2bf(p[ti][tj * 4 + 0]) | ((uint32_t)f2bf(p[ti][tj * 4 + 1]) << 16);
        uint32_t u1 = (uint32_t)f2bf(p[ti][tj * 4 + 2]) | ((uint32_t)f2bf(p[ti][tj * 4 + 3]) << 16);
        *(uint32_t*)(rowp + tj * 16)     = u0;
        *(uint32_t*)(rowp + tj * 16 + 2) = u1;
      }
    }
    asm volatile("s_waitcnt lgkmcnt(0)" ::: "memory");
    __builtin_amdgcn_sched_barrier(0);

    // ---- PV: accO[ii] = O^T tile [dd 16][i 16]; A = V^T direct global ----
    f32x4 accO[4];
    #pragma unroll
    for (int ii = 0; ii < 4; ++ii) accO[ii] = (f32x4){0.f, 0.f, 0.f, 0.f};
    #pragma unroll
    for (int ks = 0; ks < 2; ++ks) {
      vec8s aV = *(const vec8s*)(vg + l15 * 64 + ks * 32 + koct * 8);
      #pragma unroll
      for (int ii = 0; ii < 4; ++ii) {
        vec8s bP;
        const uint16_t* src = swPT + (ii * 16 + l15) * 68 + ks * 32 + koct * 8;
        *(uint2*)&bP         = *(const uint2*)(src);
        *((uint2*)&bP + 1)   = *(const uint2*)(src + 4);
        accO[ii] = __builtin_amdgcn_mfma_f32_16x16x32_bf16(aV, bP, accO[ii], 0, 0, 0);
      }
    }
    asm volatile("s_waitcnt lgkmcnt(0)" ::: "memory");
    __builtin_amdgcn_sched_barrier(0);

    // ---- O stage (overlay PT) + 16B-run NCHW stores (as r7) ----
    #pragma unroll
    for (int ii = 0; ii < 4; ++ii) {
      #pragma unroll
      for (int r = 0; r < 4; ++r) {
        int dd = koct * 4 + r;
        swO[dd * 76 + ii * 16 + l15] = accO[ii][r] * sinv[ii];
      }
    }
    asm volatile("s_waitcnt lgkmcnt(0)" ::: "memory");
    __builtin_amdgcn_sched_barrier(0);
    #pragma unroll
    for (int e2 = 0; e2 < 2; ++e2) {
      int e = l + e2 * 64;
      int dd = e >> 3, row = e & 7;
      const float* orow = swO + dd * 76 + row * 8;
      float4 a = *(const float4*)(orow);
      float4 c = *(const float4*)(orow + 4);
      uint4 pk;
      pk.x = (uint32_t)f2bf(a.x) | ((uint32_t)f2bf(a.y) << 16);
      pk.y = (uint32_t)f2bf(a.z) | ((uint32_t)f2bf(a.w) << 16);
      pk.z = (uint32_t)f2bf(c.x) | ((uint32_t)f2bf(c.y) << 16);
      pk.w = (uint32_t)f2bf(c.z) | ((uint32_t)f2bf(c.w) << 16);
      *(uint4*)(outp + (size_t)(b * 256 + n * 16 + dd) * HW + wbase + row * 128) = pk;
    }
    asm volatile("s_waitcnt lgkmcnt(0)" ::: "memory");
    __builtin_amdgcn_sched_barrier(0);
  }
}

// ---------------------------------------------------------------------------
// combined = avgpool_v(attn) + avgpool_h(attn) + local (in-place into loc)
// ---------------------------------------------------------------------------
__global__ __launch_bounds__(256) void k_pool(
    const uint16_t* __restrict__ attnb, float* __restrict__ loc)
{
  __shared__ __align__(16) float sP[71][132];
  const int t = threadIdx.x;
  const int plane = blockIdx.x >> 1;
  const int h0 = (blockIdx.x & 1) * 64;
  const size_t pbase = (size_t)plane * HW;
  for (int k = 0; k < 5; ++k) {
    int idx = t + k * 256;
    if (idx < 71 * 16) {
      int lr = idx >> 4, c8 = (idx & 15) * 8;
      int g = h0 - 3 + lr;
      if (g >= 0 && g <= 127) {
        uint4 v4 = *(const uint4*)(attnb + pbase + (size_t)g * 128 + c8);
        float f[8];
        unpack2(v4.x, f[0], f[1]); unpack2(v4.y, f[2], f[3]);
        unpack2(v4.z, f[4], f[5]); unpack2(v4.w, f[6], f[7]);
        #pragma unroll
        for (int j = 0; j < 8; ++j) sP[lr][c8 + j] = f[j];
      }
    }
  }
  __syncthreads();
  for (int k = 0; k < 32; ++k) {
    int idx = t + k * 256;
    int lh = idx >> 7, w = idx & 127;
    int h = h0 + lh;
    float ax = 0.f;
    #pragma unroll
    for (int o = -3; o <= 4; ++o) {
      int j = h + o;
      if (j >= 0 && j <= 128) {
        int jr = (j == 128) ? 126 : j;
        ax += sP[jr - h0 + 3][w];
      }
    }
    float ay = 0.f;
    #pragma unroll
    for (int o = -3; o <= 4; ++o) {
      int j = w + o;
      if (j >= 0 && j <= 128) {
        int jr = (j == 128) ? 126 : j;
        ay += sP[lh + 3][jr];
      }
    }
    size_t gi = pbase + (size_t)h * 128 + w;
    loc[gi] = fmaf(ax + ay, 0.125f, loc[gi]);
  }
}

// ---------------------------------------------------------------------------
// Depthwise 8x8 conv on reflect(+1)-padded combined, zero pad 3.
// ---------------------------------------------------------------------------
__global__ __launch_bounds__(256) void k_dw(
    const float* __restrict__ comb, const float* __restrict__ wdw,
    float* __restrict__ out)
{
  __shared__ __align__(16) float sZ[71][140];
  __shared__ float sWd[64];
  const int t = threadIdx.x;
  const int plane = blockIdx.x >> 1;
  const int cch = plane & 255;
  const int h0 = (blockIdx.x & 1) * 64;
  const size_t pbase = (size_t)plane * HW;
  if (t < 64) sWd[t] = wdw[cch * 64 + t];
  for (int k = 0; k < 38; ++k) {
    int idx = t + k * 256;
    if (idx < 71 * 136) {
      int u = idx / 136, vc = idx - u * 136;
      int g = h0 - 3 + u;
      if (g >= 0 && g <= 128) {
        int bb = vc - 3;
        float v = 0.f;
        if (bb >= 0 && bb <= 128) {
          int gr = (g == 128) ? 126 : g;
          int br = (bb == 128) ? 126 : bb;
          v = comb[pbase + gr * 128 + br];
        }
        sZ[u][vc] = v;
      }
    }
  }
  __syncthreads();
  const int wg = t & 7, hl = t >> 3;
  const int w0 = wg * 16;
  float acc[2][16];
  #pragma unroll
  for (int a = 0; a < 2; ++a)
    #pragma unroll
    for (int p = 0; p < 16; ++p) acc[a][p] = 0.f;
  #pragma unroll 1
  for (int i = 0; i < 8; ++i) {
    float wrow[8];
    *(float4*)&wrow[0] = *(const float4*)&sWd[i * 8];
    *(float4*)&wrow[4] = *(const float4*)&sWd[i * 8 + 4];
    #pragma unroll
    for (int hi = 0; hi < 2; ++hi) {
      int h = h0 + hl + 32 * hi;
      int u = h + i - 3;
      bool ok = (u >= 0 && u <= 128);
      int lr = ok ? (u - h0 + 3) : 0;
      const float* zr = &sZ[lr][w0];
      float win[24];
      *(float4*)&win[0]  = *(const float4*)(zr);
      *(float4*)&win[4]  = *(const float4*)(zr + 4);
      *(float4*)&win[8]  = *(const float4*)(zr + 8);
      *(float4*)&win[12] = *(const float4*)(zr + 12);
      *(float4*)&win[16] = *(const float4*)(zr + 16);
      *(float4*)&win[20] = *(const float4*)(zr + 20);
      float m = ok ? 1.f : 0.f;
      float wv[8];
      #pragma unroll
      for (int j = 0; j < 8; ++j) wv[j] = wrow[j] * m;
      #pragma unroll
      for (int p = 0; p < 16; ++p)
        #pragma unroll
        for (int j = 0; j < 8; ++j)
          acc[hi][p] = fmaf(wv[j], win[p + j], acc[hi][p]);
    }
  }
  #pragma unroll
  for (int hi = 0; hi < 2; ++hi) {
    int h = h0 + hl + 32 * hi;
    float* dst = out + pbase + (size_t)h * 128 + w0;
    float4 o0 = {acc[hi][0],  acc[hi][1],  acc[hi][2],  acc[hi][3]};
    float4 o1 = {acc[hi][4],  acc[hi][5],  acc[hi][6],  acc[hi][7]};
    float4 o2 = {acc[hi][8],  acc[hi][9],  acc[hi][10], acc[hi][11]};
    float4 o3 = {acc[hi][12], acc[hi][13], acc[hi][14], acc[hi][15]};
    *(float4*)(dst)      = o0;
    *(float4*)(dst + 4)  = o1;
    *(float4*)(dst + 8)  = o2;
    *(float4*)(dst + 12) = o3;
  }
}

} // namespace

extern "C" void kernel_launch(void* const* d_in, const int* in_sizes, int n_in,
                              void* d_out, int out_size, void* d_ws, size_t ws_size,
                              hipStream_t stream)
{
  const float* x      = (const float*)d_in[0];
  const float* w_pre  = (const float*)d_in[1];
  const float* bn_pre = (const float*)d_in[2];
  const float* w_l1   = (const float*)d_in[3];
  const float* bn_l1  = (const float*)d_in[4];
  const float* w_l2   = (const float*)d_in[5];
  const float* bn_l2  = (const float*)d_in[6];
  const float* w_l3   = (const float*)d_in[7];
  const float* bn_l3  = (const float*)d_in[8];
  const float* w_qkv  = (const float*)d_in[9];
  const float* rpb    = (const float*)d_in[10];
  const float* w_dw   = (const float*)d_in[11];
  const float* w_pw   = (const float*)d_in[12];
  const float* bn_pj  = (const float*)d_in[13];
  float* out = (float*)d_out;

  char* base = (char*)d_ws;
  uint16_t* xT    = (uint16_t*)base;                          // 64 MiB NHWC bf16 x; later dwT
  uint16_t* preT  = (uint16_t*)(base + (size_t)67108864);     // 64 MiB NHWC bf16 pre; later attn out
  float*    bufB  = (float*)(base + (size_t)134217728);       // 128 MiB fp32 local/combined
  uint16_t* bufQ  = (uint16_t*)(base + (size_t)268435456);    // 192 MiB bf16 qkv windows; later dw out
  uint16_t* attnO = preT;
  float*    bufDw = (float*)bufQ;
  uint16_t* dwT   = xT;

  dim3 blk(256);
  // 0. cast x -> NHWC bf16
  k_cast<<<dim3(1024), blk, 0, stream>>>(x, xT);
  // 1. pre 1x1 conv + bn -> NHWC bf16 (MFMA, X-resident)
  k_gemm_v2<0, 2><<<dim3(1024), blk, 0, stream>>>(xT, w_pre, bn_pre, 256, preT, nullptr);
  // 2. dilated 3x3 convs + bn (MFMA) -> bufB fp32 NCHW
  k_dilconv_mfma<1, 86><<<dim3(32, 2, 8), blk, 0, stream>>>(preT, w_l1, bn_l1, bufB, 0, 0);
  k_dilconv_mfma<2, 86><<<dim3(32, 2, 8), blk, 0, stream>>>(preT, w_l2, bn_l2, bufB, 86, 80);
  k_dilconv_mfma<3, 84><<<dim3(32, 2, 8), blk, 0, stream>>>(preT, w_l3, bn_l3, bufB, 172, 160);
  // 3. qkv 1x1 conv -> bufQ window-layout bf16 (MFMA, X-resident, win-major px)
  k_gemm_v2<3, 6><<<dim3(1024), blk, 0, stream>>>(xT, w_qkv, nullptr, 768, bufQ, nullptr);
  // 4. windowed attention (MFMA) -> attnO bf16 NCHW (overwrites preT; safe)
  k_attn<<<dim3(256, 8), blk, 0, stream>>>(bufQ, rpb, attnO);
  // 5. pools + residual combine (in-place on bufB)
  k_pool<<<dim3(4096), blk, 0, stream>>>(attnO, bufB);
  // 6. depthwise 8x8 -> bufDw fp32 NCHW (overwrites bufQ; safe)
  k_dw<<<dim3(4096), blk, 0, stream>>>(bufB, w_dw, bufDw);
  // 7. cast dw-out -> NHWC bf16 (overwrites xT; safe)
  k_cast<<<dim3(1024), blk, 0, stream>>>(bufDw, dwT);
  // 8. pw 1x1 conv + bn -> out fp32 NCHW (MFMA, X-resident)
  k_gemm_v2<2, 2><<<dim3(1024), blk, 0, stream>>>(dwT, w_pw, bn_pj, 256, nullptr, out);

  (void)in_sizes; (void)n_in; (void)out_size; (void)ws_size;
}

// Round 9
// 836.256 us; speedup vs baseline: 5.2069x; 1.1393x over previous
//
#include <hip/hip_runtime.h>
#include <hip/hip_bf16.h>
#include <cstdint>
#include <cstddef>

namespace {

constexpr int HW = 16384;   // 128*128

typedef short vec8s __attribute__((ext_vector_type(8)));
typedef float f32x4 __attribute__((ext_vector_type(4)));

__device__ __forceinline__ float u2f(uint32_t u){ union { uint32_t u; float f; } v; v.u = u; return v.f; }
__device__ __forceinline__ uint32_t f2u(float f){ union { float f; uint32_t u; } v; v.f = f; return v.u; }
__device__ __forceinline__ uint16_t f2bf(float f){
  uint32_t u = f2u(f);
  u += 0x7fffu + ((u >> 16) & 1u);   // round-to-nearest-even
  return (uint16_t)(u >> 16);
}
__device__ __forceinline__ void unpack2(uint32_t w, float& lo, float& hi){
  lo = u2f(w << 16);
  hi = u2f(w & 0xffff0000u);
}

// ---------------------------------------------------------------------------
// Cast NCHW fp32 (256 ch) -> NHWC bf16. Block = one (b, row).
// ---------------------------------------------------------------------------
__global__ __launch_bounds__(256) void k_cast(
    const float* __restrict__ x, uint16_t* __restrict__ xT)
{
  __shared__ float sF[64][129];
  const int t = threadIdx.x;
  const int b = blockIdx.x >> 7;
  const int y = blockIdx.x & 127;
  const size_t rowoff = (size_t)y * 128;
  for (int cc = 0; cc < 4; ++cc) {
    const int cic0 = cc * 64;
    #pragma unroll
    for (int k = 0; k < 8; ++k) {
      int e = t + k * 256;
      int ci = e >> 5;
      int pxq = (e & 31) * 4;
      float4 v = *(const float4*)(x + (size_t)(b * 256 + cic0 + ci) * HW + rowoff + pxq);
      sF[ci][pxq] = v.x; sF[ci][pxq+1] = v.y; sF[ci][pxq+2] = v.z; sF[ci][pxq+3] = v.w;
    }
    __syncthreads();
    {
      int px = t >> 1, h = t & 1;
      __align__(16) uint16_t tmp[32];
      #pragma unroll
      for (int j = 0; j < 32; ++j) tmp[j] = f2bf(sF[h * 32 + j][px]);
      uint16_t* dst = xT + ((size_t)b * HW + rowoff + px) * 256 + cic0 + h * 32;
      *(uint4*)(dst)      = *(uint4*)&tmp[0];
      *(uint4*)(dst + 8)  = *(uint4*)&tmp[8];
      *(uint4*)(dst + 16) = *(uint4*)&tmp[16];
      *(uint4*)(dst + 24) = *(uint4*)&tmp[24];
    }
    __syncthreads();
  }
}

// ---------------------------------------------------------------------------
// 1x1 conv via bf16 MFMA, X-resident co-loop version (unchanged from r6).
// ---------------------------------------------------------------------------
template<int OUT_MODE, int NCO>
__global__ __launch_bounds__(256) void k_gemm_v2(
    const uint16_t* __restrict__ xT, const float* __restrict__ wmat,
    const float* __restrict__ bnp, int M,
    uint16_t* __restrict__ outb, float* __restrict__ outf)
{
  __shared__ __align__(16) uint16_t sX[128][260];
  __shared__ __align__(16) uint16_t sW[128][36];
  const int t = threadIdx.x;
  const int b    = blockIdx.x >> 7;
  const int tile = blockIdx.x & 127;
  const int l = t & 63, w = t >> 6;
  const int l15 = l & 15, koct = l >> 4;
  const int wc = w >> 1, wp = w & 1;

  {
    const int spx = t >> 1, sh = t & 1;
    int gpx;
    if constexpr (OUT_MODE == 3) {
      int win = tile * 2 + (spx >> 6);
      int p = spx & 63;
      gpx = ((win >> 4) * 8 + (p >> 3)) * 128 + (win & 15) * 8 + (p & 7);
    } else {
      gpx = tile * 128 + spx;
    }
    const uint16_t* src = xT + ((size_t)b * HW + gpx) * 256 + sh * 128;
    uint16_t* dst = &sX[spx][sh * 128];
    #pragma unroll
    for (int i = 0; i < 16; ++i)
      *(uint4*)(dst + i * 8) = *(const uint4*)(src + i * 8);
  }

  const int swc = t >> 1, swh = t & 1;
  float4 wr0, wr1, wr2, wr3;
  {
    const float* p = wmat + (size_t)swc * 256 + swh * 16;
    wr0 = *(const float4*)(p);     wr1 = *(const float4*)(p + 4);
    wr2 = *(const float4*)(p + 8); wr3 = *(const float4*)(p + 12);
  }
  __syncthreads();

  for (int cc = 0; cc < NCO; ++cc) {
    f32x4 acc[4][4];
    #pragma unroll
    for (int cf = 0; cf < 4; ++cf)
      #pragma unroll
      for (int pf = 0; pf < 4; ++pf) acc[cf][pf] = (f32x4){0.f,0.f,0.f,0.f};

    for (int kc = 0; kc < 8; ++kc) {
      if (cc | kc) __syncthreads();
      {
        __align__(16) uint16_t tmp[16];
        tmp[0]=f2bf(wr0.x); tmp[1]=f2bf(wr0.y); tmp[2]=f2bf(wr0.z); tmp[3]=f2bf(wr0.w);
        tmp[4]=f2bf(wr1.x); tmp[5]=f2bf(wr1.y); tmp[6]=f2bf(wr1.z); tmp[7]=f2bf(wr1.w);
        tmp[8]=f2bf(wr2.x); tmp[9]=f2bf(wr2.y); tmp[10]=f2bf(wr2.z); tmp[11]=f2bf(wr2.w);
        tmp[12]=f2bf(wr3.x); tmp[13]=f2bf(wr3.y); tmp[14]=f2bf(wr3.z); tmp[15]=f2bf(wr3.w);
        uint16_t* dst = &sW[swc][swh * 16];
        *(uint4*)(dst)     = *(uint4*)&tmp[0];
        *(uint4*)(dst + 8) = *(uint4*)&tmp[8];
      }
      {
        int nkc = kc + 1, ncc = cc;
        if (nkc == 8) { nkc = 0; ncc = cc + 1; }
        if (ncc < NCO) {
          const float* p = wmat + (size_t)(ncc * 128 + swc) * 256 + nkc * 32 + swh * 16;
          wr0 = *(const float4*)(p);     wr1 = *(const float4*)(p + 4);
          wr2 = *(const float4*)(p + 8); wr3 = *(const float4*)(p + 12);
        }
      }
      __syncthreads();
      vec8s bf[4];
      #pragma unroll
      for (int pf = 0; pf < 4; ++pf)
        bf[pf] = *(const vec8s*)&sX[wp * 64 + pf * 16 + l15][kc * 32 + koct * 8];
      #pragma unroll
      for (int cf = 0; cf < 4; ++cf) {
        vec8s af = *(const vec8s*)&sW[wc * 64 + cf * 16 + l15][koct * 8];
        #pragma unroll
        for (int pf = 0; pf < 4; ++pf)
          acc[cf][pf] = __builtin_amdgcn_mfma_f32_16x16x32_bf16(af, bf[pf], acc[cf][pf], 0, 0, 0);
      }
    }

    #pragma unroll
    for (int cf = 0; cf < 4; ++cf) {
      const int cbase = cc * 128 + wc * 64 + cf * 16 + koct * 4;
      float scv[4], shv[4];
      #pragma unroll
      for (int r = 0; r < 4; ++r) {
        scv[r] = 1.f; shv[r] = 0.f;
        if constexpr (OUT_MODE == 0 || OUT_MODE == 2) {
          int c = cbase + r;
          float g = bnp[c], be = bnp[M + c], mu = bnp[2 * M + c], va = bnp[3 * M + c];
          scv[r] = g * rsqrtf(va + 1e-5f);
          shv[r] = be - mu * scv[r];
        }
      }
      #pragma unroll
      for (int pf = 0; pf < 4; ++pf) {
        if constexpr (OUT_MODE == 0) {
          int px = tile * 128 + wp * 64 + pf * 16 + l15;
          __align__(8) uint16_t pk[4];
          #pragma unroll
          for (int r = 0; r < 4; ++r)
            pk[r] = f2bf(fmaf(acc[cf][pf][r], scv[r], shv[r]));
          *(uint2*)(outb + ((size_t)b * HW + px) * 256 + cbase) = *(uint2*)pk;
        } else if constexpr (OUT_MODE == 2) {
          int px = tile * 128 + wp * 64 + pf * 16 + l15;
          #pragma unroll
          for (int r = 0; r < 4; ++r)
            outf[(size_t)(b * M + cbase + r) * HW + px] =
                fmaf(acc[cf][pf][r], scv[r], shv[r]);
        } else {
          int win = tile * 2 + wp;
          int p = pf * 16 + l15;
          uint16_t* dstp = outb + ((size_t)(b * 256 + win) * 768 + cbase) * 64 + p;
          #pragma unroll
          for (int r = 0; r < 4; ++r)
            dstp[(size_t)r * 64] = f2bf(acc[cf][pf][r]);
        }
      }
    }
  }
}

// ---------------------------------------------------------------------------
// Dilated 3x3 conv + BN via bf16 MFMA implicit GEMM (unchanged from r3).
// ---------------------------------------------------------------------------
template<int DIL, int CG>
__global__ __launch_bounds__(256) void k_dilconv_mfma(
    const uint16_t* __restrict__ preT, const float* __restrict__ wt,
    const float* __restrict__ bnp, float* __restrict__ out,
    int cb, int cb_al)
{
  constexpr int R = 8 + 2 * DIL;
  constexpr int C = 64 + 2 * DIL;
  constexpr int NPOS = R * C;
  constexpr int NIT = (NPOS + 255) / 256;
  __shared__ __align__(16) uint16_t sX[NPOS * 16];
  __shared__ __align__(16) uint16_t sW[10 * 50 * 16];

  const int t = threadIdx.x;
  const int rt    = blockIdx.x >> 1;
  const int ctile = blockIdx.x & 1;
  const int ct2   = blockIdx.y;
  const int b     = blockIdx.z;
  const int y0 = rt * 8, x0 = ctile * 64;
  const int l = t & 63, w = t >> 6;
  const int l15 = l & 15, oct = (l >> 4) & 1, half = l >> 5;
  const int rbase = w * 2;

  f32x4 acc[3][8];
  #pragma unroll
  for (int cf = 0; cf < 3; ++cf)
    #pragma unroll
    for (int q = 0; q < 8; ++q) acc[cf][q] = (f32x4){0.f,0.f,0.f,0.f};

  for (int kc = 0; kc < 6; ++kc) {
    #pragma unroll
    for (int i = 0; i < 3; ++i) {
      int pair = t + i * 256;
      int co = pair >> 4, ci = pair & 15;
      int cog = ct2 * 48 + co;
      int c = cb_al + kc * 16 + ci;
      bool ok = (cog < CG) && (c >= cb) && (c < cb + CG);
      size_t widx = ok ? ((size_t)cog * (size_t)CG + (size_t)(c - cb)) * 9u
                       : (size_t)0;
      const float* wp = wt + widx;
      uint16_t* dst = &sW[co * 16 + ci];
      #pragma unroll
      for (int tap = 0; tap < 9; ++tap)
        dst[tap * 800] = ok ? f2bf(wp[tap]) : (uint16_t)0;
      dst[9 * 800] = 0;
    }
    #pragma unroll
    for (int i = 0; i < NIT; ++i) {
      int p = t + i * 256;
      if (p < NPOS) {
        int row = p / C, col = p % C;
        int gy = y0 + row - DIL, gx = x0 + col - DIL;
        uint4 va = {0,0,0,0}, vb = {0,0,0,0};
        if ((unsigned)gy < 128u && (unsigned)gx < 128u) {
          const uint4* src = (const uint4*)(preT +
              (((size_t)b * HW + gy * 128 + gx) * 256 + cb_al + kc * 16));
          va = src[0]; vb = src[1];
        }
        uint4* dst = (uint4*)&sX[p * 16];
        dst[0] = va; dst[1] = vb;
      }
    }
    __syncthreads();

    #pragma unroll
    for (int s = 0; s < 5; ++s) {
      const int tap0 = 2 * s, tap1 = 2 * s + 1;
      const int dy0 = tap0 / 3, dx0 = tap0 % 3;
      const int dy1 = (tap1 <= 8) ? tap1 / 3 : 2;
      const int dx1 = (tap1 <= 8) ? tap1 % 3 : 2;
      const int dy = half ? dy1 : dy0;
      const int dx = half ? dx1 : dx0;
      const int atap = tap0 + half;
      vec8s a0 = *(const vec8s*)&sW[(atap * 50 + 0  + l15) * 16 + oct * 8];
      vec8s a1 = *(const vec8s*)&sW[(atap * 50 + 16 + l15) * 16 + oct * 8];
      vec8s a2 = *(const vec8s*)&sW[(atap * 50 + 32 + l15) * 16 + oct * 8];
      #pragma unroll
      for (int rs = 0; rs < 2; ++rs) {
        const int rowin = rbase + rs + dy * DIL;
        #pragma unroll
        for (int c4 = 0; c4 < 4; ++c4) {
          const int colin = c4 * 16 + l15 + dx * DIL;
          vec8s bf = *(const vec8s*)&sX[(rowin * C + colin) * 16 + oct * 8];
          acc[0][rs*4+c4] = __builtin_amdgcn_mfma_f32_16x16x32_bf16(a0, bf, acc[0][rs*4+c4], 0, 0, 0);
          acc[1][rs*4+c4] = __builtin_amdgcn_mfma_f32_16x16x32_bf16(a1, bf, acc[1][rs*4+c4], 0, 0, 0);
          acc[2][rs*4+c4] = __builtin_amdgcn_mfma_f32_16x16x32_bf16(a2, bf, acc[2][rs*4+c4], 0, 0, 0);
        }
      }
    }
    __syncthreads();
  }

  const int row4 = (l >> 4);
  #pragma unroll
  for (int cf = 0; cf < 3; ++cf) {
    #pragma unroll
    for (int r = 0; r < 4; ++r) {
      int c_loc = ct2 * 48 + cf * 16 + row4 * 4 + r;
      if (c_loc < CG) {
        int cg = cb + c_loc;
        float g = bnp[c_loc], be = bnp[CG + c_loc];
        float mu = bnp[2 * CG + c_loc], va = bnp[3 * CG + c_loc];
        float scv = g * rsqrtf(va + 1e-5f);
        float shv = be - mu * scv;
        #pragma unroll
        for (int rs = 0; rs < 2; ++rs) {
          int y = y0 + rbase + rs;
          #pragma unroll
          for (int c4 = 0; c4 < 4; ++c4) {
            int x = x0 + c4 * 16 + l15;
            out[(size_t)(b * 256 + cg) * HW + y * 128 + x] =
                fmaf(acc[cf][rs*4+c4][r], scv, shv);
          }
        }
      }
    }
  }
}

// ---------------------------------------------------------------------------
// Windowed attention, wave-autonomous + MFMA (unchanged from r8).
// ---------------------------------------------------------------------------
__global__ __launch_bounds__(256) void k_attn(
    const uint16_t* __restrict__ qkvW, const float* __restrict__ rpb,
    uint16_t* __restrict__ outp)
{
  __shared__ __align__(16) uint16_t sAll[4][9928];
  const int t = threadIdx.x;
  const int l = t & 63, w = t >> 6;
  const int l15 = l & 15, koct = l >> 4;
  const int b = blockIdx.y;
  const int win = blockIdx.x;
  const int wy = win >> 4, wx = win & 15;
  const int wbase = (wy * 8) * 128 + wx * 8;
  const uint16_t* base = qkvW + (size_t)(b * 256 + win) * 49152;
  uint16_t* swKT = &sAll[w][0];
  uint16_t* swQT = &sAll[w][2560];
  uint16_t* swPT = &sAll[w][5120];
  float*    swB  = (float*)&sAll[w][9472];
  float*    swO  = (float*)swPT;

  {
    uint4 z = {0,0,0,0};
    *(uint4*)(swKT + l * 40 + 16) = z;
    *(uint4*)(swKT + l * 40 + 24) = z;
    *(uint4*)(swQT + l * 40 + 16) = z;
    *(uint4*)(swQT + l * 40 + 24) = z;
  }

  for (int it = 0; it < 4; ++it) {
    const int n = w + it * 4;
    #pragma unroll
    for (int m = 0; m < 4; ++m) {
      int e = l + m * 64;
      if (e < 225) swB[e] = rpb[e * 16 + n];
    }
    const uint16_t* qg = base + (size_t)(n * 16) * 64;
    const uint16_t* kg = base + (size_t)(256 + n * 16) * 64;
    const uint16_t* vg = base + (size_t)(512 + n * 16) * 64;
    {
      uint32_t kp[8], qp[8];
      #pragma unroll
      for (int m = 0; m < 8; ++m) {
        uint32_t k0 = kg[(2 * m) * 64 + l], k1 = kg[(2 * m + 1) * 64 + l];
        uint32_t q0 = qg[(2 * m) * 64 + l], q1 = qg[(2 * m + 1) * 64 + l];
        kp[m] = k0 | (k1 << 16);
        qp[m] = q0 | (q1 << 16);
      }
      *(uint4*)(swKT + l * 40)     = *(uint4*)&kp[0];
      *(uint4*)(swKT + l * 40 + 8) = *(uint4*)&kp[4];
      *(uint4*)(swQT + l * 40)     = *(uint4*)&qp[0];
      *(uint4*)(swQT + l * 40 + 8) = *(uint4*)&qp[4];
    }
    asm volatile("s_waitcnt lgkmcnt(0)" ::: "memory");
    __builtin_amdgcn_sched_barrier(0);

    vec8s aK[4], bQ[4];
    #pragma unroll
    for (int tt = 0; tt < 4; ++tt) {
      aK[tt] = *(const vec8s*)(swKT + (tt * 16 + l15) * 40 + koct * 8);
      bQ[tt] = *(const vec8s*)(swQT + (tt * 16 + l15) * 40 + koct * 8);
    }
    f32x4 accS[4][4];
    #pragma unroll
    for (int ti = 0; ti < 4; ++ti)
      #pragma unroll
      for (int tj = 0; tj < 4; ++tj)
        accS[ti][tj] = __builtin_amdgcn_mfma_f32_16x16x32_bf16(
            aK[tj], bQ[ti], (f32x4){0.f, 0.f, 0.f, 0.f}, 0, 0, 0);

    float p[4][16], sinv[4];
    #pragma unroll
    for (int ti = 0; ti < 4; ++ti) {
      const int i = ti * 16 + l15;
      const int irow = i >> 3, icol = i & 7;
      #pragma unroll
      for (int tj = 0; tj < 4; ++tj) {
        #pragma unroll
        for (int r = 0; r < 4; ++r) {
          int j = tj * 16 + koct * 4 + r;
          int rel = (irow - (j >> 3) + 7) * 15 + (icol - (j & 7) + 7);
          p[ti][tj * 4 + r] = fmaf(accS[ti][tj][r], 0.25f, swB[rel]);
        }
      }
      float mx = p[ti][0];
      #pragma unroll
      for (int u = 1; u < 16; ++u) mx = fmaxf(mx, p[ti][u]);
      mx = fmaxf(mx, __shfl_xor(mx, 16));
      mx = fmaxf(mx, __shfl_xor(mx, 32));
      float s = 0.f;
      #pragma unroll
      for (int u = 0; u < 16; ++u) { p[ti][u] = __expf(p[ti][u] - mx); s += p[ti][u]; }
      s += __shfl_xor(s, 16);
      s += __shfl_xor(s, 32);
      sinv[ti] = 1.f / s;
    }

    #pragma unroll
    for (int ti = 0; ti < 4; ++ti) {
      uint16_t* rowp = swPT + (ti * 16 + l15) * 68 + koct * 4;
      #pragma unroll
      for (int tj = 0; tj < 4; ++tj) {
        uint32_t u0 = (uint32_t)f2bf(p[ti][tj * 4 + 0]) | ((uint32_t)f2bf(p[ti][tj * 4 + 1]) << 16);
        uint32_t u1 = (uint32_t)f2bf(p[ti][tj * 4 + 2]) | ((uint32_t)f2bf(p[ti][tj * 4 + 3]) << 16);
        *(uint32_t*)(rowp + tj * 16)     = u0;
        *(uint32_t*)(rowp + tj * 16 + 2) = u1;
      }
    }
    asm volatile("s_waitcnt lgkmcnt(0)" ::: "memory");
    __builtin_amdgcn_sched_barrier(0);

    f32x4 accO[4];
    #pragma unroll
    for (int ii = 0; ii < 4; ++ii) accO[ii] = (f32x4){0.f, 0.f, 0.f, 0.f};
    #pragma unroll
    for (int ks = 0; ks < 2; ++ks) {
      vec8s aV = *(const vec8s*)(vg + l15 * 64 + ks * 32 + koct * 8);
      #pragma unroll
      for (int ii = 0; ii < 4; ++ii) {
        vec8s bP;
        const uint16_t* src = swPT + (ii * 16 + l15) * 68 + ks * 32 + koct * 8;
        *(uint2*)&bP         = *(const uint2*)(src);
        *((uint2*)&bP + 1)   = *(const uint2*)(src + 4);
        accO[ii] = __builtin_amdgcn_mfma_f32_16x16x32_bf16(aV, bP, accO[ii], 0, 0, 0);
      }
    }
    asm volatile("s_waitcnt lgkmcnt(0)" ::: "memory");
    __builtin_amdgcn_sched_barrier(0);

    #pragma unroll
    for (int ii = 0; ii < 4; ++ii) {
      #pragma unroll
      for (int r = 0; r < 4; ++r) {
        int dd = koct * 4 + r;
        swO[dd * 76 + ii * 16 + l15] = accO[ii][r] * sinv[ii];
      }
    }
    asm volatile("s_waitcnt lgkmcnt(0)" ::: "memory");
    __builtin_amdgcn_sched_barrier(0);
    #pragma unroll
    for (int e2 = 0; e2 < 2; ++e2) {
      int e = l + e2 * 64;
      int dd = e >> 3, row = e & 7;
      const float* orow = swO + dd * 76 + row * 8;
      float4 a = *(const float4*)(orow);
      float4 c = *(const float4*)(orow + 4);
      uint4 pk;
      pk.x = (uint32_t)f2bf(a.x) | ((uint32_t)f2bf(a.y) << 16);
      pk.y = (uint32_t)f2bf(a.z) | ((uint32_t)f2bf(a.w) << 16);
      pk.z = (uint32_t)f2bf(c.x) | ((uint32_t)f2bf(c.y) << 16);
      pk.w = (uint32_t)f2bf(c.z) | ((uint32_t)f2bf(c.w) << 16);
      *(uint4*)(outp + (size_t)(b * 256 + n * 16 + dd) * HW + wbase + row * 128) = pk;
    }
    asm volatile("s_waitcnt lgkmcnt(0)" ::: "memory");
    __builtin_amdgcn_sched_barrier(0);
  }
}

// ---------------------------------------------------------------------------
// combined = avgpool_v(attn) + avgpool_h(attn) + local (in-place into loc)
// Rewritten: float4 tasks (4 cols x 8 rows per thread), sliding-window box
// sums, zero-padded LDS + closed-form reflect corrections (j==128 -> 126).
// sP LDS layout: data col c at [lr][4+c]; cols 0-3 & 132-135 zero; rows with
// g outside [0,127] zero.
// ---------------------------------------------------------------------------
__global__ __launch_bounds__(256) void k_pool(
    const uint16_t* __restrict__ attnb, float* __restrict__ loc)
{
  __shared__ __align__(16) float sP[71][136];
  const int t = threadIdx.x;
  const int plane = blockIdx.x >> 1;
  const int h0 = (blockIdx.x & 1) * 64;
  const size_t pbase = (size_t)plane * HW;
  // stage data: 71 rows x 16 groups of 8 cols (zeros outside [0,127])
  #pragma unroll
  for (int k = 0; k < 5; ++k) {
    int idx = t + k * 256;
    if (idx < 71 * 16) {
      int lr = idx >> 4, m = idx & 15;
      int g = h0 - 3 + lr;
      float f[8] = {0.f,0.f,0.f,0.f,0.f,0.f,0.f,0.f};
      if (g >= 0 && g <= 127) {
        uint4 v4 = *(const uint4*)(attnb + pbase + (size_t)g * 128 + m * 8);
        unpack2(v4.x, f[0], f[1]); unpack2(v4.y, f[2], f[3]);
        unpack2(v4.z, f[4], f[5]); unpack2(v4.w, f[6], f[7]);
      }
      float* dst = &sP[lr][4 + m * 8];
      *(float4*)dst       = (float4){f[0], f[1], f[2], f[3]};
      *(float4*)(dst + 4) = (float4){f[4], f[5], f[6], f[7]};
    }
  }
  // zero edge cols (0..3, 132..135): 71*8 tasks
  #pragma unroll
  for (int k = 0; k < 3; ++k) {
    int idx = t + k * 256;
    if (idx < 71 * 8) {
      int lr = idx >> 3, e = idx & 7;
      int c = (e < 4) ? e : (128 + e);
      sP[lr][c] = 0.f;
    }
  }
  __syncthreads();

  const int q  = t & 31;         // col group: cols [4q, 4q+4)
  const int r0 = (t >> 5) * 8;   // rows r0..r0+7 (lh, output h = h0+lh)
  const int w0 = q * 4;
  // vertical running box-sum for lh = r0: rows lr in [r0, r0+7]
  float4 av = {0.f, 0.f, 0.f, 0.f};
  #pragma unroll
  for (int o = 0; o < 8; ++o) {
    float4 v = *(const float4*)&sP[r0 + o][4 + w0];
    av.x += v.x; av.y += v.y; av.z += v.z; av.w += v.w;
  }
  #pragma unroll
  for (int rr = 0; rr < 8; ++rr) {
    const int lh = r0 + rr;
    const int h = h0 + lh;
    float4 a = av;
    if (h >= 124) {   // window contains j==128 -> add P[126] (h0==64 only)
      float4 cfix = *(const float4*)&sP[126 - 64 + 3][4 + w0];
      a.x += cfix.x; a.y += cfix.y; a.z += cfix.z; a.w += cfix.w;
    }
    // horizontal: v[k] = LDS col w0+k (k=0..11) via 3 aligned float4
    float4 hv0 = *(const float4*)&sP[lh + 3][w0];
    float4 hv1 = *(const float4*)&sP[lh + 3][w0 + 4];
    float4 hv2 = *(const float4*)&sP[lh + 3][w0 + 8];
    float s0 = hv0.y + hv0.z + hv0.w + hv1.x + hv1.y + hv1.z + hv1.w + hv2.x;
    float s1 = s0 - hv0.y + hv2.y;
    float s2 = s1 - hv0.z + hv2.z;
    float s3 = s2 - hv0.w + hv2.w;
    if (q == 31) {    // outputs w>=124: window contains j==128 -> add P[][126]
      float cfix = sP[lh + 3][130];
      s0 += cfix; s1 += cfix; s2 += cfix; s3 += cfix;
    }
    const size_t gi = pbase + (size_t)h * 128 + w0;
    float4 lv = *(const float4*)(loc + gi);
    float4 o4;
    o4.x = fmaf(a.x + s0, 0.125f, lv.x);
    o4.y = fmaf(a.y + s1, 0.125f, lv.y);
    o4.z = fmaf(a.z + s2, 0.125f, lv.z);
    o4.w = fmaf(a.w + s3, 0.125f, lv.w);
    *(float4*)(loc + gi) = o4;
    if (rr < 7) {   // slide vertical window: drop row lh, add row lh+8
      float4 vm = *(const float4*)&sP[lh][4 + w0];
      float4 vp = *(const float4*)&sP[lh + 8][4 + w0];
      av.x += vp.x - vm.x; av.y += vp.y - vm.y;
      av.z += vp.z - vm.z; av.w += vp.w - vm.w;
    }
  }
}

// ---------------------------------------------------------------------------
// Depthwise 8x8 conv on reflect(+1)-padded combined, zero pad 3.
// ---------------------------------------------------------------------------
__global__ __launch_bounds__(256) void k_dw(
    const float* __restrict__ comb, const float* __restrict__ wdw,
    float* __restrict__ out)
{
  __shared__ __align__(16) float sZ[71][140];
  __shared__ float sWd[64];
  const int t = threadIdx.x;
  const int plane = blockIdx.x >> 1;
  const int cch = plane & 255;
  const int h0 = (blockIdx.x & 1) * 64;
  const size_t pbase = (size_t)plane * HW;
  if (t < 64) sWd[t] = wdw[cch * 64 + t];
  for (int k = 0; k < 38; ++k) {
    int idx = t + k * 256;
    if (idx < 71 * 136) {
      int u = idx / 136, vc = idx - u * 136;
      int g = h0 - 3 + u;
      if (g >= 0 && g <= 128) {
        int bb = vc - 3;
        float v = 0.f;
        if (bb >= 0 && bb <= 128) {
          int gr = (g == 128) ? 126 : g;
          int br = (bb == 128) ? 126 : bb;
          v = comb[pbase + gr * 128 + br];
        }
        sZ[u][vc] = v;
      }
    }
  }
  __syncthreads();
  const int wg = t & 7, hl = t >> 3;
  const int w0 = wg * 16;
  float acc[2][16];
  #pragma unroll
  for (int a = 0; a < 2; ++a)
    #pragma unroll
    for (int p = 0; p < 16; ++p) acc[a][p] = 0.f;
  #pragma unroll 1
  for (int i = 0; i < 8; ++i) {
    float wrow[8];
    *(float4*)&wrow[0] = *(const float4*)&sWd[i * 8];
    *(float4*)&wrow[4] = *(const float4*)&sWd[i * 8 + 4];
    #pragma unroll
    for (int hi = 0; hi < 2; ++hi) {
      int h = h0 + hl + 32 * hi;
      int u = h + i - 3;
      bool ok = (u >= 0 && u <= 128);
      int lr = ok ? (u - h0 + 3) : 0;
      const float* zr = &sZ[lr][w0];
      float win[24];
      *(float4*)&win[0]  = *(const float4*)(zr);
      *(float4*)&win[4]  = *(const float4*)(zr + 4);
      *(float4*)&win[8]  = *(const float4*)(zr + 8);
      *(float4*)&win[12] = *(const float4*)(zr + 12);
      *(float4*)&win[16] = *(const float4*)(zr + 16);
      *(float4*)&win[20] = *(const float4*)(zr + 20);
      float m = ok ? 1.f : 0.f;
      float wv[8];
      #pragma unroll
      for (int j = 0; j < 8; ++j) wv[j] = wrow[j] * m;
      #pragma unroll
      for (int p = 0; p < 16; ++p)
        #pragma unroll
        for (int j = 0; j < 8; ++j)
          acc[hi][p] = fmaf(wv[j], win[p + j], acc[hi][p]);
    }
  }
  #pragma unroll
  for (int hi = 0; hi < 2; ++hi) {
    int h = h0 + hl + 32 * hi;
    float* dst = out + pbase + (size_t)h * 128 + w0;
    float4 o0 = {acc[hi][0],  acc[hi][1],  acc[hi][2],  acc[hi][3]};
    float4 o1 = {acc[hi][4],  acc[hi][5],  acc[hi][6],  acc[hi][7]};
    float4 o2 = {acc[hi][8],  acc[hi][9],  acc[hi][10], acc[hi][11]};
    float4 o3 = {acc[hi][12], acc[hi][13], acc[hi][14], acc[hi][15]};
    *(float4*)(dst)      = o0;
    *(float4*)(dst + 4)  = o1;
    *(float4*)(dst + 8)  = o2;
    *(float4*)(dst + 12) = o3;
  }
}

} // namespace

extern "C" void kernel_launch(void* const* d_in, const int* in_sizes, int n_in,
                              void* d_out, int out_size, void* d_ws, size_t ws_size,
                              hipStream_t stream)
{
  const float* x      = (const float*)d_in[0];
  const float* w_pre  = (const float*)d_in[1];
  const float* bn_pre = (const float*)d_in[2];
  const float* w_l1   = (const float*)d_in[3];
  const float* bn_l1  = (const float*)d_in[4];
  const float* w_l2   = (const float*)d_in[5];
  const float* bn_l2  = (const float*)d_in[6];
  const float* w_l3   = (const float*)d_in[7];
  const float* bn_l3  = (const float*)d_in[8];
  const float* w_qkv  = (const float*)d_in[9];
  const float* rpb    = (const float*)d_in[10];
  const float* w_dw   = (const float*)d_in[11];
  const float* w_pw   = (const float*)d_in[12];
  const float* bn_pj  = (const float*)d_in[13];
  float* out = (float*)d_out;

  char* base = (char*)d_ws;
  uint16_t* xT    = (uint16_t*)base;                          // 64 MiB NHWC bf16 x; later dwT
  uint16_t* preT  = (uint16_t*)(base + (size_t)67108864);     // 64 MiB NHWC bf16 pre; later attn out
  float*    bufB  = (float*)(base + (size_t)134217728);       // 128 MiB fp32 local/combined
  uint16_t* bufQ  = (uint16_t*)(base + (size_t)268435456);    // 192 MiB bf16 qkv windows; later dw out
  uint16_t* attnO = preT;
  float*    bufDw = (float*)bufQ;
  uint16_t* dwT   = xT;

  dim3 blk(256);
  // 0. cast x -> NHWC bf16
  k_cast<<<dim3(1024), blk, 0, stream>>>(x, xT);
  // 1. pre 1x1 conv + bn -> NHWC bf16 (MFMA, X-resident)
  k_gemm_v2<0, 2><<<dim3(1024), blk, 0, stream>>>(xT, w_pre, bn_pre, 256, preT, nullptr);
  // 2. dilated 3x3 convs + bn (MFMA) -> bufB fp32 NCHW
  k_dilconv_mfma<1, 86><<<dim3(32, 2, 8), blk, 0, stream>>>(preT, w_l1, bn_l1, bufB, 0, 0);
  k_dilconv_mfma<2, 86><<<dim3(32, 2, 8), blk, 0, stream>>>(preT, w_l2, bn_l2, bufB, 86, 80);
  k_dilconv_mfma<3, 84><<<dim3(32, 2, 8), blk, 0, stream>>>(preT, w_l3, bn_l3, bufB, 172, 160);
  // 3. qkv 1x1 conv -> bufQ window-layout bf16 (MFMA, X-resident, win-major px)
  k_gemm_v2<3, 6><<<dim3(1024), blk, 0, stream>>>(xT, w_qkv, nullptr, 768, bufQ, nullptr);
  // 4. windowed attention (MFMA) -> attnO bf16 NCHW (overwrites preT; safe)
  k_attn<<<dim3(256, 8), blk, 0, stream>>>(bufQ, rpb, attnO);
  // 5. pools + residual combine (in-place on bufB)
  k_pool<<<dim3(4096), blk, 0, stream>>>(attnO, bufB);
  // 6. depthwise 8x8 -> bufDw fp32 NCHW (overwrites bufQ; safe)
  k_dw<<<dim3(4096), blk, 0, stream>>>(bufB, w_dw, bufDw);
  // 7. cast dw-out -> NHWC bf16 (overwrites xT; safe)
  k_cast<<<dim3(1024), blk, 0, stream>>>(bufDw, dwT);
  // 8. pw 1x1 conv + bn -> out fp32 NCHW (MFMA, X-resident)
  k_gemm_v2<2, 2><<<dim3(1024), blk, 0, stream>>>(dwT, w_pw, bn_pj, 256, nullptr, out);

  (void)in_sizes; (void)n_in; (void)out_size; (void)ws_size;
}

// Round 10
// 761.178 us; speedup vs baseline: 5.7205x; 1.0986x over previous
//
#include <hip/hip_runtime.h>
#include <hip/hip_bf16.h>
#include <cstdint>
#include <cstddef>

namespace {

constexpr int HW = 16384;   // 128*128

typedef short vec8s __attribute__((ext_vector_type(8)));
typedef float f32x4 __attribute__((ext_vector_type(4)));

__device__ __forceinline__ float u2f(uint32_t u){ union { uint32_t u; float f; } v; v.u = u; return v.f; }
__device__ __forceinline__ uint32_t f2u(float f){ union { float f; uint32_t u; } v; v.f = f; return v.u; }
__device__ __forceinline__ uint16_t f2bf(float f){
  uint32_t u = f2u(f);
  u += 0x7fffu + ((u >> 16) & 1u);   // round-to-nearest-even
  return (uint16_t)(u >> 16);
}
__device__ __forceinline__ void unpack2(uint32_t w, float& lo, float& hi){
  lo = u2f(w << 16);
  hi = u2f(w & 0xffff0000u);
}

// ---------------------------------------------------------------------------
// Cast NCHW fp32 (256 ch) -> NHWC bf16. Block = one (b, row).
// ---------------------------------------------------------------------------
__global__ __launch_bounds__(256) void k_cast(
    const float* __restrict__ x, uint16_t* __restrict__ xT)
{
  __shared__ float sF[64][129];
  const int t = threadIdx.x;
  const int b = blockIdx.x >> 7;
  const int y = blockIdx.x & 127;
  const size_t rowoff = (size_t)y * 128;
  for (int cc = 0; cc < 4; ++cc) {
    const int cic0 = cc * 64;
    #pragma unroll
    for (int k = 0; k < 8; ++k) {
      int e = t + k * 256;
      int ci = e >> 5;
      int pxq = (e & 31) * 4;
      float4 v = *(const float4*)(x + (size_t)(b * 256 + cic0 + ci) * HW + rowoff + pxq);
      sF[ci][pxq] = v.x; sF[ci][pxq+1] = v.y; sF[ci][pxq+2] = v.z; sF[ci][pxq+3] = v.w;
    }
    __syncthreads();
    {
      int px = t >> 1, h = t & 1;
      __align__(16) uint16_t tmp[32];
      #pragma unroll
      for (int j = 0; j < 32; ++j) tmp[j] = f2bf(sF[h * 32 + j][px]);
      uint16_t* dst = xT + ((size_t)b * HW + rowoff + px) * 256 + cic0 + h * 32;
      *(uint4*)(dst)      = *(uint4*)&tmp[0];
      *(uint4*)(dst + 8)  = *(uint4*)&tmp[8];
      *(uint4*)(dst + 16) = *(uint4*)&tmp[16];
      *(uint4*)(dst + 24) = *(uint4*)&tmp[24];
    }
    __syncthreads();
  }
}

// ---------------------------------------------------------------------------
// 1x1 conv via bf16 MFMA, X-resident co-loop version (unchanged from r6).
// ---------------------------------------------------------------------------
template<int OUT_MODE, int NCO>
__global__ __launch_bounds__(256) void k_gemm_v2(
    const uint16_t* __restrict__ xT, const float* __restrict__ wmat,
    const float* __restrict__ bnp, int M,
    uint16_t* __restrict__ outb, float* __restrict__ outf)
{
  __shared__ __align__(16) uint16_t sX[128][260];
  __shared__ __align__(16) uint16_t sW[128][36];
  const int t = threadIdx.x;
  const int b    = blockIdx.x >> 7;
  const int tile = blockIdx.x & 127;
  const int l = t & 63, w = t >> 6;
  const int l15 = l & 15, koct = l >> 4;
  const int wc = w >> 1, wp = w & 1;

  {
    const int spx = t >> 1, sh = t & 1;
    int gpx;
    if constexpr (OUT_MODE == 3) {
      int win = tile * 2 + (spx >> 6);
      int p = spx & 63;
      gpx = ((win >> 4) * 8 + (p >> 3)) * 128 + (win & 15) * 8 + (p & 7);
    } else {
      gpx = tile * 128 + spx;
    }
    const uint16_t* src = xT + ((size_t)b * HW + gpx) * 256 + sh * 128;
    uint16_t* dst = &sX[spx][sh * 128];
    #pragma unroll
    for (int i = 0; i < 16; ++i)
      *(uint4*)(dst + i * 8) = *(const uint4*)(src + i * 8);
  }

  const int swc = t >> 1, swh = t & 1;
  float4 wr0, wr1, wr2, wr3;
  {
    const float* p = wmat + (size_t)swc * 256 + swh * 16;
    wr0 = *(const float4*)(p);     wr1 = *(const float4*)(p + 4);
    wr2 = *(const float4*)(p + 8); wr3 = *(const float4*)(p + 12);
  }
  __syncthreads();

  for (int cc = 0; cc < NCO; ++cc) {
    f32x4 acc[4][4];
    #pragma unroll
    for (int cf = 0; cf < 4; ++cf)
      #pragma unroll
      for (int pf = 0; pf < 4; ++pf) acc[cf][pf] = (f32x4){0.f,0.f,0.f,0.f};

    for (int kc = 0; kc < 8; ++kc) {
      if (cc | kc) __syncthreads();
      {
        __align__(16) uint16_t tmp[16];
        tmp[0]=f2bf(wr0.x); tmp[1]=f2bf(wr0.y); tmp[2]=f2bf(wr0.z); tmp[3]=f2bf(wr0.w);
        tmp[4]=f2bf(wr1.x); tmp[5]=f2bf(wr1.y); tmp[6]=f2bf(wr1.z); tmp[7]=f2bf(wr1.w);
        tmp[8]=f2bf(wr2.x); tmp[9]=f2bf(wr2.y); tmp[10]=f2bf(wr2.z); tmp[11]=f2bf(wr2.w);
        tmp[12]=f2bf(wr3.x); tmp[13]=f2bf(wr3.y); tmp[14]=f2bf(wr3.z); tmp[15]=f2bf(wr3.w);
        uint16_t* dst = &sW[swc][swh * 16];
        *(uint4*)(dst)     = *(uint4*)&tmp[0];
        *(uint4*)(dst + 8) = *(uint4*)&tmp[8];
      }
      {
        int nkc = kc + 1, ncc = cc;
        if (nkc == 8) { nkc = 0; ncc = cc + 1; }
        if (ncc < NCO) {
          const float* p = wmat + (size_t)(ncc * 128 + swc) * 256 + nkc * 32 + swh * 16;
          wr0 = *(const float4*)(p);     wr1 = *(const float4*)(p + 4);
          wr2 = *(const float4*)(p + 8); wr3 = *(const float4*)(p + 12);
        }
      }
      __syncthreads();
      vec8s bf[4];
      #pragma unroll
      for (int pf = 0; pf < 4; ++pf)
        bf[pf] = *(const vec8s*)&sX[wp * 64 + pf * 16 + l15][kc * 32 + koct * 8];
      #pragma unroll
      for (int cf = 0; cf < 4; ++cf) {
        vec8s af = *(const vec8s*)&sW[wc * 64 + cf * 16 + l15][koct * 8];
        #pragma unroll
        for (int pf = 0; pf < 4; ++pf)
          acc[cf][pf] = __builtin_amdgcn_mfma_f32_16x16x32_bf16(af, bf[pf], acc[cf][pf], 0, 0, 0);
      }
    }

    #pragma unroll
    for (int cf = 0; cf < 4; ++cf) {
      const int cbase = cc * 128 + wc * 64 + cf * 16 + koct * 4;
      float scv[4], shv[4];
      #pragma unroll
      for (int r = 0; r < 4; ++r) {
        scv[r] = 1.f; shv[r] = 0.f;
        if constexpr (OUT_MODE == 0 || OUT_MODE == 2) {
          int c = cbase + r;
          float g = bnp[c], be = bnp[M + c], mu = bnp[2 * M + c], va = bnp[3 * M + c];
          scv[r] = g * rsqrtf(va + 1e-5f);
          shv[r] = be - mu * scv[r];
        }
      }
      #pragma unroll
      for (int pf = 0; pf < 4; ++pf) {
        if constexpr (OUT_MODE == 0) {
          int px = tile * 128 + wp * 64 + pf * 16 + l15;
          __align__(8) uint16_t pk[4];
          #pragma unroll
          for (int r = 0; r < 4; ++r)
            pk[r] = f2bf(fmaf(acc[cf][pf][r], scv[r], shv[r]));
          *(uint2*)(outb + ((size_t)b * HW + px) * 256 + cbase) = *(uint2*)pk;
        } else if constexpr (OUT_MODE == 2) {
          int px = tile * 128 + wp * 64 + pf * 16 + l15;
          #pragma unroll
          for (int r = 0; r < 4; ++r)
            outf[(size_t)(b * M + cbase + r) * HW + px] =
                fmaf(acc[cf][pf][r], scv[r], shv[r]);
        } else {
          int win = tile * 2 + wp;
          int p = pf * 16 + l15;
          uint16_t* dstp = outb + ((size_t)(b * 256 + win) * 768 + cbase) * 64 + p;
          #pragma unroll
          for (int r = 0; r < 4; ++r)
            dstp[(size_t)r * 64] = f2bf(acc[cf][pf][r]);
        }
      }
    }
  }
}

// ---------------------------------------------------------------------------
// Dilated 3x3 conv + BN via bf16 MFMA implicit GEMM (unchanged from r3).
// ---------------------------------------------------------------------------
template<int DIL, int CG>
__global__ __launch_bounds__(256) void k_dilconv_mfma(
    const uint16_t* __restrict__ preT, const float* __restrict__ wt,
    const float* __restrict__ bnp, float* __restrict__ out,
    int cb, int cb_al)
{
  constexpr int R = 8 + 2 * DIL;
  constexpr int C = 64 + 2 * DIL;
  constexpr int NPOS = R * C;
  constexpr int NIT = (NPOS + 255) / 256;
  __shared__ __align__(16) uint16_t sX[NPOS * 16];
  __shared__ __align__(16) uint16_t sW[10 * 50 * 16];

  const int t = threadIdx.x;
  const int rt    = blockIdx.x >> 1;
  const int ctile = blockIdx.x & 1;
  const int ct2   = blockIdx.y;
  const int b     = blockIdx.z;
  const int y0 = rt * 8, x0 = ctile * 64;
  const int l = t & 63, w = t >> 6;
  const int l15 = l & 15, oct = (l >> 4) & 1, half = l >> 5;
  const int rbase = w * 2;

  f32x4 acc[3][8];
  #pragma unroll
  for (int cf = 0; cf < 3; ++cf)
    #pragma unroll
    for (int q = 0; q < 8; ++q) acc[cf][q] = (f32x4){0.f,0.f,0.f,0.f};

  for (int kc = 0; kc < 6; ++kc) {
    #pragma unroll
    for (int i = 0; i < 3; ++i) {
      int pair = t + i * 256;
      int co = pair >> 4, ci = pair & 15;
      int cog = ct2 * 48 + co;
      int c = cb_al + kc * 16 + ci;
      bool ok = (cog < CG) && (c >= cb) && (c < cb + CG);
      size_t widx = ok ? ((size_t)cog * (size_t)CG + (size_t)(c - cb)) * 9u
                       : (size_t)0;
      const float* wp = wt + widx;
      uint16_t* dst = &sW[co * 16 + ci];
      #pragma unroll
      for (int tap = 0; tap < 9; ++tap)
        dst[tap * 800] = ok ? f2bf(wp[tap]) : (uint16_t)0;
      dst[9 * 800] = 0;
    }
    #pragma unroll
    for (int i = 0; i < NIT; ++i) {
      int p = t + i * 256;
      if (p < NPOS) {
        int row = p / C, col = p % C;
        int gy = y0 + row - DIL, gx = x0 + col - DIL;
        uint4 va = {0,0,0,0}, vb = {0,0,0,0};
        if ((unsigned)gy < 128u && (unsigned)gx < 128u) {
          const uint4* src = (const uint4*)(preT +
              (((size_t)b * HW + gy * 128 + gx) * 256 + cb_al + kc * 16));
          va = src[0]; vb = src[1];
        }
        uint4* dst = (uint4*)&sX[p * 16];
        dst[0] = va; dst[1] = vb;
      }
    }
    __syncthreads();

    #pragma unroll
    for (int s = 0; s < 5; ++s) {
      const int tap0 = 2 * s, tap1 = 2 * s + 1;
      const int dy0 = tap0 / 3, dx0 = tap0 % 3;
      const int dy1 = (tap1 <= 8) ? tap1 / 3 : 2;
      const int dx1 = (tap1 <= 8) ? tap1 % 3 : 2;
      const int dy = half ? dy1 : dy0;
      const int dx = half ? dx1 : dx0;
      const int atap = tap0 + half;
      vec8s a0 = *(const vec8s*)&sW[(atap * 50 + 0  + l15) * 16 + oct * 8];
      vec8s a1 = *(const vec8s*)&sW[(atap * 50 + 16 + l15) * 16 + oct * 8];
      vec8s a2 = *(const vec8s*)&sW[(atap * 50 + 32 + l15) * 16 + oct * 8];
      #pragma unroll
      for (int rs = 0; rs < 2; ++rs) {
        const int rowin = rbase + rs + dy * DIL;
        #pragma unroll
        for (int c4 = 0; c4 < 4; ++c4) {
          const int colin = c4 * 16 + l15 + dx * DIL;
          vec8s bf = *(const vec8s*)&sX[(rowin * C + colin) * 16 + oct * 8];
          acc[0][rs*4+c4] = __builtin_amdgcn_mfma_f32_16x16x32_bf16(a0, bf, acc[0][rs*4+c4], 0, 0, 0);
          acc[1][rs*4+c4] = __builtin_amdgcn_mfma_f32_16x16x32_bf16(a1, bf, acc[1][rs*4+c4], 0, 0, 0);
          acc[2][rs*4+c4] = __builtin_amdgcn_mfma_f32_16x16x32_bf16(a2, bf, acc[2][rs*4+c4], 0, 0, 0);
        }
      }
    }
    __syncthreads();
  }

  const int row4 = (l >> 4);
  #pragma unroll
  for (int cf = 0; cf < 3; ++cf) {
    #pragma unroll
    for (int r = 0; r < 4; ++r) {
      int c_loc = ct2 * 48 + cf * 16 + row4 * 4 + r;
      if (c_loc < CG) {
        int cg = cb + c_loc;
        float g = bnp[c_loc], be = bnp[CG + c_loc];
        float mu = bnp[2 * CG + c_loc], va = bnp[3 * CG + c_loc];
        float scv = g * rsqrtf(va + 1e-5f);
        float shv = be - mu * scv;
        #pragma unroll
        for (int rs = 0; rs < 2; ++rs) {
          int y = y0 + rbase + rs;
          #pragma unroll
          for (int c4 = 0; c4 < 4; ++c4) {
            int x = x0 + c4 * 16 + l15;
            out[(size_t)(b * 256 + cg) * HW + y * 128 + x] =
                fmaf(acc[cf][rs*4+c4][r], scv, shv);
          }
        }
      }
    }
  }
}

// ---------------------------------------------------------------------------
// Windowed attention, wave-autonomous + MFMA (unchanged from r8).
// ---------------------------------------------------------------------------
__global__ __launch_bounds__(256) void k_attn(
    const uint16_t* __restrict__ qkvW, const float* __restrict__ rpb,
    uint16_t* __restrict__ outp)
{
  __shared__ __align__(16) uint16_t sAll[4][9928];
  const int t = threadIdx.x;
  const int l = t & 63, w = t >> 6;
  const int l15 = l & 15, koct = l >> 4;
  const int b = blockIdx.y;
  const int win = blockIdx.x;
  const int wy = win >> 4, wx = win & 15;
  const int wbase = (wy * 8) * 128 + wx * 8;
  const uint16_t* base = qkvW + (size_t)(b * 256 + win) * 49152;
  uint16_t* swKT = &sAll[w][0];
  uint16_t* swQT = &sAll[w][2560];
  uint16_t* swPT = &sAll[w][5120];
  float*    swB  = (float*)&sAll[w][9472];
  float*    swO  = (float*)swPT;

  {
    uint4 z = {0,0,0,0};
    *(uint4*)(swKT + l * 40 + 16) = z;
    *(uint4*)(swKT + l * 40 + 24) = z;
    *(uint4*)(swQT + l * 40 + 16) = z;
    *(uint4*)(swQT + l * 40 + 24) = z;
  }

  for (int it = 0; it < 4; ++it) {
    const int n = w + it * 4;
    #pragma unroll
    for (int m = 0; m < 4; ++m) {
      int e = l + m * 64;
      if (e < 225) swB[e] = rpb[e * 16 + n];
    }
    const uint16_t* qg = base + (size_t)(n * 16) * 64;
    const uint16_t* kg = base + (size_t)(256 + n * 16) * 64;
    const uint16_t* vg = base + (size_t)(512 + n * 16) * 64;
    {
      uint32_t kp[8], qp[8];
      #pragma unroll
      for (int m = 0; m < 8; ++m) {
        uint32_t k0 = kg[(2 * m) * 64 + l], k1 = kg[(2 * m + 1) * 64 + l];
        uint32_t q0 = qg[(2 * m) * 64 + l], q1 = qg[(2 * m + 1) * 64 + l];
        kp[m] = k0 | (k1 << 16);
        qp[m] = q0 | (q1 << 16);
      }
      *(uint4*)(swKT + l * 40)     = *(uint4*)&kp[0];
      *(uint4*)(swKT + l * 40 + 8) = *(uint4*)&kp[4];
      *(uint4*)(swQT + l * 40)     = *(uint4*)&qp[0];
      *(uint4*)(swQT + l * 40 + 8) = *(uint4*)&qp[4];
    }
    asm volatile("s_waitcnt lgkmcnt(0)" ::: "memory");
    __builtin_amdgcn_sched_barrier(0);

    vec8s aK[4], bQ[4];
    #pragma unroll
    for (int tt = 0; tt < 4; ++tt) {
      aK[tt] = *(const vec8s*)(swKT + (tt * 16 + l15) * 40 + koct * 8);
      bQ[tt] = *(const vec8s*)(swQT + (tt * 16 + l15) * 40 + koct * 8);
    }
    f32x4 accS[4][4];
    #pragma unroll
    for (int ti = 0; ti < 4; ++ti)
      #pragma unroll
      for (int tj = 0; tj < 4; ++tj)
        accS[ti][tj] = __builtin_amdgcn_mfma_f32_16x16x32_bf16(
            aK[tj], bQ[ti], (f32x4){0.f, 0.f, 0.f, 0.f}, 0, 0, 0);

    float p[4][16], sinv[4];
    #pragma unroll
    for (int ti = 0; ti < 4; ++ti) {
      const int i = ti * 16 + l15;
      const int irow = i >> 3, icol = i & 7;
      #pragma unroll
      for (int tj = 0; tj < 4; ++tj) {
        #pragma unroll
        for (int r = 0; r < 4; ++r) {
          int j = tj * 16 + koct * 4 + r;
          int rel = (irow - (j >> 3) + 7) * 15 + (icol - (j & 7) + 7);
          p[ti][tj * 4 + r] = fmaf(accS[ti][tj][r], 0.25f, swB[rel]);
        }
      }
      float mx = p[ti][0];
      #pragma unroll
      for (int u = 1; u < 16; ++u) mx = fmaxf(mx, p[ti][u]);
      mx = fmaxf(mx, __shfl_xor(mx, 16));
      mx = fmaxf(mx, __shfl_xor(mx, 32));
      float s = 0.f;
      #pragma unroll
      for (int u = 0; u < 16; ++u) { p[ti][u] = __expf(p[ti][u] - mx); s += p[ti][u]; }
      s += __shfl_xor(s, 16);
      s += __shfl_xor(s, 32);
      sinv[ti] = 1.f / s;
    }

    #pragma unroll
    for (int ti = 0; ti < 4; ++ti) {
      uint16_t* rowp = swPT + (ti * 16 + l15) * 68 + koct * 4;
      #pragma unroll
      for (int tj = 0; tj < 4; ++tj) {
        uint32_t u0 = (uint32_t)f2bf(p[ti][tj * 4 + 0]) | ((uint32_t)f2bf(p[ti][tj * 4 + 1]) << 16);
        uint32_t u1 = (uint32_t)f2bf(p[ti][tj * 4 + 2]) | ((uint32_t)f2bf(p[ti][tj * 4 + 3]) << 16);
        *(uint32_t*)(rowp + tj * 16)     = u0;
        *(uint32_t*)(rowp + tj * 16 + 2) = u1;
      }
    }
    asm volatile("s_waitcnt lgkmcnt(0)" ::: "memory");
    __builtin_amdgcn_sched_barrier(0);

    f32x4 accO[4];
    #pragma unroll
    for (int ii = 0; ii < 4; ++ii) accO[ii] = (f32x4){0.f, 0.f, 0.f, 0.f};
    #pragma unroll
    for (int ks = 0; ks < 2; ++ks) {
      vec8s aV = *(const vec8s*)(vg + l15 * 64 + ks * 32 + koct * 8);
      #pragma unroll
      for (int ii = 0; ii < 4; ++ii) {
        vec8s bP;
        const uint16_t* src = swPT + (ii * 16 + l15) * 68 + ks * 32 + koct * 8;
        *(uint2*)&bP         = *(const uint2*)(src);
        *((uint2*)&bP + 1)   = *(const uint2*)(src + 4);
        accO[ii] = __builtin_amdgcn_mfma_f32_16x16x32_bf16(aV, bP, accO[ii], 0, 0, 0);
      }
    }
    asm volatile("s_waitcnt lgkmcnt(0)" ::: "memory");
    __builtin_amdgcn_sched_barrier(0);

    #pragma unroll
    for (int ii = 0; ii < 4; ++ii) {
      #pragma unroll
      for (int r = 0; r < 4; ++r) {
        int dd = koct * 4 + r;
        swO[dd * 76 + ii * 16 + l15] = accO[ii][r] * sinv[ii];
      }
    }
    asm volatile("s_waitcnt lgkmcnt(0)" ::: "memory");
    __builtin_amdgcn_sched_barrier(0);
    #pragma unroll
    for (int e2 = 0; e2 < 2; ++e2) {
      int e = l + e2 * 64;
      int dd = e >> 3, row = e & 7;
      const float* orow = swO + dd * 76 + row * 8;
      float4 a = *(const float4*)(orow);
      float4 c = *(const float4*)(orow + 4);
      uint4 pk;
      pk.x = (uint32_t)f2bf(a.x) | ((uint32_t)f2bf(a.y) << 16);
      pk.y = (uint32_t)f2bf(a.z) | ((uint32_t)f2bf(a.w) << 16);
      pk.z = (uint32_t)f2bf(c.x) | ((uint32_t)f2bf(c.y) << 16);
      pk.w = (uint32_t)f2bf(c.z) | ((uint32_t)f2bf(c.w) << 16);
      *(uint4*)(outp + (size_t)(b * 256 + n * 16 + dd) * HW + wbase + row * 128) = pk;
    }
    asm volatile("s_waitcnt lgkmcnt(0)" ::: "memory");
    __builtin_amdgcn_sched_barrier(0);
  }
}

// ---------------------------------------------------------------------------
// combined = avgpool_v(attn) + avgpool_h(attn) + local (unchanged from r9).
// ---------------------------------------------------------------------------
__global__ __launch_bounds__(256) void k_pool(
    const uint16_t* __restrict__ attnb, float* __restrict__ loc)
{
  __shared__ __align__(16) float sP[71][136];
  const int t = threadIdx.x;
  const int plane = blockIdx.x >> 1;
  const int h0 = (blockIdx.x & 1) * 64;
  const size_t pbase = (size_t)plane * HW;
  #pragma unroll
  for (int k = 0; k < 5; ++k) {
    int idx = t + k * 256;
    if (idx < 71 * 16) {
      int lr = idx >> 4, m = idx & 15;
      int g = h0 - 3 + lr;
      float f[8] = {0.f,0.f,0.f,0.f,0.f,0.f,0.f,0.f};
      if (g >= 0 && g <= 127) {
        uint4 v4 = *(const uint4*)(attnb + pbase + (size_t)g * 128 + m * 8);
        unpack2(v4.x, f[0], f[1]); unpack2(v4.y, f[2], f[3]);
        unpack2(v4.z, f[4], f[5]); unpack2(v4.w, f[6], f[7]);
      }
      float* dst = &sP[lr][4 + m * 8];
      *(float4*)dst       = (float4){f[0], f[1], f[2], f[3]};
      *(float4*)(dst + 4) = (float4){f[4], f[5], f[6], f[7]};
    }
  }
  #pragma unroll
  for (int k = 0; k < 3; ++k) {
    int idx = t + k * 256;
    if (idx < 71 * 8) {
      int lr = idx >> 3, e = idx & 7;
      int c = (e < 4) ? e : (128 + e);
      sP[lr][c] = 0.f;
    }
  }
  __syncthreads();

  const int q  = t & 31;
  const int r0 = (t >> 5) * 8;
  const int w0 = q * 4;
  float4 av = {0.f, 0.f, 0.f, 0.f};
  #pragma unroll
  for (int o = 0; o < 8; ++o) {
    float4 v = *(const float4*)&sP[r0 + o][4 + w0];
    av.x += v.x; av.y += v.y; av.z += v.z; av.w += v.w;
  }
  #pragma unroll
  for (int rr = 0; rr < 8; ++rr) {
    const int lh = r0 + rr;
    const int h = h0 + lh;
    float4 a = av;
    if (h >= 124) {
      float4 cfix = *(const float4*)&sP[126 - 64 + 3][4 + w0];
      a.x += cfix.x; a.y += cfix.y; a.z += cfix.z; a.w += cfix.w;
    }
    float4 hv0 = *(const float4*)&sP[lh + 3][w0];
    float4 hv1 = *(const float4*)&sP[lh + 3][w0 + 4];
    float4 hv2 = *(const float4*)&sP[lh + 3][w0 + 8];
    float s0 = hv0.y + hv0.z + hv0.w + hv1.x + hv1.y + hv1.z + hv1.w + hv2.x;
    float s1 = s0 - hv0.y + hv2.y;
    float s2 = s1 - hv0.z + hv2.z;
    float s3 = s2 - hv0.w + hv2.w;
    if (q == 31) {
      float cfix = sP[lh + 3][130];
      s0 += cfix; s1 += cfix; s2 += cfix; s3 += cfix;
    }
    const size_t gi = pbase + (size_t)h * 128 + w0;
    float4 lv = *(const float4*)(loc + gi);
    float4 o4;
    o4.x = fmaf(a.x + s0, 0.125f, lv.x);
    o4.y = fmaf(a.y + s1, 0.125f, lv.y);
    o4.z = fmaf(a.z + s2, 0.125f, lv.z);
    o4.w = fmaf(a.w + s3, 0.125f, lv.w);
    *(float4*)(loc + gi) = o4;
    if (rr < 7) {
      float4 vm = *(const float4*)&sP[lh][4 + w0];
      float4 vp = *(const float4*)&sP[lh + 8][4 + w0];
      av.x += vp.x - vm.x; av.y += vp.y - vm.y;
      av.z += vp.z - vm.z; av.w += vp.w - vm.w;
    }
  }
}

// ---------------------------------------------------------------------------
// Depthwise 8x8 conv, rewritten: thread = 4 cols x 8 output rows; 15 input
// rows read once (3 aligned b128 each, conflict-free); weights in registers.
// sZ: col bb at idx 4+bb; idx0-3 zero; idx132 = reflect(bb=128->126);
// idx133-135 zero. Rows: g in [0,128] (128->126), else zero.
// ---------------------------------------------------------------------------
__global__ __launch_bounds__(256) void k_dw(
    const float* __restrict__ comb, const float* __restrict__ wdw,
    float* __restrict__ out)
{
  __shared__ __align__(16) float sZ[71][136];
  __shared__ float sWd[64];
  const int t = threadIdx.x;
  const int plane = blockIdx.x >> 1;
  const int cch = plane & 255;
  const int h0 = (blockIdx.x & 1) * 64;
  const size_t pbase = (size_t)plane * HW;
  if (t < 64) sWd[t] = wdw[cch * 64 + t];
  #pragma unroll
  for (int k = 0; k < 5; ++k) {
    int idx = t + k * 256;
    if (idx < 71 * 16) {
      int lr = idx >> 4, m = idx & 15;
      int g = h0 - 3 + lr;
      float4 a = {0.f,0.f,0.f,0.f}, c = {0.f,0.f,0.f,0.f};
      if (g >= 0 && g <= 128) {
        int gr = (g == 128) ? 126 : g;
        const float* src = comb + pbase + (size_t)gr * 128 + m * 8;
        a = *(const float4*)(src);
        c = *(const float4*)(src + 4);
      }
      float* dst = &sZ[lr][4 + m * 8];
      *(float4*)dst       = a;
      *(float4*)(dst + 4) = c;
    }
  }
  if (t < 71) {
    int lr = t;
    int g = h0 - 3 + lr;
    float rv = 0.f;
    if (g >= 0 && g <= 128) {
      int gr = (g == 128) ? 126 : g;
      rv = comb[pbase + (size_t)gr * 128 + 126];
    }
    *(float4*)&sZ[lr][0] = (float4){0.f, 0.f, 0.f, 0.f};
    sZ[lr][132] = rv;
    sZ[lr][133] = 0.f; sZ[lr][134] = 0.f; sZ[lr][135] = 0.f;
  }
  __syncthreads();

  float wt[8][8];
  #pragma unroll
  for (int i = 0; i < 8; ++i) {
    *(float4*)&wt[i][0] = *(const float4*)&sWd[i * 8];
    *(float4*)&wt[i][4] = *(const float4*)&sWd[i * 8 + 4];
  }

  const int q  = t & 31;
  const int rg = t >> 5;
  const int w0 = q * 4;
  f32x4 acc[8];
  #pragma unroll
  for (int rr = 0; rr < 8; ++rr) acc[rr] = (f32x4){0.f,0.f,0.f,0.f};

  #pragma unroll
  for (int v = 0; v < 15; ++v) {
    const int lr = rg * 8 + v;
    float win[12];
    *(float4*)&win[0] = *(const float4*)&sZ[lr][w0];       // bb w0-4..w0-1
    *(float4*)&win[4] = *(const float4*)&sZ[lr][w0 + 4];   // bb w0..w0+3
    *(float4*)&win[8] = *(const float4*)&sZ[lr][w0 + 8];   // bb w0+4..w0+7
    #pragma unroll
    for (int rr = 0; rr < 8; ++rr) {
      const int i = v - rr;
      if (i >= 0 && i < 8) {
        #pragma unroll
        for (int c = 0; c < 4; ++c) {
          float s = acc[rr][c];
          #pragma unroll
          for (int j = 0; j < 8; ++j)
            s = fmaf(wt[i][j], win[c + j + 1], s);   // bb = w0+c+j-3
          acc[rr][c] = s;
        }
      }
    }
  }
  #pragma unroll
  for (int rr = 0; rr < 8; ++rr) {
    int h = h0 + rg * 8 + rr;
    float* dst = out + pbase + (size_t)h * 128 + w0;
    *(float4*)dst = (float4){acc[rr][0], acc[rr][1], acc[rr][2], acc[rr][3]};
  }
}

} // namespace

extern "C" void kernel_launch(void* const* d_in, const int* in_sizes, int n_in,
                              void* d_out, int out_size, void* d_ws, size_t ws_size,
                              hipStream_t stream)
{
  const float* x      = (const float*)d_in[0];
  const float* w_pre  = (const float*)d_in[1];
  const float* bn_pre = (const float*)d_in[2];
  const float* w_l1   = (const float*)d_in[3];
  const float* bn_l1  = (const float*)d_in[4];
  const float* w_l2   = (const float*)d_in[5];
  const float* bn_l2  = (const float*)d_in[6];
  const float* w_l3   = (const float*)d_in[7];
  const float* bn_l3  = (const float*)d_in[8];
  const float* w_qkv  = (const float*)d_in[9];
  const float* rpb    = (const float*)d_in[10];
  const float* w_dw   = (const float*)d_in[11];
  const float* w_pw   = (const float*)d_in[12];
  const float* bn_pj  = (const float*)d_in[13];
  float* out = (float*)d_out;

  char* base = (char*)d_ws;
  uint16_t* xT    = (uint16_t*)base;                          // 64 MiB NHWC bf16 x; later dwT
  uint16_t* preT  = (uint16_t*)(base + (size_t)67108864);     // 64 MiB NHWC bf16 pre; later attn out
  float*    bufB  = (float*)(base + (size_t)134217728);       // 128 MiB fp32 local/combined
  uint16_t* bufQ  = (uint16_t*)(base + (size_t)268435456);    // 192 MiB bf16 qkv windows; later dw out
  uint16_t* attnO = preT;
  float*    bufDw = (float*)bufQ;
  uint16_t* dwT   = xT;

  dim3 blk(256);
  // 0. cast x -> NHWC bf16
  k_cast<<<dim3(1024), blk, 0, stream>>>(x, xT);
  // 1. pre 1x1 conv + bn -> NHWC bf16 (MFMA, X-resident)
  k_gemm_v2<0, 2><<<dim3(1024), blk, 0, stream>>>(xT, w_pre, bn_pre, 256, preT, nullptr);
  // 2. dilated 3x3 convs + bn (MFMA) -> bufB fp32 NCHW
  k_dilconv_mfma<1, 86><<<dim3(32, 2, 8), blk, 0, stream>>>(preT, w_l1, bn_l1, bufB, 0, 0);
  k_dilconv_mfma<2, 86><<<dim3(32, 2, 8), blk, 0, stream>>>(preT, w_l2, bn_l2, bufB, 86, 80);
  k_dilconv_mfma<3, 84><<<dim3(32, 2, 8), blk, 0, stream>>>(preT, w_l3, bn_l3, bufB, 172, 160);
  // 3. qkv 1x1 conv -> bufQ window-layout bf16 (MFMA, X-resident, win-major px)
  k_gemm_v2<3, 6><<<dim3(1024), blk, 0, stream>>>(xT, w_qkv, nullptr, 768, bufQ, nullptr);
  // 4. windowed attention (MFMA) -> attnO bf16 NCHW (overwrites preT; safe)
  k_attn<<<dim3(256, 8), blk, 0, stream>>>(bufQ, rpb, attnO);
  // 5. pools + residual combine (in-place on bufB)
  k_pool<<<dim3(4096), blk, 0, stream>>>(attnO, bufB);
  // 6. depthwise 8x8 -> bufDw fp32 NCHW (overwrites bufQ; safe)
  k_dw<<<dim3(4096), blk, 0, stream>>>(bufB, w_dw, bufDw);
  // 7. cast dw-out -> NHWC bf16 (overwrites xT; safe)
  k_cast<<<dim3(1024), blk, 0, stream>>>(bufDw, dwT);
  // 8. pw 1x1 conv + bn -> out fp32 NCHW (MFMA, X-resident)
  k_gemm_v2<2, 2><<<dim3(1024), blk, 0, stream>>>(dwT, w_pw, bn_pj, 256, nullptr, out);

  (void)in_sizes; (void)n_in; (void)out_size; (void)ws_size;
}